// Round 1
// baseline (3052.905 us; speedup 1.0000x reference)
//
#include <hip/hip_runtime.h>

#define KNB 16
#define BSZ 8
#define NPT 2048

__device__ __forceinline__ float lrelu(float x) { return x >= 0.f ? x : 0.01f * x; }

// ---------------------------------------------------------------------------
// Per-point squared norms
// ---------------------------------------------------------------------------
template<int C>
__global__ void norms_kernel(const float* __restrict__ feat, float* __restrict__ out) {
    int gid = blockIdx.x * blockDim.x + threadIdx.x;
    if (gid < BSZ * NPT) {
        const float* p = feat + (size_t)gid * C;
        float s = 0.f;
#pragma unroll
        for (int c = 0; c < C; ++c) s = fmaf(p[c], p[c], s);
        out[gid] = s;
    }
}

// ---------------------------------------------------------------------------
// KNN: for each (b,i) find the 16 j minimizing |x_i - x_j|^2.
// score s(i,j) = |p_j|^2 - 2 q_i . p_j  (same ranking as d^2; |q|^2 constant).
// Block: 256 threads = 64 queries x 4 j-partitions. Query in registers,
// j-tiles staged in LDS (broadcast reads). Private top-16 per thread, merged
// through LDS into partition 0 at the end.
// ---------------------------------------------------------------------------
template<int C, int TJ>
__launch_bounds__(256)
__global__ void knn_kernel(const float* __restrict__ feat,
                           const float* __restrict__ norms,
                           int* __restrict__ knn_out) {
    constexpr int JPT = TJ / 4;   // j's per thread per tile
    constexpr int CP  = C + 4;    // row pad (keeps rows 16B aligned for C=32/128)
    const int b   = blockIdx.y;
    const int i0  = blockIdx.x * 64;
    const int tid = threadIdx.x;
    const int il  = tid & 63;     // local query index (lane)
    const int jg  = tid >> 6;     // j partition (wave-uniform)
    const float* fb = feat + (size_t)b * NPT * C;

    __shared__ float sP[TJ][CP];
    __shared__ float sPn[TJ];
    __shared__ float sMd[64][KNB + 1];
    __shared__ int   sMi[64][KNB + 1];

    // query into registers
    float q[C];
    {
        const float* qp = fb + (size_t)(i0 + il) * C;
#pragma unroll
        for (int c = 0; c < C; ++c) q[c] = qp[c];
    }

    float bd[KNB]; int bi[KNB];
#pragma unroll
    for (int t = 0; t < KNB; ++t) { bd[t] = 1e30f; bi[t] = 0; }
    float mx = 1e30f; int mp = 0;

    auto insert = [&](float d, int j) {
#pragma unroll
        for (int t = 0; t < KNB; ++t) if (t == mp) { bd[t] = d; bi[t] = j; }
        mx = -1e30f;
#pragma unroll
        for (int t = 0; t < KNB; ++t) if (bd[t] > mx) { mx = bd[t]; mp = t; }
    };

    for (int j0 = 0; j0 < NPT; j0 += TJ) {
        __syncthreads();   // previous tile fully consumed
        for (int t = tid; t < TJ * C; t += 256) {
            int r = t / C, c = t - r * C;
            sP[r][c] = fb[(size_t)j0 * C + t];   // == fb[(j0+r)*C + c]
        }
        if (tid < TJ) sPn[tid] = norms[b * NPT + j0 + tid];
        __syncthreads();
#pragma unroll 1
        for (int jj = 0; jj < JPT; ++jj) {
            const int jl = jg * JPT + jj;
            float dot = 0.f;
#pragma unroll
            for (int c = 0; c < C; ++c) dot = fmaf(q[c], sP[jl][c], dot);
            const float d = fmaf(-2.f, dot, sPn[jl]);
            if (d < mx) insert(d, j0 + jl);
        }
    }

    // merge partitions 1..3 into partition 0 (wave-uniform branches)
#pragma unroll 1
    for (int r = 1; r < 4; ++r) {
        __syncthreads();
        if (jg == r) {
#pragma unroll
            for (int t = 0; t < KNB; ++t) { sMd[il][t] = bd[t]; sMi[il][t] = bi[t]; }
        }
        __syncthreads();
        if (jg == 0) {
#pragma unroll 1
            for (int t = 0; t < KNB; ++t) {
                const float d = sMd[il][t];
                if (d < mx) insert(d, sMi[il][t]);
            }
        }
    }
    if (jg == 0) {
        int* o = knn_out + ((size_t)b * NPT + i0 + il) * KNB;
#pragma unroll
        for (int t = 0; t < KNB; ++t) o[t] = bi[t];
    }
}

// ---------------------------------------------------------------------------
// Block 1: concat(x_i(3), x_j(3)) -> 16 -> 64 -> 32, lrelu each, sum over k.
// Block: 256 threads = 16 points x 16 neighbors; weights in LDS (13 KB).
// ---------------------------------------------------------------------------
__launch_bounds__(256)
__global__ void block1_kernel(const float* __restrict__ x, const int* __restrict__ knn,
                              const float* __restrict__ w1, const float* __restrict__ b1,
                              const float* __restrict__ w2, const float* __restrict__ b2,
                              const float* __restrict__ w3, const float* __restrict__ b3,
                              float* __restrict__ x2out) {
    __shared__ float sw1[96], sb1[16], sw2[1024], sb2[64], sw3[2048], sb3[32];
    __shared__ float sh[16][16][32];
    const int tid = threadIdx.x;
    for (int t = tid; t < 96;  t += 256) sw1[t] = w1[t];
    if (tid < 16) sb1[tid] = b1[tid];
    for (int t = tid; t < 1024; t += 256) sw2[t] = w2[t];
    if (tid < 64) sb2[tid] = b2[tid];
    for (int t = tid; t < 2048; t += 256) sw3[t] = w3[t];
    if (tid < 32) sb3[tid] = b3[tid];
    __syncthreads();

    const int pt = tid >> 4, k = tid & 15;
    const int bn = blockIdx.x * 16 + pt;            // global point id
    const int b  = bn >> 11, n = bn & (NPT - 1);
    const float* xb = x + (size_t)b * NPT * 3;
    const int j = knn[(size_t)bn * KNB + k];

    float in6[6] = { xb[n*3+0], xb[n*3+1], xb[n*3+2],
                     xb[j*3+0], xb[j*3+1], xb[j*3+2] };
    float h1[16];
#pragma unroll
    for (int o = 0; o < 16; ++o) {
        float a = sb1[o];
#pragma unroll
        for (int i = 0; i < 6; ++i) a = fmaf(in6[i], sw1[i * 16 + o], a);
        h1[o] = lrelu(a);
    }
    float h2[64];
#pragma unroll
    for (int o = 0; o < 64; ++o) {
        float a = sb2[o];
#pragma unroll
        for (int i = 0; i < 16; ++i) a = fmaf(h1[i], sw2[i * 64 + o], a);
        h2[o] = lrelu(a);
    }
#pragma unroll
    for (int o = 0; o < 32; ++o) {
        float a = sb3[o];
#pragma unroll
        for (int i = 0; i < 64; ++i) a = fmaf(h2[i], sw3[i * 32 + o], a);
        sh[pt][k][o] = lrelu(a);
    }
    __syncthreads();
    for (int t = tid; t < 16 * 32; t += 256) {
        int p2 = t >> 5, o = t & 31;
        float s = 0.f;
#pragma unroll
        for (int kk = 0; kk < 16; ++kk) s += sh[p2][kk][o];
        x2out[(size_t)(blockIdx.x * 16 + p2) * 32 + o] = s;
    }
}

// ---------------------------------------------------------------------------
// Block 2: concat(x2_i(32), x2_j(32)) -> 256 -> 128, lrelu each, sum over k.
// One workgroup (256 threads) per point. Center contribution of layer 1 is
// shared across k. h1 staged in LDS [16][256].
// ---------------------------------------------------------------------------
__launch_bounds__(256)
__global__ void block2_kernel(const float* __restrict__ x2, const int* __restrict__ knn,
                              const float* __restrict__ w1, const float* __restrict__ b1,
                              const float* __restrict__ w2, const float* __restrict__ b2,
                              float* __restrict__ x3) {
    const int bn = blockIdx.x;
    const int b  = bn >> 11;
    const int tid = threadIdx.x;
    __shared__ float s_in[17][33];     // [0]=center, [1+k]=neighbor k (32 used)
    __shared__ float s_h1[16][256];
    __shared__ float s_part[256];
    __shared__ int   s_nb[16];
    if (tid < 16) s_nb[tid] = knn[(size_t)bn * KNB + tid];
    __syncthreads();
    for (int t = tid; t < 17 * 32; t += 256) {
        int r = t >> 5, c = t & 31;
        int src = (r == 0) ? bn : (b * NPT + s_nb[r - 1]);
        s_in[r][c] = x2[(size_t)src * 32 + c];
    }
    __syncthreads();

    // layer 1: thread tid owns output column tid (of 256)
    float cp = 0.f;
#pragma unroll 4
    for (int i = 0; i < 32; ++i) cp = fmaf(s_in[0][i], w1[i * 256 + tid], cp);
    float acc[16];
#pragma unroll
    for (int k = 0; k < 16; ++k) acc[k] = 0.f;
#pragma unroll 2
    for (int i = 0; i < 32; ++i) {
        float w = w1[(32 + i) * 256 + tid];
#pragma unroll
        for (int k = 0; k < 16; ++k) acc[k] = fmaf(s_in[1 + k][i], w, acc[k]);
    }
    float bb = b1[tid];
#pragma unroll
    for (int k = 0; k < 16; ++k) s_h1[k][tid] = lrelu(cp + acc[k] + bb);
    __syncthreads();

    // layer 2: thread tid -> column o = tid&127, k-half kh = tid>>7
    const int o = tid & 127, kh = tid >> 7;
    float a2[8];
#pragma unroll
    for (int k = 0; k < 8; ++k) a2[k] = 0.f;
#pragma unroll 4
    for (int i = 0; i < 256; ++i) {
        float w = w2[i * 128 + o];
#pragma unroll
        for (int k = 0; k < 8; ++k) a2[k] = fmaf(s_h1[kh * 8 + k][i], w, a2[k]);
    }
    float b2v = b2[o];
    float ps = 0.f;
#pragma unroll
    for (int k = 0; k < 8; ++k) ps += lrelu(a2[k] + b2v);
    s_part[tid] = ps;
    __syncthreads();
    if (tid < 128) x3[(size_t)bn * 128 + tid] = s_part[tid] + s_part[tid + 128];
}

// ---------------------------------------------------------------------------
// Block 3: concat(x3_i(128), x3_j(128)) -> 128, lrelu, sum over k.
// One workgroup (128 threads) per point.
// ---------------------------------------------------------------------------
__launch_bounds__(128)
__global__ void block3_kernel(const float* __restrict__ x3, const int* __restrict__ knn,
                              const float* __restrict__ w, const float* __restrict__ bias,
                              float* __restrict__ x4) {
    const int bn = blockIdx.x;
    const int b  = bn >> 11;
    const int tid = threadIdx.x;   // 128
    __shared__ float s_ctr[128];
    __shared__ float s_nbr[16][128];
    __shared__ int   s_nb[16];
    if (tid < 16) s_nb[tid] = knn[(size_t)bn * KNB + tid];
    s_ctr[tid] = x3[(size_t)bn * 128 + tid];
    __syncthreads();
    for (int k = 0; k < 16; ++k)
        s_nbr[k][tid] = x3[((size_t)b * NPT + s_nb[k]) * 128 + tid];
    __syncthreads();

    float cp = 0.f;
#pragma unroll 4
    for (int i = 0; i < 128; ++i) cp = fmaf(s_ctr[i], w[i * 128 + tid], cp);
    float acc[16];
#pragma unroll
    for (int k = 0; k < 16; ++k) acc[k] = 0.f;
#pragma unroll 2
    for (int i = 0; i < 128; ++i) {
        float wv = w[(128 + i) * 128 + tid];
#pragma unroll
        for (int k = 0; k < 16; ++k) acc[k] = fmaf(s_nbr[k][i], wv, acc[k]);
    }
    const float bv = bias[tid];
    float s = 0.f;
#pragma unroll
    for (int k = 0; k < 16; ++k) s += lrelu(cp + acc[k] + bv);
    x4[(size_t)bn * 128 + tid] = s;
}

// ---------------------------------------------------------------------------
// Head: maxpool over N -> fc1 -> fc2 -> fc3. One block (128 thr) per batch.
// ---------------------------------------------------------------------------
__launch_bounds__(128)
__global__ void head_kernel(const float* __restrict__ x4,
                            const float* __restrict__ fc1w, const float* __restrict__ fc1b,
                            const float* __restrict__ fc2w, const float* __restrict__ fc2b,
                            const float* __restrict__ fc3w, const float* __restrict__ fc3b,
                            float* __restrict__ out) {
    const int b = blockIdx.x, t = threadIdx.x;
    __shared__ float s5[128], s6[128], s7[128];
    const float* xb = x4 + (size_t)b * NPT * 128;
    float m = -1e30f;
    for (int n = 0; n < NPT; ++n) m = fmaxf(m, xb[n * 128 + t]);
    s5[t] = m;
    __syncthreads();
    float a = fc1b[t];
#pragma unroll 4
    for (int i = 0; i < 128; ++i) a = fmaf(s5[i], fc1w[i * 128 + t], a);
    s6[t] = lrelu(a);
    __syncthreads();
    a = fc2b[t];
#pragma unroll 4
    for (int i = 0; i < 128; ++i) a = fmaf(s6[i], fc2w[i * 128 + t], a);
    s7[t] = lrelu(a);
    __syncthreads();
    float* ob = out + (size_t)b * 6144;
    for (int g = 0; g < 48; ++g) {
        const int o = g * 128 + t;
        float acc = fc3b[o];
#pragma unroll 4
        for (int i = 0; i < 128; ++i) acc = fmaf(s7[i], fc3w[i * 6144 + o], acc);
        ob[o] = acc;
    }
}

// ---------------------------------------------------------------------------
extern "C" void kernel_launch(void* const* d_in, const int* in_sizes, int n_in,
                              void* d_out, int out_size, void* d_ws, size_t ws_size,
                              hipStream_t stream) {
    const float* x    = (const float*)d_in[0];
    const float* h1w1 = (const float*)d_in[1];
    const float* h1b1 = (const float*)d_in[2];
    const float* h1w2 = (const float*)d_in[3];
    const float* h1b2 = (const float*)d_in[4];
    const float* h1w3 = (const float*)d_in[5];
    const float* h1b3 = (const float*)d_in[6];
    const float* h2w1 = (const float*)d_in[7];
    const float* h2b1 = (const float*)d_in[8];
    const float* h2w2 = (const float*)d_in[9];
    const float* h2b2 = (const float*)d_in[10];
    const float* h3w1 = (const float*)d_in[11];
    const float* h3b1 = (const float*)d_in[12];
    const float* fc1w = (const float*)d_in[13];
    const float* fc1b = (const float*)d_in[14];
    const float* fc2w = (const float*)d_in[15];
    const float* fc2b = (const float*)d_in[16];
    const float* fc3w = (const float*)d_in[17];
    const float* fc3b = (const float*)d_in[18];

    float* ws  = (float*)d_ws;
    float* x2  = ws;                      //  524288 floats
    float* x3  = ws + 524288;             // 2097152 floats
    float* x4  = ws + 2621440;            // 2097152 floats
    int*   idx = (int*)(ws + 4718592);    //  262144 ints
    float* nrm = ws + 4980736;            //   16384 floats  (~20 MB total)
    float* out = (float*)d_out;

    const dim3 kg(32, 8);

    norms_kernel<3><<<64, 256, 0, stream>>>(x, nrm);
    knn_kernel<3, 64><<<kg, 256, 0, stream>>>(x, nrm, idx);
    block1_kernel<<<1024, 256, 0, stream>>>(x, idx, h1w1, h1b1, h1w2, h1b2, h1w3, h1b3, x2);

    norms_kernel<32><<<64, 256, 0, stream>>>(x2, nrm);
    knn_kernel<32, 64><<<kg, 256, 0, stream>>>(x2, nrm, idx);
    block2_kernel<<<BSZ * NPT, 256, 0, stream>>>(x2, idx, h2w1, h2b1, h2w2, h2b2, x3);

    norms_kernel<128><<<64, 256, 0, stream>>>(x3, nrm);
    knn_kernel<128, 32><<<kg, 256, 0, stream>>>(x3, nrm, idx);
    block3_kernel<<<BSZ * NPT, 128, 0, stream>>>(x3, idx, h3w1, h3b1, x4);

    head_kernel<<<BSZ, 128, 0, stream>>>(x4, fc1w, fc1b, fc2w, fc2b, fc3w, fc3b, out);
}

// Round 2
// 2242.584 us; speedup vs baseline: 1.3613x; 1.3613x over previous
//
#include <hip/hip_runtime.h>

#define KNB 16
#define BSZ 8
#define NPT 2048

__device__ __forceinline__ float lrelu(float x) { return x >= 0.f ? x : 0.01f * x; }

// ---------------------------------------------------------------------------
// Per-point squared norms
// ---------------------------------------------------------------------------
template<int C>
__global__ void norms_kernel(const float* __restrict__ feat, float* __restrict__ out) {
    int gid = blockIdx.x * blockDim.x + threadIdx.x;
    if (gid < BSZ * NPT) {
        const float* p = feat + (size_t)gid * C;
        float s = 0.f;
#pragma unroll
        for (int c = 0; c < C; ++c) s = fmaf(p[c], p[c], s);
        out[gid] = s;
    }
}

// ---------------------------------------------------------------------------
// KNN: for each (b,i) find the 16 j minimizing |x_i - x_j|^2.
// score s(i,j) = |p_j|^2 - 2 q_i . p_j  (same ranking as d^2; |q|^2 constant).
// Block: 256 threads = 64 queries x 4 j-partitions. Query in registers,
// j-tiles staged in LDS (broadcast reads). Private top-16 per thread, merged
// through LDS into partition 0 at the end.
// ---------------------------------------------------------------------------
template<int C, int TJ>
__launch_bounds__(256)
__global__ void knn_kernel(const float* __restrict__ feat,
                           const float* __restrict__ norms,
                           int* __restrict__ knn_out) {
    constexpr int JPT = TJ / 4;   // j's per thread per tile
    constexpr int CP  = C + 4;    // row pad (keeps rows 16B aligned for C=32/128)
    const int b   = blockIdx.y;
    const int i0  = blockIdx.x * 64;
    const int tid = threadIdx.x;
    const int il  = tid & 63;     // local query index (lane)
    const int jg  = tid >> 6;     // j partition (wave-uniform)
    const float* fb = feat + (size_t)b * NPT * C;

    __shared__ float sP[TJ][CP];
    __shared__ float sPn[TJ];
    __shared__ float sMd[64][KNB + 1];
    __shared__ int   sMi[64][KNB + 1];

    // query into registers
    float q[C];
    {
        const float* qp = fb + (size_t)(i0 + il) * C;
#pragma unroll
        for (int c = 0; c < C; ++c) q[c] = qp[c];
    }

    float bd[KNB]; int bi[KNB];
#pragma unroll
    for (int t = 0; t < KNB; ++t) { bd[t] = 1e30f; bi[t] = 0; }
    float mx = 1e30f; int mp = 0;

    auto insert = [&](float d, int j) {
#pragma unroll
        for (int t = 0; t < KNB; ++t) if (t == mp) { bd[t] = d; bi[t] = j; }
        mx = -1e30f;
#pragma unroll
        for (int t = 0; t < KNB; ++t) if (bd[t] > mx) { mx = bd[t]; mp = t; }
    };

    for (int j0 = 0; j0 < NPT; j0 += TJ) {
        __syncthreads();   // previous tile fully consumed
        for (int t = tid; t < TJ * C; t += 256) {
            int r = t / C, c = t - r * C;
            sP[r][c] = fb[(size_t)j0 * C + t];   // == fb[(j0+r)*C + c]
        }
        if (tid < TJ) sPn[tid] = norms[b * NPT + j0 + tid];
        __syncthreads();
#pragma unroll 1
        for (int jj = 0; jj < JPT; ++jj) {
            const int jl = jg * JPT + jj;
            float dot = 0.f;
#pragma unroll
            for (int c = 0; c < C; ++c) dot = fmaf(q[c], sP[jl][c], dot);
            const float d = fmaf(-2.f, dot, sPn[jl]);
            if (d < mx) insert(d, j0 + jl);
        }
    }

    // merge partitions 1..3 into partition 0 (wave-uniform branches)
#pragma unroll 1
    for (int r = 1; r < 4; ++r) {
        __syncthreads();
        if (jg == r) {
#pragma unroll
            for (int t = 0; t < KNB; ++t) { sMd[il][t] = bd[t]; sMi[il][t] = bi[t]; }
        }
        __syncthreads();
        if (jg == 0) {
#pragma unroll 1
            for (int t = 0; t < KNB; ++t) {
                const float d = sMd[il][t];
                if (d < mx) insert(d, sMi[il][t]);
            }
        }
    }
    if (jg == 0) {
        int* o = knn_out + ((size_t)b * NPT + i0 + il) * KNB;
#pragma unroll
        for (int t = 0; t < KNB; ++t) o[t] = bi[t];
    }
}

// ---------------------------------------------------------------------------
// Block 1: concat(x_i(3), x_j(3)) -> 16 -> 64 -> 32, lrelu each, sum over k.
// Block: 256 threads = 16 points x 16 neighbors; weights in LDS (13 KB).
// ---------------------------------------------------------------------------
__launch_bounds__(256)
__global__ void block1_kernel(const float* __restrict__ x, const int* __restrict__ knn,
                              const float* __restrict__ w1, const float* __restrict__ b1,
                              const float* __restrict__ w2, const float* __restrict__ b2,
                              const float* __restrict__ w3, const float* __restrict__ b3,
                              float* __restrict__ x2out) {
    __shared__ float sw1[96], sb1[16], sw2[1024], sb2[64], sw3[2048], sb3[32];
    __shared__ float sh[16][16][32];
    const int tid = threadIdx.x;
    for (int t = tid; t < 96;  t += 256) sw1[t] = w1[t];
    if (tid < 16) sb1[tid] = b1[tid];
    for (int t = tid; t < 1024; t += 256) sw2[t] = w2[t];
    if (tid < 64) sb2[tid] = b2[tid];
    for (int t = tid; t < 2048; t += 256) sw3[t] = w3[t];
    if (tid < 32) sb3[tid] = b3[tid];
    __syncthreads();

    const int pt = tid >> 4, k = tid & 15;
    const int bn = blockIdx.x * 16 + pt;            // global point id
    const int b  = bn >> 11, n = bn & (NPT - 1);
    const float* xb = x + (size_t)b * NPT * 3;
    const int j = knn[(size_t)bn * KNB + k];

    float in6[6] = { xb[n*3+0], xb[n*3+1], xb[n*3+2],
                     xb[j*3+0], xb[j*3+1], xb[j*3+2] };
    float h1[16];
#pragma unroll
    for (int o = 0; o < 16; ++o) {
        float a = sb1[o];
#pragma unroll
        for (int i = 0; i < 6; ++i) a = fmaf(in6[i], sw1[i * 16 + o], a);
        h1[o] = lrelu(a);
    }
    float h2[64];
#pragma unroll
    for (int o = 0; o < 64; ++o) {
        float a = sb2[o];
#pragma unroll
        for (int i = 0; i < 16; ++i) a = fmaf(h1[i], sw2[i * 64 + o], a);
        h2[o] = lrelu(a);
    }
#pragma unroll
    for (int o = 0; o < 32; ++o) {
        float a = sb3[o];
#pragma unroll
        for (int i = 0; i < 64; ++i) a = fmaf(h2[i], sw3[i * 32 + o], a);
        sh[pt][k][o] = lrelu(a);
    }
    __syncthreads();
    for (int t = tid; t < 16 * 32; t += 256) {
        int p2 = t >> 5, o = t & 31;
        float s = 0.f;
#pragma unroll
        for (int kk = 0; kk < 16; ++kk) s += sh[p2][kk][o];
        x2out[(size_t)(blockIdx.x * 16 + p2) * 32 + o] = s;
    }
}

// ---------------------------------------------------------------------------
// Block 2: concat(x2_i(32), x2_j(32)) -> 256 -> 128, lrelu each, sum over k.
// One workgroup (256 threads) per point. Center contribution of layer 1 is
// shared across k. h1 staged in LDS [16][256].
// ---------------------------------------------------------------------------
__launch_bounds__(256)
__global__ void block2_kernel(const float* __restrict__ x2, const int* __restrict__ knn,
                              const float* __restrict__ w1, const float* __restrict__ b1,
                              const float* __restrict__ w2, const float* __restrict__ b2,
                              float* __restrict__ x3) {
    const int bn = blockIdx.x;
    const int b  = bn >> 11;
    const int tid = threadIdx.x;
    __shared__ float s_in[17][33];     // [0]=center, [1+k]=neighbor k (32 used)
    __shared__ float s_h1[16][256];
    __shared__ float s_part[256];
    __shared__ int   s_nb[16];
    if (tid < 16) s_nb[tid] = knn[(size_t)bn * KNB + tid];
    __syncthreads();
    for (int t = tid; t < 17 * 32; t += 256) {
        int r = t >> 5, c = t & 31;
        int src = (r == 0) ? bn : (b * NPT + s_nb[r - 1]);
        s_in[r][c] = x2[(size_t)src * 32 + c];
    }
    __syncthreads();

    // layer 1: thread tid owns output column tid (of 256)
    float cp = 0.f;
#pragma unroll 4
    for (int i = 0; i < 32; ++i) cp = fmaf(s_in[0][i], w1[i * 256 + tid], cp);
    float acc[16];
#pragma unroll
    for (int k = 0; k < 16; ++k) acc[k] = 0.f;
#pragma unroll 2
    for (int i = 0; i < 32; ++i) {
        float w = w1[(32 + i) * 256 + tid];
#pragma unroll
        for (int k = 0; k < 16; ++k) acc[k] = fmaf(s_in[1 + k][i], w, acc[k]);
    }
    float bb = b1[tid];
#pragma unroll
    for (int k = 0; k < 16; ++k) s_h1[k][tid] = lrelu(cp + acc[k] + bb);
    __syncthreads();

    // layer 2: thread tid -> column o = tid&127, k-half kh = tid>>7
    const int o = tid & 127, kh = tid >> 7;
    float a2[8];
#pragma unroll
    for (int k = 0; k < 8; ++k) a2[k] = 0.f;
#pragma unroll 4
    for (int i = 0; i < 256; ++i) {
        float w = w2[i * 128 + o];
#pragma unroll
        for (int k = 0; k < 8; ++k) a2[k] = fmaf(s_h1[kh * 8 + k][i], w, a2[k]);
    }
    float b2v = b2[o];
    float ps = 0.f;
#pragma unroll
    for (int k = 0; k < 8; ++k) ps += lrelu(a2[k] + b2v);
    s_part[tid] = ps;
    __syncthreads();
    if (tid < 128) x3[(size_t)bn * 128 + tid] = s_part[tid] + s_part[tid + 128];
}

// ---------------------------------------------------------------------------
// Block 3: concat(x3_i(128), x3_j(128)) -> 128, lrelu, sum over k.
// One workgroup (128 threads) per point.
// ---------------------------------------------------------------------------
__launch_bounds__(128)
__global__ void block3_kernel(const float* __restrict__ x3, const int* __restrict__ knn,
                              const float* __restrict__ w, const float* __restrict__ bias,
                              float* __restrict__ x4) {
    const int bn = blockIdx.x;
    const int b  = bn >> 11;
    const int tid = threadIdx.x;   // 128
    __shared__ float s_ctr[128];
    __shared__ float s_nbr[16][128];
    __shared__ int   s_nb[16];
    if (tid < 16) s_nb[tid] = knn[(size_t)bn * KNB + tid];
    s_ctr[tid] = x3[(size_t)bn * 128 + tid];
    __syncthreads();
    for (int k = 0; k < 16; ++k)
        s_nbr[k][tid] = x3[((size_t)b * NPT + s_nb[k]) * 128 + tid];
    __syncthreads();

    float cp = 0.f;
#pragma unroll 4
    for (int i = 0; i < 128; ++i) cp = fmaf(s_ctr[i], w[i * 128 + tid], cp);
    float acc[16];
#pragma unroll
    for (int k = 0; k < 16; ++k) acc[k] = 0.f;
#pragma unroll 2
    for (int i = 0; i < 128; ++i) {
        float wv = w[(128 + i) * 128 + tid];
#pragma unroll
        for (int k = 0; k < 16; ++k) acc[k] = fmaf(s_nbr[k][i], wv, acc[k]);
    }
    const float bv = bias[tid];
    float s = 0.f;
#pragma unroll
    for (int k = 0; k < 16; ++k) s += lrelu(cp + acc[k] + bv);
    x4[(size_t)bn * 128 + tid] = s;
}

// ---------------------------------------------------------------------------
// Maxpool stage 1: grid (chunk=16, b=8); each block maxes 128 points x 128 ch.
// Coalesced: thread t owns channel t.
// ---------------------------------------------------------------------------
__launch_bounds__(128)
__global__ void maxpool_partial_kernel(const float* __restrict__ x4,
                                       float* __restrict__ part) {
    const int chunk = blockIdx.x, b = blockIdx.y, t = threadIdx.x;
    const float* xb = x4 + ((size_t)b * NPT + (size_t)chunk * 128) * 128;
    float m = -1e30f;
#pragma unroll 8
    for (int n = 0; n < 128; ++n) m = fmaxf(m, xb[(size_t)n * 128 + t]);
    part[((size_t)b * 16 + chunk) * 128 + t] = m;
}

// ---------------------------------------------------------------------------
// Head stage 2: grid (g=48, b=8). Each block redundantly reduces the 16
// partial maxes + fc1 + fc2 (cheap, L2-resident weights), then computes its
// own 128-wide slice of fc3.
// ---------------------------------------------------------------------------
__launch_bounds__(128)
__global__ void head2_kernel(const float* __restrict__ part,
                             const float* __restrict__ fc1w, const float* __restrict__ fc1b,
                             const float* __restrict__ fc2w, const float* __restrict__ fc2b,
                             const float* __restrict__ fc3w, const float* __restrict__ fc3b,
                             float* __restrict__ out) {
    const int g = blockIdx.x, b = blockIdx.y, t = threadIdx.x;
    __shared__ float s5[128], s6[128], s7[128];
    float m = -1e30f;
#pragma unroll
    for (int c = 0; c < 16; ++c)
        m = fmaxf(m, part[((size_t)b * 16 + c) * 128 + t]);
    s5[t] = m;
    __syncthreads();
    float a = fc1b[t];
#pragma unroll 4
    for (int i = 0; i < 128; ++i) a = fmaf(s5[i], fc1w[i * 128 + t], a);
    s6[t] = lrelu(a);
    __syncthreads();
    a = fc2b[t];
#pragma unroll 4
    for (int i = 0; i < 128; ++i) a = fmaf(s6[i], fc2w[i * 128 + t], a);
    s7[t] = lrelu(a);
    __syncthreads();
    const int o = g * 128 + t;
    float acc = fc3b[o];
#pragma unroll 4
    for (int i = 0; i < 128; ++i) acc = fmaf(s7[i], fc3w[(size_t)i * 6144 + o], acc);
    out[(size_t)b * 6144 + o] = acc;
}

// ---------------------------------------------------------------------------
extern "C" void kernel_launch(void* const* d_in, const int* in_sizes, int n_in,
                              void* d_out, int out_size, void* d_ws, size_t ws_size,
                              hipStream_t stream) {
    const float* x    = (const float*)d_in[0];
    const float* h1w1 = (const float*)d_in[1];
    const float* h1b1 = (const float*)d_in[2];
    const float* h1w2 = (const float*)d_in[3];
    const float* h1b2 = (const float*)d_in[4];
    const float* h1w3 = (const float*)d_in[5];
    const float* h1b3 = (const float*)d_in[6];
    const float* h2w1 = (const float*)d_in[7];
    const float* h2b1 = (const float*)d_in[8];
    const float* h2w2 = (const float*)d_in[9];
    const float* h2b2 = (const float*)d_in[10];
    const float* h3w1 = (const float*)d_in[11];
    const float* h3b1 = (const float*)d_in[12];
    const float* fc1w = (const float*)d_in[13];
    const float* fc1b = (const float*)d_in[14];
    const float* fc2w = (const float*)d_in[15];
    const float* fc2b = (const float*)d_in[16];
    const float* fc3w = (const float*)d_in[17];
    const float* fc3b = (const float*)d_in[18];

    float* ws  = (float*)d_ws;
    float* x2  = ws;                      //  524288 floats
    float* x3  = ws + 524288;             // 2097152 floats
    float* x4  = ws + 2621440;            // 2097152 floats
    int*   idx = (int*)(ws + 4718592);    //  262144 ints
    float* nrm = ws + 4980736;            //   16384 floats
    float* part= ws + 4997120;            //   16384 floats  (~20 MB total)
    float* out = (float*)d_out;

    const dim3 kg(32, 8);

    norms_kernel<3><<<64, 256, 0, stream>>>(x, nrm);
    knn_kernel<3, 64><<<kg, 256, 0, stream>>>(x, nrm, idx);
    block1_kernel<<<1024, 256, 0, stream>>>(x, idx, h1w1, h1b1, h1w2, h1b2, h1w3, h1b3, x2);

    norms_kernel<32><<<64, 256, 0, stream>>>(x2, nrm);
    knn_kernel<32, 64><<<kg, 256, 0, stream>>>(x2, nrm, idx);
    block2_kernel<<<BSZ * NPT, 256, 0, stream>>>(x2, idx, h2w1, h2b1, h2w2, h2b2, x3);

    norms_kernel<128><<<64, 256, 0, stream>>>(x3, nrm);
    knn_kernel<128, 32><<<kg, 256, 0, stream>>>(x3, nrm, idx);
    block3_kernel<<<BSZ * NPT, 128, 0, stream>>>(x3, idx, h3w1, h3b1, x4);

    maxpool_partial_kernel<<<dim3(16, 8), 128, 0, stream>>>(x4, part);
    head2_kernel<<<dim3(48, 8), 128, 0, stream>>>(part, fc1w, fc1b, fc2w, fc2b,
                                                  fc3w, fc3b, out);
}

// Round 3
// 2014.566 us; speedup vs baseline: 1.5154x; 1.1132x over previous
//
#include <hip/hip_runtime.h>

#define KNB 16
#define BSZ 8
#define NPT 2048

__device__ __forceinline__ float lrelu(float x) { return x >= 0.f ? x : 0.01f * x; }

// ---------------------------------------------------------------------------
// Per-point squared norms
// ---------------------------------------------------------------------------
template<int C>
__global__ void norms_kernel(const float* __restrict__ feat, float* __restrict__ out) {
    int gid = blockIdx.x * blockDim.x + threadIdx.x;
    if (gid < BSZ * NPT) {
        const float* p = feat + (size_t)gid * C;
        float s = 0.f;
#pragma unroll
        for (int c = 0; c < C; ++c) s = fmaf(p[c], p[c], s);
        out[gid] = s;
    }
}

// ---------------------------------------------------------------------------
// KNN for tiny C (C=3): original structure. 64 queries x 4 j-partitions.
// ---------------------------------------------------------------------------
template<int C, int TJ>
__launch_bounds__(256)
__global__ void knn_kernel(const float* __restrict__ feat,
                           const float* __restrict__ norms,
                           int* __restrict__ knn_out) {
    constexpr int JPT = TJ / 4;
    constexpr int CP  = C + 4;
    const int b   = blockIdx.y;
    const int i0  = blockIdx.x * 64;
    const int tid = threadIdx.x;
    const int il  = tid & 63;
    const int jg  = tid >> 6;
    const float* fb = feat + (size_t)b * NPT * C;

    __shared__ float sP[TJ][CP];
    __shared__ float sPn[TJ];
    __shared__ float sMd[64][KNB + 1];
    __shared__ int   sMi[64][KNB + 1];

    float q[C];
    {
        const float* qp = fb + (size_t)(i0 + il) * C;
#pragma unroll
        for (int c = 0; c < C; ++c) q[c] = qp[c];
    }

    float bd[KNB]; int bi[KNB];
#pragma unroll
    for (int t = 0; t < KNB; ++t) { bd[t] = 1e30f; bi[t] = 0; }
    float mx = 1e30f; int mp = 0;

    auto insert = [&](float d, int j) {
#pragma unroll
        for (int t = 0; t < KNB; ++t) if (t == mp) { bd[t] = d; bi[t] = j; }
        mx = -1e30f;
#pragma unroll
        for (int t = 0; t < KNB; ++t) if (bd[t] > mx) { mx = bd[t]; mp = t; }
    };

    for (int j0 = 0; j0 < NPT; j0 += TJ) {
        __syncthreads();
        for (int t = tid; t < TJ * C; t += 256) {
            int r = t / C, c = t - r * C;
            sP[r][c] = fb[(size_t)j0 * C + t];
        }
        if (tid < TJ) sPn[tid] = norms[b * NPT + j0 + tid];
        __syncthreads();
#pragma unroll 1
        for (int jj = 0; jj < JPT; ++jj) {
            const int jl = jg * JPT + jj;
            float dot = 0.f;
#pragma unroll
            for (int c = 0; c < C; ++c) dot = fmaf(q[c], sP[jl][c], dot);
            const float d = fmaf(-2.f, dot, sPn[jl]);
            if (d < mx) insert(d, j0 + jl);
        }
    }

#pragma unroll 1
    for (int r = 1; r < 4; ++r) {
        __syncthreads();
        if (jg == r) {
#pragma unroll
            for (int t = 0; t < KNB; ++t) { sMd[il][t] = bd[t]; sMi[il][t] = bi[t]; }
        }
        __syncthreads();
        if (jg == 0) {
#pragma unroll 1
            for (int t = 0; t < KNB; ++t) {
                const float d = sMd[il][t];
                if (d < mx) insert(d, sMi[il][t]);
            }
        }
    }
    if (jg == 0) {
        int* o = knn_out + ((size_t)b * NPT + i0 + il) * KNB;
#pragma unroll
        for (int t = 0; t < KNB; ++t) o[t] = bi[t];
    }
}

// ---------------------------------------------------------------------------
// KNN for C in {32,128}: GEMM-structured scores + fused selection.
// Block = 64 queries. Per 64x64 j-tile: stage Q/P channel-chunks transposed
// ([c][row], pad 68 -> conflict-free float4 reads), each thread accumulates a
// 4x4 score sub-tile (16 FMA per 2 ds_read_b128). Tile round-trips through
// LDS so each thread's top-16 covers ONE query row (4 partitions per row),
// merged at the end. score = |p_j|^2 - 2 q.p (same ranking as d^2).
// ---------------------------------------------------------------------------
template<int C>
__launch_bounds__(256)
__global__ void knn_gemm_kernel(const float* __restrict__ feat,
                                const float* __restrict__ norms,
                                int* __restrict__ knn_out) {
    constexpr int KC = 32;                 // channel chunk
    const int b  = blockIdx.y;
    const int i0 = blockIdx.x * 64;
    const int t  = threadIdx.x;
    const int tr = t >> 4, tc = t & 15;    // 16x16 GEMM thread grid
    const int sr = t >> 2, lp = t & 3;     // selection row / partition
    const float* fb = feat + (size_t)b * NPT * C;

    __shared__ __align__(16) float sQ[KC][68];
    __shared__ __align__(16) float sP[KC][68];
    __shared__ __align__(16) float sS[64][68];
    __shared__ __align__(16) float sPn[64];
    // merge buffers alias sS (only used after the main loop, behind barriers)
    float (*sMd)[17] = (float (*)[17]) & sS[0][0];
    int   (*sMi)[17] = (int   (*)[17]) & sS[32][0];

    float bd[KNB]; int bi[KNB];
#pragma unroll
    for (int u = 0; u < KNB; ++u) { bd[u] = 1e30f; bi[u] = 0; }
    float mx = 1e30f; int mp = 0;

    auto insert = [&](float d, int j) {
#pragma unroll
        for (int u = 0; u < KNB; ++u) if (u == mp) { bd[u] = d; bi[u] = j; }
        mx = -1e30f;
#pragma unroll
        for (int u = 0; u < KNB; ++u) if (bd[u] > mx) { mx = bd[u]; mp = u; }
    };

#pragma unroll 1
    for (int j0 = 0; j0 < NPT; j0 += 64) {
        float acc[4][4] = {{0.f,0.f,0.f,0.f},{0.f,0.f,0.f,0.f},
                           {0.f,0.f,0.f,0.f},{0.f,0.f,0.f,0.f}};
#pragma unroll 1
        for (int c0 = 0; c0 < C; c0 += KC) {
            __syncthreads();   // prior tile's selection / prior chunk's compute done
            if (C > KC || j0 == 0) {
#pragma unroll
                for (int ii = 0; ii < 8; ++ii) {
                    const int idx = t + 256 * ii;       // 2048 = 32c x 64r
                    const int r = idx >> 5, c = idx & 31;
                    sQ[c][r] = fb[(size_t)(i0 + r) * C + (c0 + c)];
                }
            }
#pragma unroll
            for (int ii = 0; ii < 8; ++ii) {
                const int idx = t + 256 * ii;
                const int r = idx >> 5, c = idx & 31;
                sP[c][r] = fb[(size_t)(j0 + r) * C + (c0 + c)];
            }
            if (c0 == 0 && t < 64) sPn[t] = norms[b * NPT + j0 + t];
            __syncthreads();
#pragma unroll
            for (int c = 0; c < KC; ++c) {
                const float4 qv = *(const float4*)&sQ[c][tr * 4];
                const float4 pv = *(const float4*)&sP[c][tc * 4];
                acc[0][0] = fmaf(qv.x, pv.x, acc[0][0]);
                acc[0][1] = fmaf(qv.x, pv.y, acc[0][1]);
                acc[0][2] = fmaf(qv.x, pv.z, acc[0][2]);
                acc[0][3] = fmaf(qv.x, pv.w, acc[0][3]);
                acc[1][0] = fmaf(qv.y, pv.x, acc[1][0]);
                acc[1][1] = fmaf(qv.y, pv.y, acc[1][1]);
                acc[1][2] = fmaf(qv.y, pv.z, acc[1][2]);
                acc[1][3] = fmaf(qv.y, pv.w, acc[1][3]);
                acc[2][0] = fmaf(qv.z, pv.x, acc[2][0]);
                acc[2][1] = fmaf(qv.z, pv.y, acc[2][1]);
                acc[2][2] = fmaf(qv.z, pv.z, acc[2][2]);
                acc[2][3] = fmaf(qv.z, pv.w, acc[2][3]);
                acc[3][0] = fmaf(qv.w, pv.x, acc[3][0]);
                acc[3][1] = fmaf(qv.w, pv.y, acc[3][1]);
                acc[3][2] = fmaf(qv.w, pv.z, acc[3][2]);
                acc[3][3] = fmaf(qv.w, pv.w, acc[3][3]);
            }
        }
        // scores into sS: d = |p|^2 - 2*dot
        {
            const float4 pn = *(const float4*)&sPn[tc * 4];
#pragma unroll
            for (int a = 0; a < 4; ++a) {
                float4 sv;
                sv.x = fmaf(-2.f, acc[a][0], pn.x);
                sv.y = fmaf(-2.f, acc[a][1], pn.y);
                sv.z = fmaf(-2.f, acc[a][2], pn.z);
                sv.w = fmaf(-2.f, acc[a][3], pn.w);
                *(float4*)&sS[tr * 4 + a][tc * 4] = sv;
            }
        }
        __syncthreads();
        // selection: thread owns row sr, j's with j%4 == lp
#pragma unroll 1
        for (int jj = 0; jj < 16; ++jj) {
            const int jl = 4 * jj + lp;
            const float d = sS[sr][jl];
            if (d < mx) insert(d, j0 + jl);
        }
    }

    // merge partitions 1..3 into partition 0
#pragma unroll 1
    for (int r = 1; r < 4; ++r) {
        __syncthreads();
        if (lp == r) {
#pragma unroll
            for (int u = 0; u < KNB; ++u) { sMd[sr][u] = bd[u]; sMi[sr][u] = bi[u]; }
        }
        __syncthreads();
        if (lp == 0) {
#pragma unroll 1
            for (int u = 0; u < KNB; ++u) {
                const float d = sMd[sr][u];
                if (d < mx) insert(d, sMi[sr][u]);
            }
        }
    }
    if (lp == 0) {
        int* o = knn_out + ((size_t)b * NPT + i0 + sr) * KNB;
#pragma unroll
        for (int u = 0; u < KNB; ++u) o[u] = bi[u];
    }
}

// ---------------------------------------------------------------------------
// Block 1: concat(x_i(3), x_j(3)) -> 16 -> 64 -> 32, lrelu each, sum over k.
// ---------------------------------------------------------------------------
__launch_bounds__(256)
__global__ void block1_kernel(const float* __restrict__ x, const int* __restrict__ knn,
                              const float* __restrict__ w1, const float* __restrict__ b1,
                              const float* __restrict__ w2, const float* __restrict__ b2,
                              const float* __restrict__ w3, const float* __restrict__ b3,
                              float* __restrict__ x2out) {
    __shared__ float sw1[96], sb1[16], sw2[1024], sb2[64], sw3[2048], sb3[32];
    __shared__ float sh[16][16][32];
    const int tid = threadIdx.x;
    for (int t = tid; t < 96;  t += 256) sw1[t] = w1[t];
    if (tid < 16) sb1[tid] = b1[tid];
    for (int t = tid; t < 1024; t += 256) sw2[t] = w2[t];
    if (tid < 64) sb2[tid] = b2[tid];
    for (int t = tid; t < 2048; t += 256) sw3[t] = w3[t];
    if (tid < 32) sb3[tid] = b3[tid];
    __syncthreads();

    const int pt = tid >> 4, k = tid & 15;
    const int bn = blockIdx.x * 16 + pt;
    const int b  = bn >> 11, n = bn & (NPT - 1);
    const float* xb = x + (size_t)b * NPT * 3;
    const int j = knn[(size_t)bn * KNB + k];

    float in6[6] = { xb[n*3+0], xb[n*3+1], xb[n*3+2],
                     xb[j*3+0], xb[j*3+1], xb[j*3+2] };
    float h1[16];
#pragma unroll
    for (int o = 0; o < 16; ++o) {
        float a = sb1[o];
#pragma unroll
        for (int i = 0; i < 6; ++i) a = fmaf(in6[i], sw1[i * 16 + o], a);
        h1[o] = lrelu(a);
    }
    float h2[64];
#pragma unroll
    for (int o = 0; o < 64; ++o) {
        float a = sb2[o];
#pragma unroll
        for (int i = 0; i < 16; ++i) a = fmaf(h1[i], sw2[i * 64 + o], a);
        h2[o] = lrelu(a);
    }
#pragma unroll
    for (int o = 0; o < 32; ++o) {
        float a = sb3[o];
#pragma unroll
        for (int i = 0; i < 64; ++i) a = fmaf(h2[i], sw3[i * 32 + o], a);
        sh[pt][k][o] = lrelu(a);
    }
    __syncthreads();
    for (int t = tid; t < 16 * 32; t += 256) {
        int p2 = t >> 5, o = t & 31;
        float s = 0.f;
#pragma unroll
        for (int kk = 0; kk < 16; ++kk) s += sh[p2][kk][o];
        x2out[(size_t)(blockIdx.x * 16 + p2) * 32 + o] = s;
    }
}

// ---------------------------------------------------------------------------
// Block 2: concat(x2_i(32), x2_j(32)) -> 256 -> 128, lrelu each, sum over k.
// ---------------------------------------------------------------------------
__launch_bounds__(256)
__global__ void block2_kernel(const float* __restrict__ x2, const int* __restrict__ knn,
                              const float* __restrict__ w1, const float* __restrict__ b1,
                              const float* __restrict__ w2, const float* __restrict__ b2,
                              float* __restrict__ x3) {
    const int bn = blockIdx.x;
    const int b  = bn >> 11;
    const int tid = threadIdx.x;
    __shared__ float s_in[17][33];
    __shared__ float s_h1[16][256];
    __shared__ float s_part[256];
    __shared__ int   s_nb[16];
    if (tid < 16) s_nb[tid] = knn[(size_t)bn * KNB + tid];
    __syncthreads();
    for (int t = tid; t < 17 * 32; t += 256) {
        int r = t >> 5, c = t & 31;
        int src = (r == 0) ? bn : (b * NPT + s_nb[r - 1]);
        s_in[r][c] = x2[(size_t)src * 32 + c];
    }
    __syncthreads();

    float cp = 0.f;
#pragma unroll 4
    for (int i = 0; i < 32; ++i) cp = fmaf(s_in[0][i], w1[i * 256 + tid], cp);
    float acc[16];
#pragma unroll
    for (int k = 0; k < 16; ++k) acc[k] = 0.f;
#pragma unroll 2
    for (int i = 0; i < 32; ++i) {
        float w = w1[(32 + i) * 256 + tid];
#pragma unroll
        for (int k = 0; k < 16; ++k) acc[k] = fmaf(s_in[1 + k][i], w, acc[k]);
    }
    float bb = b1[tid];
#pragma unroll
    for (int k = 0; k < 16; ++k) s_h1[k][tid] = lrelu(cp + acc[k] + bb);
    __syncthreads();

    const int o = tid & 127, kh = tid >> 7;
    float a2[8];
#pragma unroll
    for (int k = 0; k < 8; ++k) a2[k] = 0.f;
#pragma unroll 4
    for (int i = 0; i < 256; ++i) {
        float w = w2[i * 128 + o];
#pragma unroll
        for (int k = 0; k < 8; ++k) a2[k] = fmaf(s_h1[kh * 8 + k][i], w, a2[k]);
    }
    float b2v = b2[o];
    float ps = 0.f;
#pragma unroll
    for (int k = 0; k < 8; ++k) ps += lrelu(a2[k] + b2v);
    s_part[tid] = ps;
    __syncthreads();
    if (tid < 128) x3[(size_t)bn * 128 + tid] = s_part[tid] + s_part[tid + 128];
}

// ---------------------------------------------------------------------------
// Block 3: concat(x3_i(128), x3_j(128)) -> 128, lrelu, sum over k.
// ---------------------------------------------------------------------------
__launch_bounds__(128)
__global__ void block3_kernel(const float* __restrict__ x3, const int* __restrict__ knn,
                              const float* __restrict__ w, const float* __restrict__ bias,
                              float* __restrict__ x4) {
    const int bn = blockIdx.x;
    const int b  = bn >> 11;
    const int tid = threadIdx.x;
    __shared__ float s_ctr[128];
    __shared__ float s_nbr[16][128];
    __shared__ int   s_nb[16];
    if (tid < 16) s_nb[tid] = knn[(size_t)bn * KNB + tid];
    s_ctr[tid] = x3[(size_t)bn * 128 + tid];
    __syncthreads();
    for (int k = 0; k < 16; ++k)
        s_nbr[k][tid] = x3[((size_t)b * NPT + s_nb[k]) * 128 + tid];
    __syncthreads();

    float cp = 0.f;
#pragma unroll 4
    for (int i = 0; i < 128; ++i) cp = fmaf(s_ctr[i], w[i * 128 + tid], cp);
    float acc[16];
#pragma unroll
    for (int k = 0; k < 16; ++k) acc[k] = 0.f;
#pragma unroll 2
    for (int i = 0; i < 128; ++i) {
        float wv = w[(128 + i) * 128 + tid];
#pragma unroll
        for (int k = 0; k < 16; ++k) acc[k] = fmaf(s_nbr[k][i], wv, acc[k]);
    }
    const float bv = bias[tid];
    float s = 0.f;
#pragma unroll
    for (int k = 0; k < 16; ++k) s += lrelu(cp + acc[k] + bv);
    x4[(size_t)bn * 128 + tid] = s;
}

// ---------------------------------------------------------------------------
// Maxpool stage 1
// ---------------------------------------------------------------------------
__launch_bounds__(128)
__global__ void maxpool_partial_kernel(const float* __restrict__ x4,
                                       float* __restrict__ part) {
    const int chunk = blockIdx.x, b = blockIdx.y, t = threadIdx.x;
    const float* xb = x4 + ((size_t)b * NPT + (size_t)chunk * 128) * 128;
    float m = -1e30f;
#pragma unroll 8
    for (int n = 0; n < 128; ++n) m = fmaxf(m, xb[(size_t)n * 128 + t]);
    part[((size_t)b * 16 + chunk) * 128 + t] = m;
}

// ---------------------------------------------------------------------------
// Head stage 2
// ---------------------------------------------------------------------------
__launch_bounds__(128)
__global__ void head2_kernel(const float* __restrict__ part,
                             const float* __restrict__ fc1w, const float* __restrict__ fc1b,
                             const float* __restrict__ fc2w, const float* __restrict__ fc2b,
                             const float* __restrict__ fc3w, const float* __restrict__ fc3b,
                             float* __restrict__ out) {
    const int g = blockIdx.x, b = blockIdx.y, t = threadIdx.x;
    __shared__ float s5[128], s6[128], s7[128];
    float m = -1e30f;
#pragma unroll
    for (int c = 0; c < 16; ++c)
        m = fmaxf(m, part[((size_t)b * 16 + c) * 128 + t]);
    s5[t] = m;
    __syncthreads();
    float a = fc1b[t];
#pragma unroll 4
    for (int i = 0; i < 128; ++i) a = fmaf(s5[i], fc1w[i * 128 + t], a);
    s6[t] = lrelu(a);
    __syncthreads();
    a = fc2b[t];
#pragma unroll 4
    for (int i = 0; i < 128; ++i) a = fmaf(s6[i], fc2w[i * 128 + t], a);
    s7[t] = lrelu(a);
    __syncthreads();
    const int o = g * 128 + t;
    float acc = fc3b[o];
#pragma unroll 4
    for (int i = 0; i < 128; ++i) acc = fmaf(s7[i], fc3w[(size_t)i * 6144 + o], acc);
    out[(size_t)b * 6144 + o] = acc;
}

// ---------------------------------------------------------------------------
extern "C" void kernel_launch(void* const* d_in, const int* in_sizes, int n_in,
                              void* d_out, int out_size, void* d_ws, size_t ws_size,
                              hipStream_t stream) {
    const float* x    = (const float*)d_in[0];
    const float* h1w1 = (const float*)d_in[1];
    const float* h1b1 = (const float*)d_in[2];
    const float* h1w2 = (const float*)d_in[3];
    const float* h1b2 = (const float*)d_in[4];
    const float* h1w3 = (const float*)d_in[5];
    const float* h1b3 = (const float*)d_in[6];
    const float* h2w1 = (const float*)d_in[7];
    const float* h2b1 = (const float*)d_in[8];
    const float* h2w2 = (const float*)d_in[9];
    const float* h2b2 = (const float*)d_in[10];
    const float* h3w1 = (const float*)d_in[11];
    const float* h3b1 = (const float*)d_in[12];
    const float* fc1w = (const float*)d_in[13];
    const float* fc1b = (const float*)d_in[14];
    const float* fc2w = (const float*)d_in[15];
    const float* fc2b = (const float*)d_in[16];
    const float* fc3w = (const float*)d_in[17];
    const float* fc3b = (const float*)d_in[18];

    float* ws  = (float*)d_ws;
    float* x2  = ws;                      //  524288 floats
    float* x3  = ws + 524288;             // 2097152 floats
    float* x4  = ws + 2621440;            // 2097152 floats
    int*   idx = (int*)(ws + 4718592);    //  262144 ints
    float* nrm = ws + 4980736;            //   16384 floats
    float* part= ws + 4997120;            //   16384 floats  (~20 MB total)
    float* out = (float*)d_out;

    const dim3 kg(32, 8);

    norms_kernel<3><<<64, 256, 0, stream>>>(x, nrm);
    knn_kernel<3, 64><<<kg, 256, 0, stream>>>(x, nrm, idx);
    block1_kernel<<<1024, 256, 0, stream>>>(x, idx, h1w1, h1b1, h1w2, h1b2, h1w3, h1b3, x2);

    norms_kernel<32><<<64, 256, 0, stream>>>(x2, nrm);
    knn_gemm_kernel<32><<<kg, 256, 0, stream>>>(x2, nrm, idx);
    block2_kernel<<<BSZ * NPT, 256, 0, stream>>>(x2, idx, h2w1, h2b1, h2w2, h2b2, x3);

    norms_kernel<128><<<64, 256, 0, stream>>>(x3, nrm);
    knn_gemm_kernel<128><<<kg, 256, 0, stream>>>(x3, nrm, idx);
    block3_kernel<<<BSZ * NPT, 128, 0, stream>>>(x3, idx, h3w1, h3b1, x4);

    maxpool_partial_kernel<<<dim3(16, 8), 128, 0, stream>>>(x4, part);
    head2_kernel<<<dim3(48, 8), 128, 0, stream>>>(part, fc1w, fc1b, fc2w, fc2b,
                                                  fc3w, fc3b, out);
}

// Round 4
// 1902.058 us; speedup vs baseline: 1.6051x; 1.0592x over previous
//
#include <hip/hip_runtime.h>

#define KNB 16
#define BSZ 8
#define NPT 2048

__device__ __forceinline__ float lrelu(float x) { return x >= 0.f ? x : 0.01f * x; }

// ---------------------------------------------------------------------------
// Per-point squared norms
// ---------------------------------------------------------------------------
template<int C>
__global__ void norms_kernel(const float* __restrict__ feat, float* __restrict__ out) {
    int gid = blockIdx.x * blockDim.x + threadIdx.x;
    if (gid < BSZ * NPT) {
        const float* p = feat + (size_t)gid * C;
        float s = 0.f;
#pragma unroll
        for (int c = 0; c < C; ++c) s = fmaf(p[c], p[c], s);
        out[gid] = s;
    }
}

// ---------------------------------------------------------------------------
// KNN for tiny C (C=3), j-split JS ways. Block (qtile, js, b): 64 queries x
// JL=NPT/JS candidates. Emits provisional top-16 (dist+idx) per query to the
// candidate buffer; knn_merge_kernel reduces JS lists -> final 16.
// ---------------------------------------------------------------------------
template<int C, int TJ, int JS>
__launch_bounds__(256)
__global__ void knn_kernel(const float* __restrict__ feat,
                           const float* __restrict__ norms,
                           float* __restrict__ cand_d,
                           int* __restrict__ cand_i) {
    constexpr int JL  = NPT / JS;
    constexpr int JPT = TJ / 4;
    constexpr int CP  = C + 4;
    const int b   = blockIdx.z;
    const int js  = blockIdx.y;
    const int i0  = blockIdx.x * 64;
    const int tid = threadIdx.x;
    const int il  = tid & 63;
    const int jg  = tid >> 6;
    const float* fb = feat + (size_t)b * NPT * C;

    __shared__ float sP[TJ][CP];
    __shared__ float sPn[TJ];
    __shared__ float sMd[64][KNB + 1];
    __shared__ int   sMi[64][KNB + 1];

    float q[C];
    {
        const float* qp = fb + (size_t)(i0 + il) * C;
#pragma unroll
        for (int c = 0; c < C; ++c) q[c] = qp[c];
    }

    float bd[KNB]; int bi[KNB];
#pragma unroll
    for (int t = 0; t < KNB; ++t) { bd[t] = 1e30f; bi[t] = 0; }
    float mx = 1e30f; int mp = 0;

    auto insert = [&](float d, int j) {
#pragma unroll
        for (int t = 0; t < KNB; ++t) if (t == mp) { bd[t] = d; bi[t] = j; }
        mx = -1e30f;
#pragma unroll
        for (int t = 0; t < KNB; ++t) if (bd[t] > mx) { mx = bd[t]; mp = t; }
    };

    for (int j0 = js * JL; j0 < (js + 1) * JL; j0 += TJ) {
        __syncthreads();
        for (int t = tid; t < TJ * C; t += 256) {
            int r = t / C, c = t - r * C;
            sP[r][c] = fb[(size_t)j0 * C + t];
        }
        if (tid < TJ) sPn[tid] = norms[b * NPT + j0 + tid];
        __syncthreads();
#pragma unroll 1
        for (int jj = 0; jj < JPT; ++jj) {
            const int jl = jg * JPT + jj;
            float dot = 0.f;
#pragma unroll
            for (int c = 0; c < C; ++c) dot = fmaf(q[c], sP[jl][c], dot);
            const float d = fmaf(-2.f, dot, sPn[jl]);
            if (d < mx) insert(d, j0 + jl);
        }
    }

#pragma unroll 1
    for (int r = 1; r < 4; ++r) {
        __syncthreads();
        if (jg == r) {
#pragma unroll
            for (int t = 0; t < KNB; ++t) { sMd[il][t] = bd[t]; sMi[il][t] = bi[t]; }
        }
        __syncthreads();
        if (jg == 0) {
#pragma unroll 1
            for (int t = 0; t < KNB; ++t) {
                const float d = sMd[il][t];
                if (d < mx) insert(d, sMi[il][t]);
            }
        }
    }
    if (jg == 0) {
        const size_t base = (((size_t)b * NPT + i0 + il) * JS + js) * KNB;
#pragma unroll
        for (int t = 0; t < KNB; ++t) { cand_d[base + t] = bd[t]; cand_i[base + t] = bi[t]; }
    }
}

// ---------------------------------------------------------------------------
// KNN for C in {32,128}, GEMM-structured, j-split JS ways.
// Block (qtile, js, b) = 64 queries x JL=NPT/JS candidates. Per 64x64 j-tile:
// stage Q/P channel-chunks transposed in LDS, each thread accumulates a 4x4
// score sub-tile, round-trip through LDS, 4-partition selection per query.
// Emits provisional top-16 (dist+idx) to the candidate buffer.
// ---------------------------------------------------------------------------
template<int C, int JS>
__launch_bounds__(256)
__global__ void knn_gemm_kernel(const float* __restrict__ feat,
                                const float* __restrict__ norms,
                                float* __restrict__ cand_d,
                                int* __restrict__ cand_i) {
    constexpr int KC = 32;
    constexpr int JL = NPT / JS;
    const int b  = blockIdx.z;
    const int js = blockIdx.y;
    const int i0 = blockIdx.x * 64;
    const int t  = threadIdx.x;
    const int tr = t >> 4, tc = t & 15;
    const int sr = t >> 2, lp = t & 3;
    const float* fb = feat + (size_t)b * NPT * C;

    __shared__ __align__(16) float sQ[KC][68];
    __shared__ __align__(16) float sP[KC][68];
    __shared__ __align__(16) float sS[64][68];
    __shared__ __align__(16) float sPn[64];
    float (*sMd)[17] = (float (*)[17]) & sS[0][0];
    int   (*sMi)[17] = (int   (*)[17]) & sS[32][0];

    float bd[KNB]; int bi[KNB];
#pragma unroll
    for (int u = 0; u < KNB; ++u) { bd[u] = 1e30f; bi[u] = 0; }
    float mx = 1e30f; int mp = 0;

    auto insert = [&](float d, int j) {
#pragma unroll
        for (int u = 0; u < KNB; ++u) if (u == mp) { bd[u] = d; bi[u] = j; }
        mx = -1e30f;
#pragma unroll
        for (int u = 0; u < KNB; ++u) if (bd[u] > mx) { mx = bd[u]; mp = u; }
    };

    const int jend = (js + 1) * JL;
#pragma unroll 1
    for (int j0 = js * JL; j0 < jend; j0 += 64) {
        float acc[4][4] = {{0.f,0.f,0.f,0.f},{0.f,0.f,0.f,0.f},
                           {0.f,0.f,0.f,0.f},{0.f,0.f,0.f,0.f}};
#pragma unroll 1
        for (int c0 = 0; c0 < C; c0 += KC) {
            __syncthreads();
            if (C > KC || j0 == js * JL) {
#pragma unroll
                for (int ii = 0; ii < 8; ++ii) {
                    const int idx = t + 256 * ii;
                    const int r = idx >> 5, c = idx & 31;
                    sQ[c][r] = fb[(size_t)(i0 + r) * C + (c0 + c)];
                }
            }
#pragma unroll
            for (int ii = 0; ii < 8; ++ii) {
                const int idx = t + 256 * ii;
                const int r = idx >> 5, c = idx & 31;
                sP[c][r] = fb[(size_t)(j0 + r) * C + (c0 + c)];
            }
            if (c0 == 0 && t < 64) sPn[t] = norms[b * NPT + j0 + t];
            __syncthreads();
#pragma unroll
            for (int c = 0; c < KC; ++c) {
                const float4 qv = *(const float4*)&sQ[c][tr * 4];
                const float4 pv = *(const float4*)&sP[c][tc * 4];
                acc[0][0] = fmaf(qv.x, pv.x, acc[0][0]);
                acc[0][1] = fmaf(qv.x, pv.y, acc[0][1]);
                acc[0][2] = fmaf(qv.x, pv.z, acc[0][2]);
                acc[0][3] = fmaf(qv.x, pv.w, acc[0][3]);
                acc[1][0] = fmaf(qv.y, pv.x, acc[1][0]);
                acc[1][1] = fmaf(qv.y, pv.y, acc[1][1]);
                acc[1][2] = fmaf(qv.y, pv.z, acc[1][2]);
                acc[1][3] = fmaf(qv.y, pv.w, acc[1][3]);
                acc[2][0] = fmaf(qv.z, pv.x, acc[2][0]);
                acc[2][1] = fmaf(qv.z, pv.y, acc[2][1]);
                acc[2][2] = fmaf(qv.z, pv.z, acc[2][2]);
                acc[2][3] = fmaf(qv.z, pv.w, acc[2][3]);
                acc[3][0] = fmaf(qv.w, pv.x, acc[3][0]);
                acc[3][1] = fmaf(qv.w, pv.y, acc[3][1]);
                acc[3][2] = fmaf(qv.w, pv.z, acc[3][2]);
                acc[3][3] = fmaf(qv.w, pv.w, acc[3][3]);
            }
        }
        {
            const float4 pn = *(const float4*)&sPn[tc * 4];
#pragma unroll
            for (int a = 0; a < 4; ++a) {
                float4 sv;
                sv.x = fmaf(-2.f, acc[a][0], pn.x);
                sv.y = fmaf(-2.f, acc[a][1], pn.y);
                sv.z = fmaf(-2.f, acc[a][2], pn.z);
                sv.w = fmaf(-2.f, acc[a][3], pn.w);
                *(float4*)&sS[tr * 4 + a][tc * 4] = sv;
            }
        }
        __syncthreads();
#pragma unroll 1
        for (int jj = 0; jj < 16; ++jj) {
            const int jl = 4 * jj + lp;
            const float d = sS[sr][jl];
            if (d < mx) insert(d, j0 + jl);
        }
    }

#pragma unroll 1
    for (int r = 1; r < 4; ++r) {
        __syncthreads();
        if (lp == r) {
#pragma unroll
            for (int u = 0; u < KNB; ++u) { sMd[sr][u] = bd[u]; sMi[sr][u] = bi[u]; }
        }
        __syncthreads();
        if (lp == 0) {
#pragma unroll 1
            for (int u = 0; u < KNB; ++u) {
                const float d = sMd[sr][u];
                if (d < mx) insert(d, sMi[sr][u]);
            }
        }
    }
    if (lp == 0) {
        const size_t base = (((size_t)b * NPT + i0 + sr) * JS + js) * KNB;
#pragma unroll
        for (int u = 0; u < KNB; ++u) { cand_d[base + u] = bd[u]; cand_i[base + u] = bi[u]; }
    }
}

// ---------------------------------------------------------------------------
// Merge JS provisional top-16 lists per query -> final top-16 indices.
// One thread per query.
// ---------------------------------------------------------------------------
template<int JS>
__launch_bounds__(256)
__global__ void knn_merge_kernel(const float* __restrict__ cand_d,
                                 const int* __restrict__ cand_i,
                                 int* __restrict__ knn_out) {
    const int q = blockIdx.x * 256 + threadIdx.x;
    float bd[KNB]; int bi[KNB];
#pragma unroll
    for (int u = 0; u < KNB; ++u) { bd[u] = 1e30f; bi[u] = 0; }
    float mx = 1e30f; int mp = 0;

    auto insert = [&](float d, int j) {
#pragma unroll
        for (int u = 0; u < KNB; ++u) if (u == mp) { bd[u] = d; bi[u] = j; }
        mx = -1e30f;
#pragma unroll
        for (int u = 0; u < KNB; ++u) if (bd[u] > mx) { mx = bd[u]; mp = u; }
    };

    const float* pd = cand_d + (size_t)q * JS * KNB;
    const int*   pi = cand_i + (size_t)q * JS * KNB;
#pragma unroll 1
    for (int u = 0; u < JS * KNB; ++u) {
        const float d = pd[u];
        if (d < mx) insert(d, pi[u]);
    }
    int* o = knn_out + (size_t)q * KNB;
#pragma unroll
    for (int u = 0; u < KNB; ++u) o[u] = bi[u];
}

// ---------------------------------------------------------------------------
// Block 1: concat(x_i(3), x_j(3)) -> 16 -> 64 -> 32, lrelu each, sum over k.
// ---------------------------------------------------------------------------
__launch_bounds__(256)
__global__ void block1_kernel(const float* __restrict__ x, const int* __restrict__ knn,
                              const float* __restrict__ w1, const float* __restrict__ b1,
                              const float* __restrict__ w2, const float* __restrict__ b2,
                              const float* __restrict__ w3, const float* __restrict__ b3,
                              float* __restrict__ x2out) {
    __shared__ float sw1[96], sb1[16], sw2[1024], sb2[64], sw3[2048], sb3[32];
    __shared__ float sh[16][16][32];
    const int tid = threadIdx.x;
    for (int t = tid; t < 96;  t += 256) sw1[t] = w1[t];
    if (tid < 16) sb1[tid] = b1[tid];
    for (int t = tid; t < 1024; t += 256) sw2[t] = w2[t];
    if (tid < 64) sb2[tid] = b2[tid];
    for (int t = tid; t < 2048; t += 256) sw3[t] = w3[t];
    if (tid < 32) sb3[tid] = b3[tid];
    __syncthreads();

    const int pt = tid >> 4, k = tid & 15;
    const int bn = blockIdx.x * 16 + pt;
    const int b  = bn >> 11, n = bn & (NPT - 1);
    const float* xb = x + (size_t)b * NPT * 3;
    const int j = knn[(size_t)bn * KNB + k];

    float in6[6] = { xb[n*3+0], xb[n*3+1], xb[n*3+2],
                     xb[j*3+0], xb[j*3+1], xb[j*3+2] };
    float h1[16];
#pragma unroll
    for (int o = 0; o < 16; ++o) {
        float a = sb1[o];
#pragma unroll
        for (int i = 0; i < 6; ++i) a = fmaf(in6[i], sw1[i * 16 + o], a);
        h1[o] = lrelu(a);
    }
    float h2[64];
#pragma unroll
    for (int o = 0; o < 64; ++o) {
        float a = sb2[o];
#pragma unroll
        for (int i = 0; i < 16; ++i) a = fmaf(h1[i], sw2[i * 64 + o], a);
        h2[o] = lrelu(a);
    }
#pragma unroll
    for (int o = 0; o < 32; ++o) {
        float a = sb3[o];
#pragma unroll
        for (int i = 0; i < 64; ++i) a = fmaf(h2[i], sw3[i * 32 + o], a);
        sh[pt][k][o] = lrelu(a);
    }
    __syncthreads();
    for (int t = tid; t < 16 * 32; t += 256) {
        int p2 = t >> 5, o = t & 31;
        float s = 0.f;
#pragma unroll
        for (int kk = 0; kk < 16; ++kk) s += sh[p2][kk][o];
        x2out[(size_t)(blockIdx.x * 16 + p2) * 32 + o] = s;
    }
}

// ---------------------------------------------------------------------------
// Block 2: concat(x2_i(32), x2_j(32)) -> 256 -> 128, lrelu each, sum over k.
// ---------------------------------------------------------------------------
__launch_bounds__(256)
__global__ void block2_kernel(const float* __restrict__ x2, const int* __restrict__ knn,
                              const float* __restrict__ w1, const float* __restrict__ b1,
                              const float* __restrict__ w2, const float* __restrict__ b2,
                              float* __restrict__ x3) {
    const int bn = blockIdx.x;
    const int b  = bn >> 11;
    const int tid = threadIdx.x;
    __shared__ float s_in[17][33];
    __shared__ float s_h1[16][256];
    __shared__ float s_part[256];
    __shared__ int   s_nb[16];
    if (tid < 16) s_nb[tid] = knn[(size_t)bn * KNB + tid];
    __syncthreads();
    for (int t = tid; t < 17 * 32; t += 256) {
        int r = t >> 5, c = t & 31;
        int src = (r == 0) ? bn : (b * NPT + s_nb[r - 1]);
        s_in[r][c] = x2[(size_t)src * 32 + c];
    }
    __syncthreads();

    float cp = 0.f;
#pragma unroll 4
    for (int i = 0; i < 32; ++i) cp = fmaf(s_in[0][i], w1[i * 256 + tid], cp);
    float acc[16];
#pragma unroll
    for (int k = 0; k < 16; ++k) acc[k] = 0.f;
#pragma unroll 2
    for (int i = 0; i < 32; ++i) {
        float w = w1[(32 + i) * 256 + tid];
#pragma unroll
        for (int k = 0; k < 16; ++k) acc[k] = fmaf(s_in[1 + k][i], w, acc[k]);
    }
    float bb = b1[tid];
#pragma unroll
    for (int k = 0; k < 16; ++k) s_h1[k][tid] = lrelu(cp + acc[k] + bb);
    __syncthreads();

    const int o = tid & 127, kh = tid >> 7;
    float a2[8];
#pragma unroll
    for (int k = 0; k < 8; ++k) a2[k] = 0.f;
#pragma unroll 4
    for (int i = 0; i < 256; ++i) {
        float w = w2[i * 128 + o];
#pragma unroll
        for (int k = 0; k < 8; ++k) a2[k] = fmaf(s_h1[kh * 8 + k][i], w, a2[k]);
    }
    float b2v = b2[o];
    float ps = 0.f;
#pragma unroll
    for (int k = 0; k < 8; ++k) ps += lrelu(a2[k] + b2v);
    s_part[tid] = ps;
    __syncthreads();
    if (tid < 128) x3[(size_t)bn * 128 + tid] = s_part[tid] + s_part[tid + 128];
}

// ---------------------------------------------------------------------------
// Block 3: concat(x3_i(128), x3_j(128)) -> 128, lrelu, sum over k.
// ---------------------------------------------------------------------------
__launch_bounds__(128)
__global__ void block3_kernel(const float* __restrict__ x3, const int* __restrict__ knn,
                              const float* __restrict__ w, const float* __restrict__ bias,
                              float* __restrict__ x4) {
    const int bn = blockIdx.x;
    const int b  = bn >> 11;
    const int tid = threadIdx.x;
    __shared__ float s_ctr[128];
    __shared__ float s_nbr[16][128];
    __shared__ int   s_nb[16];
    if (tid < 16) s_nb[tid] = knn[(size_t)bn * KNB + tid];
    s_ctr[tid] = x3[(size_t)bn * 128 + tid];
    __syncthreads();
    for (int k = 0; k < 16; ++k)
        s_nbr[k][tid] = x3[((size_t)b * NPT + s_nb[k]) * 128 + tid];
    __syncthreads();

    float cp = 0.f;
#pragma unroll 4
    for (int i = 0; i < 128; ++i) cp = fmaf(s_ctr[i], w[i * 128 + tid], cp);
    float acc[16];
#pragma unroll
    for (int k = 0; k < 16; ++k) acc[k] = 0.f;
#pragma unroll 2
    for (int i = 0; i < 128; ++i) {
        float wv = w[(128 + i) * 128 + tid];
#pragma unroll
        for (int k = 0; k < 16; ++k) acc[k] = fmaf(s_nbr[k][i], wv, acc[k]);
    }
    const float bv = bias[tid];
    float s = 0.f;
#pragma unroll
    for (int k = 0; k < 16; ++k) s += lrelu(cp + acc[k] + bv);
    x4[(size_t)bn * 128 + tid] = s;
}

// ---------------------------------------------------------------------------
// Maxpool stage 1
// ---------------------------------------------------------------------------
__launch_bounds__(128)
__global__ void maxpool_partial_kernel(const float* __restrict__ x4,
                                       float* __restrict__ part) {
    const int chunk = blockIdx.x, b = blockIdx.y, t = threadIdx.x;
    const float* xb = x4 + ((size_t)b * NPT + (size_t)chunk * 128) * 128;
    float m = -1e30f;
#pragma unroll 8
    for (int n = 0; n < 128; ++n) m = fmaxf(m, xb[(size_t)n * 128 + t]);
    part[((size_t)b * 16 + chunk) * 128 + t] = m;
}

// ---------------------------------------------------------------------------
// Head stage 2
// ---------------------------------------------------------------------------
__launch_bounds__(128)
__global__ void head2_kernel(const float* __restrict__ part,
                             const float* __restrict__ fc1w, const float* __restrict__ fc1b,
                             const float* __restrict__ fc2w, const float* __restrict__ fc2b,
                             const float* __restrict__ fc3w, const float* __restrict__ fc3b,
                             float* __restrict__ out) {
    const int g = blockIdx.x, b = blockIdx.y, t = threadIdx.x;
    __shared__ float s5[128], s6[128], s7[128];
    float m = -1e30f;
#pragma unroll
    for (int c = 0; c < 16; ++c)
        m = fmaxf(m, part[((size_t)b * 16 + c) * 128 + t]);
    s5[t] = m;
    __syncthreads();
    float a = fc1b[t];
#pragma unroll 4
    for (int i = 0; i < 128; ++i) a = fmaf(s5[i], fc1w[i * 128 + t], a);
    s6[t] = lrelu(a);
    __syncthreads();
    a = fc2b[t];
#pragma unroll 4
    for (int i = 0; i < 128; ++i) a = fmaf(s6[i], fc2w[i * 128 + t], a);
    s7[t] = lrelu(a);
    __syncthreads();
    const int o = g * 128 + t;
    float acc = fc3b[o];
#pragma unroll 4
    for (int i = 0; i < 128; ++i) acc = fmaf(s7[i], fc3w[(size_t)i * 6144 + o], acc);
    out[(size_t)b * 6144 + o] = acc;
}

// ---------------------------------------------------------------------------
extern "C" void kernel_launch(void* const* d_in, const int* in_sizes, int n_in,
                              void* d_out, int out_size, void* d_ws, size_t ws_size,
                              hipStream_t stream) {
    const float* x    = (const float*)d_in[0];
    const float* h1w1 = (const float*)d_in[1];
    const float* h1b1 = (const float*)d_in[2];
    const float* h1w2 = (const float*)d_in[3];
    const float* h1b2 = (const float*)d_in[4];
    const float* h1w3 = (const float*)d_in[5];
    const float* h1b3 = (const float*)d_in[6];
    const float* h2w1 = (const float*)d_in[7];
    const float* h2b1 = (const float*)d_in[8];
    const float* h2w2 = (const float*)d_in[9];
    const float* h2b2 = (const float*)d_in[10];
    const float* h3w1 = (const float*)d_in[11];
    const float* h3b1 = (const float*)d_in[12];
    const float* fc1w = (const float*)d_in[13];
    const float* fc1b = (const float*)d_in[14];
    const float* fc2w = (const float*)d_in[15];
    const float* fc2b = (const float*)d_in[16];
    const float* fc3w = (const float*)d_in[17];
    const float* fc3b = (const float*)d_in[18];

    float* ws  = (float*)d_ws;
    float* x2  = ws;                      //  524288 floats
    float* x3  = ws + 524288;             // 2097152 floats
    float* x4  = ws + 2621440;            // 2097152 floats
    int*   idx = (int*)(ws + 4718592);    //  262144 ints
    float* nrm = ws + 4980736;            //   16384 floats
    float* part= ws + 4997120;            //   16384 floats  (~20 MB total)
    // candidate buffers alias the x4 region (free until block3 runs)
    float* cd  = ws + 2621440;            // 1048576 floats
    int*   ci  = (int*)(ws + 3670016);    // 1048576 ints
    float* out = (float*)d_out;

    const dim3 kg(32, 4, 8);   // (qtile, j-split, batch)

    norms_kernel<3><<<64, 256, 0, stream>>>(x, nrm);
    knn_kernel<3, 64, 4><<<kg, 256, 0, stream>>>(x, nrm, cd, ci);
    knn_merge_kernel<4><<<64, 256, 0, stream>>>(cd, ci, idx);
    block1_kernel<<<1024, 256, 0, stream>>>(x, idx, h1w1, h1b1, h1w2, h1b2, h1w3, h1b3, x2);

    norms_kernel<32><<<64, 256, 0, stream>>>(x2, nrm);
    knn_gemm_kernel<32, 4><<<kg, 256, 0, stream>>>(x2, nrm, cd, ci);
    knn_merge_kernel<4><<<64, 256, 0, stream>>>(cd, ci, idx);
    block2_kernel<<<BSZ * NPT, 256, 0, stream>>>(x2, idx, h2w1, h2b1, h2w2, h2b2, x3);

    norms_kernel<128><<<64, 256, 0, stream>>>(x3, nrm);
    knn_gemm_kernel<128, 4><<<kg, 256, 0, stream>>>(x3, nrm, cd, ci);
    knn_merge_kernel<4><<<64, 256, 0, stream>>>(cd, ci, idx);
    block3_kernel<<<BSZ * NPT, 128, 0, stream>>>(x3, idx, h3w1, h3b1, x4);

    maxpool_partial_kernel<<<dim3(16, 8), 128, 0, stream>>>(x4, part);
    head2_kernel<<<dim3(48, 8), 128, 0, stream>>>(part, fc1w, fc1b, fc2w, fc2b,
                                                  fc3w, fc3b, out);
}

// Round 5
// 1572.111 us; speedup vs baseline: 1.9419x; 1.2099x over previous
//
#include <hip/hip_runtime.h>

#define KNB 16
#define BSZ 8
#define NPT 2048

typedef __attribute__((ext_vector_type(8))) short bf16x8;
typedef __attribute__((ext_vector_type(4))) float f32x4;

__device__ __forceinline__ float lrelu(float x) { return x >= 0.f ? x : 0.01f * x; }

// ---------------------------------------------------------------------------
// fp32 -> bf16 (round-to-nearest-even), flat
// ---------------------------------------------------------------------------
__global__ void tobf16_kernel(const float* __restrict__ in, unsigned short* __restrict__ out, int n) {
    int i = blockIdx.x * 256 + threadIdx.x;
    if (i < n) {
        union { float f; unsigned int u; } v; v.f = in[i];
        unsigned int r = (v.u + 0x7FFFu + ((v.u >> 16) & 1u)) >> 16;
        out[i] = (unsigned short)r;
    }
}

// ---------------------------------------------------------------------------
// Per-point squared norms from bf16 features (consistent with MFMA distances)
// ---------------------------------------------------------------------------
template<int C>
__global__ void norms16_kernel(const unsigned short* __restrict__ feat, float* __restrict__ out) {
    int gid = blockIdx.x * blockDim.x + threadIdx.x;
    if (gid < BSZ * NPT) {
        const unsigned short* p = feat + (size_t)gid * C;
        float s = 0.f;
#pragma unroll
        for (int c = 0; c < C; ++c) {
            union { unsigned int u; float f; } v; v.u = ((unsigned int)p[c]) << 16;
            s = fmaf(v.f, v.f, s);
        }
        out[gid] = s;
    }
}

// ---------------------------------------------------------------------------
// KNN for tiny C (C=3), fp32, j-split JS ways (unchanged from R3).
// ---------------------------------------------------------------------------
template<int C>
__global__ void norms_kernel(const float* __restrict__ feat, float* __restrict__ out) {
    int gid = blockIdx.x * blockDim.x + threadIdx.x;
    if (gid < BSZ * NPT) {
        const float* p = feat + (size_t)gid * C;
        float s = 0.f;
#pragma unroll
        for (int c = 0; c < C; ++c) s = fmaf(p[c], p[c], s);
        out[gid] = s;
    }
}

template<int C, int TJ, int JS>
__launch_bounds__(256)
__global__ void knn_kernel(const float* __restrict__ feat,
                           const float* __restrict__ norms,
                           float* __restrict__ cand_d,
                           int* __restrict__ cand_i) {
    constexpr int JL  = NPT / JS;
    constexpr int JPT = TJ / 4;
    constexpr int CP  = C + 4;
    const int b   = blockIdx.z;
    const int js  = blockIdx.y;
    const int i0  = blockIdx.x * 64;
    const int tid = threadIdx.x;
    const int il  = tid & 63;
    const int jg  = tid >> 6;
    const float* fb = feat + (size_t)b * NPT * C;

    __shared__ float sP[TJ][CP];
    __shared__ float sPn[TJ];
    __shared__ float sMd[64][KNB + 1];
    __shared__ int   sMi[64][KNB + 1];

    float q[C];
    {
        const float* qp = fb + (size_t)(i0 + il) * C;
#pragma unroll
        for (int c = 0; c < C; ++c) q[c] = qp[c];
    }

    float bd[KNB]; int bi[KNB];
#pragma unroll
    for (int t = 0; t < KNB; ++t) { bd[t] = 1e30f; bi[t] = 0; }
    float mx = 1e30f; int mp = 0;

    auto insert = [&](float d, int j) {
#pragma unroll
        for (int t = 0; t < KNB; ++t) if (t == mp) { bd[t] = d; bi[t] = j; }
        mx = -1e30f;
#pragma unroll
        for (int t = 0; t < KNB; ++t) if (bd[t] > mx) { mx = bd[t]; mp = t; }
    };

    for (int j0 = js * JL; j0 < (js + 1) * JL; j0 += TJ) {
        __syncthreads();
        for (int t = tid; t < TJ * C; t += 256) {
            int r = t / C, c = t - r * C;
            sP[r][c] = fb[(size_t)j0 * C + t];
        }
        if (tid < TJ) sPn[tid] = norms[b * NPT + j0 + tid];
        __syncthreads();
#pragma unroll 1
        for (int jj = 0; jj < JPT; ++jj) {
            const int jl = jg * JPT + jj;
            float dot = 0.f;
#pragma unroll
            for (int c = 0; c < C; ++c) dot = fmaf(q[c], sP[jl][c], dot);
            const float d = fmaf(-2.f, dot, sPn[jl]);
            if (d < mx) insert(d, j0 + jl);
        }
    }

#pragma unroll 1
    for (int r = 1; r < 4; ++r) {
        __syncthreads();
        if (jg == r) {
#pragma unroll
            for (int t = 0; t < KNB; ++t) { sMd[il][t] = bd[t]; sMi[il][t] = bi[t]; }
        }
        __syncthreads();
        if (jg == 0) {
#pragma unroll 1
            for (int t = 0; t < KNB; ++t) {
                const float d = sMd[il][t];
                if (d < mx) insert(d, sMi[il][t]);
            }
        }
    }
    if (jg == 0) {
        const size_t base = (((size_t)b * NPT + i0 + il) * JS + js) * KNB;
#pragma unroll
        for (int t = 0; t < KNB; ++t) { cand_d[base + t] = bd[t]; cand_i[base + t] = bi[t]; }
    }
}

// ---------------------------------------------------------------------------
// KNN scores via bf16 MFMA, C in {32,128}, j-split JS ways.
// Block = 64 queries x JL candidates; 4 waves, wave w owns cols [w*16,w*16+16)
// of each 64x64 score tile. A-frags (query rows) preloaded once per block in
// registers; B-frags streamed from global (16B/lane). Epilogue writes
// |p|^2 - 2 q.p to sS (C/D layout: col=lane&15, row=quad*4+reg), then the
// proven 4-partition per-row selection. No staging LDS, 2 barriers/tile.
// ---------------------------------------------------------------------------
template<int C, int JS>
__launch_bounds__(256)
__global__ void knn_mfma_kernel(const unsigned short* __restrict__ fb16,
                                const float* __restrict__ norms,
                                float* __restrict__ cand_d,
                                int* __restrict__ cand_i) {
    constexpr int JL = NPT / JS;
    constexpr int KS = C / 32;             // k-steps
    const int b    = blockIdx.z;
    const int js   = blockIdx.y;
    const int i0   = blockIdx.x * 64;
    const int t    = threadIdx.x;
    const int w    = t >> 6;               // wave id -> n-subtile
    const int lane = t & 63;
    const int l15  = lane & 15;
    const int quad = lane >> 4;
    const int sr   = t >> 2, lp = t & 3;   // selection row / partition
    const unsigned short* fbb = fb16 + (size_t)b * NPT * C;
    const float* nb = norms + (size_t)b * NPT;

    __shared__ __align__(16) float sS[64][68];
    float (*sMd)[17] = (float (*)[17]) & sS[0][0];
    int   (*sMi)[17] = (int   (*)[17]) & sS[32][0];

    // preload A fragments: rows i0 + mi*16 + l15, k = ks*32 + quad*8 .. +7
    bf16x8 afr[KS * 4];
#pragma unroll
    for (int ks = 0; ks < KS; ++ks)
#pragma unroll
        for (int mi = 0; mi < 4; ++mi)
            afr[ks * 4 + mi] = *(const bf16x8*)(fbb + (size_t)(i0 + mi * 16 + l15) * C + ks * 32 + quad * 8);

    float bd[KNB]; int bi[KNB];
#pragma unroll
    for (int u = 0; u < KNB; ++u) { bd[u] = 1e30f; bi[u] = 0; }
    float mx = 1e30f; int mp = 0;

    auto insert = [&](float d, int j) {
#pragma unroll
        for (int u = 0; u < KNB; ++u) if (u == mp) { bd[u] = d; bi[u] = j; }
        mx = -1e30f;
#pragma unroll
        for (int u = 0; u < KNB; ++u) if (bd[u] > mx) { mx = bd[u]; mp = u; }
    };

    const int jend = (js + 1) * JL;
#pragma unroll 1
    for (int j0 = js * JL; j0 < jend; j0 += 64) {
        f32x4 acc[4];
#pragma unroll
        for (int mi = 0; mi < 4; ++mi) acc[mi] = (f32x4){0.f, 0.f, 0.f, 0.f};
        const unsigned short* prow = fbb + (size_t)(j0 + w * 16 + l15) * C + quad * 8;
#pragma unroll
        for (int ks = 0; ks < KS; ++ks) {
            const bf16x8 bfr = *(const bf16x8*)(prow + ks * 32);
#pragma unroll
            for (int mi = 0; mi < 4; ++mi)
                acc[mi] = __builtin_amdgcn_mfma_f32_16x16x32_bf16(afr[ks * 4 + mi], bfr, acc[mi], 0, 0, 0);
        }
        const float nv = nb[j0 + w * 16 + l15];
        __syncthreads();                       // prev selection done reading sS
#pragma unroll
        for (int mi = 0; mi < 4; ++mi)
#pragma unroll
            for (int r = 0; r < 4; ++r)
                sS[mi * 16 + quad * 4 + r][w * 16 + l15] = fmaf(-2.f, acc[mi][r], nv);
        __syncthreads();                       // scores visible
        // selection: thread owns row sr, cols == lp (mod 4); fully unrolled
        // so the 16 ds_reads batch under one lgkmcnt wait.
#pragma unroll
        for (int jj = 0; jj < 16; ++jj) {
            const float d = sS[sr][4 * jj + lp];
            if (d < mx) insert(d, j0 + 4 * jj + lp);
        }
    }

    // merge partitions 1..3 into partition 0 (sMd/sMi alias sS, barrier-safe)
#pragma unroll 1
    for (int r = 1; r < 4; ++r) {
        __syncthreads();
        if (lp == r) {
#pragma unroll
            for (int u = 0; u < KNB; ++u) { sMd[sr][u] = bd[u]; sMi[sr][u] = bi[u]; }
        }
        __syncthreads();
        if (lp == 0) {
#pragma unroll 1
            for (int u = 0; u < KNB; ++u) {
                const float d = sMd[sr][u];
                if (d < mx) insert(d, sMi[sr][u]);
            }
        }
    }
    if (lp == 0) {
        const size_t base = (((size_t)b * NPT + i0 + sr) * JS + js) * KNB;
#pragma unroll
        for (int u = 0; u < KNB; ++u) { cand_d[base + u] = bd[u]; cand_i[base + u] = bi[u]; }
    }
}

// ---------------------------------------------------------------------------
// Merge JS provisional top-16 lists per query -> final top-16 indices.
// ---------------------------------------------------------------------------
template<int JS>
__launch_bounds__(256)
__global__ void knn_merge_kernel(const float* __restrict__ cand_d,
                                 const int* __restrict__ cand_i,
                                 int* __restrict__ knn_out) {
    const int q = blockIdx.x * 256 + threadIdx.x;
    float bd[KNB]; int bi[KNB];
#pragma unroll
    for (int u = 0; u < KNB; ++u) { bd[u] = 1e30f; bi[u] = 0; }
    float mx = 1e30f; int mp = 0;

    auto insert = [&](float d, int j) {
#pragma unroll
        for (int u = 0; u < KNB; ++u) if (u == mp) { bd[u] = d; bi[u] = j; }
        mx = -1e30f;
#pragma unroll
        for (int u = 0; u < KNB; ++u) if (bd[u] > mx) { mx = bd[u]; mp = u; }
    };

    const float* pd = cand_d + (size_t)q * JS * KNB;
    const int*   pi = cand_i + (size_t)q * JS * KNB;
#pragma unroll 1
    for (int u = 0; u < JS * KNB; ++u) {
        const float d = pd[u];
        if (d < mx) insert(d, pi[u]);
    }
    int* o = knn_out + (size_t)q * KNB;
#pragma unroll
    for (int u = 0; u < KNB; ++u) o[u] = bi[u];
}

// ---------------------------------------------------------------------------
// Block 1: concat(x_i(3), x_j(3)) -> 16 -> 64 -> 32, lrelu each, sum over k.
// ---------------------------------------------------------------------------
__launch_bounds__(256)
__global__ void block1_kernel(const float* __restrict__ x, const int* __restrict__ knn,
                              const float* __restrict__ w1, const float* __restrict__ b1,
                              const float* __restrict__ w2, const float* __restrict__ b2,
                              const float* __restrict__ w3, const float* __restrict__ b3,
                              float* __restrict__ x2out) {
    __shared__ float sw1[96], sb1[16], sw2[1024], sb2[64], sw3[2048], sb3[32];
    __shared__ float sh[16][16][32];
    const int tid = threadIdx.x;
    for (int t = tid; t < 96;  t += 256) sw1[t] = w1[t];
    if (tid < 16) sb1[tid] = b1[tid];
    for (int t = tid; t < 1024; t += 256) sw2[t] = w2[t];
    if (tid < 64) sb2[tid] = b2[tid];
    for (int t = tid; t < 2048; t += 256) sw3[t] = w3[t];
    if (tid < 32) sb3[tid] = b3[tid];
    __syncthreads();

    const int pt = tid >> 4, k = tid & 15;
    const int bn = blockIdx.x * 16 + pt;
    const int b  = bn >> 11, n = bn & (NPT - 1);
    const float* xb = x + (size_t)b * NPT * 3;
    const int j = knn[(size_t)bn * KNB + k];

    float in6[6] = { xb[n*3+0], xb[n*3+1], xb[n*3+2],
                     xb[j*3+0], xb[j*3+1], xb[j*3+2] };
    float h1[16];
#pragma unroll
    for (int o = 0; o < 16; ++o) {
        float a = sb1[o];
#pragma unroll
        for (int i = 0; i < 6; ++i) a = fmaf(in6[i], sw1[i * 16 + o], a);
        h1[o] = lrelu(a);
    }
    float h2[64];
#pragma unroll
    for (int o = 0; o < 64; ++o) {
        float a = sb2[o];
#pragma unroll
        for (int i = 0; i < 16; ++i) a = fmaf(h1[i], sw2[i * 64 + o], a);
        h2[o] = lrelu(a);
    }
#pragma unroll
    for (int o = 0; o < 32; ++o) {
        float a = sb3[o];
#pragma unroll
        for (int i = 0; i < 64; ++i) a = fmaf(h2[i], sw3[i * 32 + o], a);
        sh[pt][k][o] = lrelu(a);
    }
    __syncthreads();
    for (int t = tid; t < 16 * 32; t += 256) {
        int p2 = t >> 5, o = t & 31;
        float s = 0.f;
#pragma unroll
        for (int kk = 0; kk < 16; ++kk) s += sh[p2][kk][o];
        x2out[(size_t)(blockIdx.x * 16 + p2) * 32 + o] = s;
    }
}

// ---------------------------------------------------------------------------
// Block 2: concat(x2_i(32), x2_j(32)) -> 256 -> 128, lrelu each, sum over k.
// ---------------------------------------------------------------------------
__launch_bounds__(256)
__global__ void block2_kernel(const float* __restrict__ x2, const int* __restrict__ knn,
                              const float* __restrict__ w1, const float* __restrict__ b1,
                              const float* __restrict__ w2, const float* __restrict__ b2,
                              float* __restrict__ x3) {
    const int bn = blockIdx.x;
    const int b  = bn >> 11;
    const int tid = threadIdx.x;
    __shared__ float s_in[17][33];
    __shared__ float s_h1[16][256];
    __shared__ float s_part[256];
    __shared__ int   s_nb[16];
    if (tid < 16) s_nb[tid] = knn[(size_t)bn * KNB + tid];
    __syncthreads();
    for (int t = tid; t < 17 * 32; t += 256) {
        int r = t >> 5, c = t & 31;
        int src = (r == 0) ? bn : (b * NPT + s_nb[r - 1]);
        s_in[r][c] = x2[(size_t)src * 32 + c];
    }
    __syncthreads();

    float cp = 0.f;
#pragma unroll 4
    for (int i = 0; i < 32; ++i) cp = fmaf(s_in[0][i], w1[i * 256 + tid], cp);
    float acc[16];
#pragma unroll
    for (int k = 0; k < 16; ++k) acc[k] = 0.f;
#pragma unroll 2
    for (int i = 0; i < 32; ++i) {
        float w = w1[(32 + i) * 256 + tid];
#pragma unroll
        for (int k = 0; k < 16; ++k) acc[k] = fmaf(s_in[1 + k][i], w, acc[k]);
    }
    float bb = b1[tid];
#pragma unroll
    for (int k = 0; k < 16; ++k) s_h1[k][tid] = lrelu(cp + acc[k] + bb);
    __syncthreads();

    const int o = tid & 127, kh = tid >> 7;
    float a2[8];
#pragma unroll
    for (int k = 0; k < 8; ++k) a2[k] = 0.f;
#pragma unroll 4
    for (int i = 0; i < 256; ++i) {
        float w = w2[i * 128 + o];
#pragma unroll
        for (int k = 0; k < 8; ++k) a2[k] = fmaf(s_h1[kh * 8 + k][i], w, a2[k]);
    }
    float b2v = b2[o];
    float ps = 0.f;
#pragma unroll
    for (int k = 0; k < 8; ++k) ps += lrelu(a2[k] + b2v);
    s_part[tid] = ps;
    __syncthreads();
    if (tid < 128) x3[(size_t)bn * 128 + tid] = s_part[tid] + s_part[tid + 128];
}

// ---------------------------------------------------------------------------
// Block 3: concat(x3_i(128), x3_j(128)) -> 128, lrelu, sum over k.
// ---------------------------------------------------------------------------
__launch_bounds__(128)
__global__ void block3_kernel(const float* __restrict__ x3, const int* __restrict__ knn,
                              const float* __restrict__ w, const float* __restrict__ bias,
                              float* __restrict__ x4) {
    const int bn = blockIdx.x;
    const int b  = bn >> 11;
    const int tid = threadIdx.x;
    __shared__ float s_ctr[128];
    __shared__ float s_nbr[16][128];
    __shared__ int   s_nb[16];
    if (tid < 16) s_nb[tid] = knn[(size_t)bn * KNB + tid];
    s_ctr[tid] = x3[(size_t)bn * 128 + tid];
    __syncthreads();
    for (int k = 0; k < 16; ++k)
        s_nbr[k][tid] = x3[((size_t)b * NPT + s_nb[k]) * 128 + tid];
    __syncthreads();

    float cp = 0.f;
#pragma unroll 4
    for (int i = 0; i < 128; ++i) cp = fmaf(s_ctr[i], w[i * 128 + tid], cp);
    float acc[16];
#pragma unroll
    for (int k = 0; k < 16; ++k) acc[k] = 0.f;
#pragma unroll 2
    for (int i = 0; i < 128; ++i) {
        float wv = w[(128 + i) * 128 + tid];
#pragma unroll
        for (int k = 0; k < 16; ++k) acc[k] = fmaf(s_nbr[k][i], wv, acc[k]);
    }
    const float bv = bias[tid];
    float s = 0.f;
#pragma unroll
    for (int k = 0; k < 16; ++k) s += lrelu(cp + acc[k] + bv);
    x4[(size_t)bn * 128 + tid] = s;
}

// ---------------------------------------------------------------------------
// Maxpool stage 1
// ---------------------------------------------------------------------------
__launch_bounds__(128)
__global__ void maxpool_partial_kernel(const float* __restrict__ x4,
                                       float* __restrict__ part) {
    const int chunk = blockIdx.x, b = blockIdx.y, t = threadIdx.x;
    const float* xb = x4 + ((size_t)b * NPT + (size_t)chunk * 128) * 128;
    float m = -1e30f;
#pragma unroll 8
    for (int n = 0; n < 128; ++n) m = fmaxf(m, xb[(size_t)n * 128 + t]);
    part[((size_t)b * 16 + chunk) * 128 + t] = m;
}

// ---------------------------------------------------------------------------
// Head stage 2
// ---------------------------------------------------------------------------
__launch_bounds__(128)
__global__ void head2_kernel(const float* __restrict__ part,
                             const float* __restrict__ fc1w, const float* __restrict__ fc1b,
                             const float* __restrict__ fc2w, const float* __restrict__ fc2b,
                             const float* __restrict__ fc3w, const float* __restrict__ fc3b,
                             float* __restrict__ out) {
    const int g = blockIdx.x, b = blockIdx.y, t = threadIdx.x;
    __shared__ float s5[128], s6[128], s7[128];
    float m = -1e30f;
#pragma unroll
    for (int c = 0; c < 16; ++c)
        m = fmaxf(m, part[((size_t)b * 16 + c) * 128 + t]);
    s5[t] = m;
    __syncthreads();
    float a = fc1b[t];
#pragma unroll 4
    for (int i = 0; i < 128; ++i) a = fmaf(s5[i], fc1w[i * 128 + t], a);
    s6[t] = lrelu(a);
    __syncthreads();
    a = fc2b[t];
#pragma unroll 4
    for (int i = 0; i < 128; ++i) a = fmaf(s6[i], fc2w[i * 128 + t], a);
    s7[t] = lrelu(a);
    __syncthreads();
    const int o = g * 128 + t;
    float acc = fc3b[o];
#pragma unroll 4
    for (int i = 0; i < 128; ++i) acc = fmaf(s7[i], fc3w[(size_t)i * 6144 + o], acc);
    out[(size_t)b * 6144 + o] = acc;
}

// ---------------------------------------------------------------------------
extern "C" void kernel_launch(void* const* d_in, const int* in_sizes, int n_in,
                              void* d_out, int out_size, void* d_ws, size_t ws_size,
                              hipStream_t stream) {
    const float* x    = (const float*)d_in[0];
    const float* h1w1 = (const float*)d_in[1];
    const float* h1b1 = (const float*)d_in[2];
    const float* h1w2 = (const float*)d_in[3];
    const float* h1b2 = (const float*)d_in[4];
    const float* h1w3 = (const float*)d_in[5];
    const float* h1b3 = (const float*)d_in[6];
    const float* h2w1 = (const float*)d_in[7];
    const float* h2b1 = (const float*)d_in[8];
    const float* h2w2 = (const float*)d_in[9];
    const float* h2b2 = (const float*)d_in[10];
    const float* h3w1 = (const float*)d_in[11];
    const float* h3b1 = (const float*)d_in[12];
    const float* fc1w = (const float*)d_in[13];
    const float* fc1b = (const float*)d_in[14];
    const float* fc2w = (const float*)d_in[15];
    const float* fc2b = (const float*)d_in[16];
    const float* fc3w = (const float*)d_in[17];
    const float* fc3b = (const float*)d_in[18];

    float* ws  = (float*)d_ws;
    float* x2  = ws;                      //  524288 floats
    float* x3  = ws + 524288;             // 2097152 floats
    float* x4  = ws + 2621440;            // 2097152 floats
    int*   idx = (int*)(ws + 4718592);    //  262144 ints
    float* nrm = ws + 4980736;            //   16384 floats
    float* part= ws + 4997120;            //   16384 floats
    unsigned short* fb16 = (unsigned short*)(ws + 5013504); // up to 2M ushorts (1M floats)
    // candidate buffers alias the x4 region (free until block3 runs)
    float* cd  = ws + 2621440;            // 1048576 floats
    int*   ci  = (int*)(ws + 3670016);    // 1048576 ints
    float* out = (float*)d_out;

    const dim3 kg(32, 4, 8);   // (qtile, j-split, batch)

    norms_kernel<3><<<64, 256, 0, stream>>>(x, nrm);
    knn_kernel<3, 64, 4><<<kg, 256, 0, stream>>>(x, nrm, cd, ci);
    knn_merge_kernel<4><<<64, 256, 0, stream>>>(cd, ci, idx);
    block1_kernel<<<1024, 256, 0, stream>>>(x, idx, h1w1, h1b1, h1w2, h1b2, h1w3, h1b3, x2);

    tobf16_kernel<<<2048, 256, 0, stream>>>(x2, fb16, BSZ * NPT * 32);
    norms16_kernel<32><<<64, 256, 0, stream>>>(fb16, nrm);
    knn_mfma_kernel<32, 4><<<kg, 256, 0, stream>>>(fb16, nrm, cd, ci);
    knn_merge_kernel<4><<<64, 256, 0, stream>>>(cd, ci, idx);
    block2_kernel<<<BSZ * NPT, 256, 0, stream>>>(x2, idx, h2w1, h2b1, h2w2, h2b2, x3);

    tobf16_kernel<<<8192, 256, 0, stream>>>(x3, fb16, BSZ * NPT * 128);
    norms16_kernel<128><<<64, 256, 0, stream>>>(fb16, nrm);
    knn_mfma_kernel<128, 4><<<kg, 256, 0, stream>>>(fb16, nrm, cd, ci);
    knn_merge_kernel<4><<<64, 256, 0, stream>>>(cd, ci, idx);
    block3_kernel<<<BSZ * NPT, 128, 0, stream>>>(x3, idx, h3w1, h3b1, x4);

    maxpool_partial_kernel<<<dim3(16, 8), 128, 0, stream>>>(x4, part);
    head2_kernel<<<dim3(48, 8), 128, 0, stream>>>(part, fc1w, fc1b, fc2w, fc2b,
                                                  fc3w, fc3b, out);
}

// Round 6
// 1305.401 us; speedup vs baseline: 2.3387x; 1.2043x over previous
//
#include <hip/hip_runtime.h>

#define KNB 16
#define BSZ 8
#define NPT 2048

typedef __attribute__((ext_vector_type(8))) short bf16x8;
typedef __attribute__((ext_vector_type(4))) float f32x4;

__device__ __forceinline__ float lrelu(float x) { return x >= 0.f ? x : 0.01f * x; }

__device__ __forceinline__ unsigned short bf16rne(float f) {
    union { float f; unsigned int u; } v; v.f = f;
    return (unsigned short)((v.u + 0x7FFFu + ((v.u >> 16) & 1u)) >> 16);
}

// ---------------------------------------------------------------------------
// fp32 -> bf16 (RNE), flat
// ---------------------------------------------------------------------------
__global__ void tobf16_kernel(const float* __restrict__ in, unsigned short* __restrict__ out, int n) {
    int i = blockIdx.x * 256 + threadIdx.x;
    if (i < n) out[i] = bf16rne(in[i]);
}

// ---------------------------------------------------------------------------
// Weight prep: w[K][N] fp32 -> wt[N][K] bf16 (B-operand friendly layout)
// ---------------------------------------------------------------------------
__global__ void wprep_kernel(const float* __restrict__ w, unsigned short* __restrict__ wt,
                             int K, int N) {
    int i = blockIdx.x * 256 + threadIdx.x;
    if (i < K * N) { int k = i / N, n = i - k * N; wt[n * K + k] = bf16rne(w[i]); }
}

// ---------------------------------------------------------------------------
// Per-point squared norms from bf16 features (consistent with MFMA distances)
// ---------------------------------------------------------------------------
template<int C>
__global__ void norms16_kernel(const unsigned short* __restrict__ feat, float* __restrict__ out) {
    int gid = blockIdx.x * blockDim.x + threadIdx.x;
    if (gid < BSZ * NPT) {
        const unsigned short* p = feat + (size_t)gid * C;
        float s = 0.f;
#pragma unroll
        for (int c = 0; c < C; ++c) {
            union { unsigned int u; float f; } v; v.u = ((unsigned int)p[c]) << 16;
            s = fmaf(v.f, v.f, s);
        }
        out[gid] = s;
    }
}

template<int C>
__global__ void norms_kernel(const float* __restrict__ feat, float* __restrict__ out) {
    int gid = blockIdx.x * blockDim.x + threadIdx.x;
    if (gid < BSZ * NPT) {
        const float* p = feat + (size_t)gid * C;
        float s = 0.f;
#pragma unroll
        for (int c = 0; c < C; ++c) s = fmaf(p[c], p[c], s);
        out[gid] = s;
    }
}

// ---------------------------------------------------------------------------
// KNN for tiny C (C=3), fp32, j-split JS ways.
// ---------------------------------------------------------------------------
template<int C, int TJ, int JS>
__launch_bounds__(256)
__global__ void knn_kernel(const float* __restrict__ feat,
                           const float* __restrict__ norms,
                           float* __restrict__ cand_d,
                           int* __restrict__ cand_i) {
    constexpr int JL  = NPT / JS;
    constexpr int JPT = TJ / 4;
    constexpr int CP  = C + 4;
    const int b   = blockIdx.z;
    const int js  = blockIdx.y;
    const int i0  = blockIdx.x * 64;
    const int tid = threadIdx.x;
    const int il  = tid & 63;
    const int jg  = tid >> 6;
    const float* fb = feat + (size_t)b * NPT * C;

    __shared__ float sP[TJ][CP];
    __shared__ float sPn[TJ];
    __shared__ float sMd[64][KNB + 1];
    __shared__ int   sMi[64][KNB + 1];

    float q[C];
    {
        const float* qp = fb + (size_t)(i0 + il) * C;
#pragma unroll
        for (int c = 0; c < C; ++c) q[c] = qp[c];
    }

    float bd[KNB]; int bi[KNB];
#pragma unroll
    for (int t = 0; t < KNB; ++t) { bd[t] = 1e30f; bi[t] = 0; }
    float mx = 1e30f; int mp = 0;

    auto insert = [&](float d, int j) {
#pragma unroll
        for (int t = 0; t < KNB; ++t) if (t == mp) { bd[t] = d; bi[t] = j; }
        mx = -1e30f;
#pragma unroll
        for (int t = 0; t < KNB; ++t) if (bd[t] > mx) { mx = bd[t]; mp = t; }
    };

    for (int j0 = js * JL; j0 < (js + 1) * JL; j0 += TJ) {
        __syncthreads();
        for (int t = tid; t < TJ * C; t += 256) {
            int r = t / C, c = t - r * C;
            sP[r][c] = fb[(size_t)j0 * C + t];
        }
        if (tid < TJ) sPn[tid] = norms[b * NPT + j0 + tid];
        __syncthreads();
#pragma unroll 1
        for (int jj = 0; jj < JPT; ++jj) {
            const int jl = jg * JPT + jj;
            float dot = 0.f;
#pragma unroll
            for (int c = 0; c < C; ++c) dot = fmaf(q[c], sP[jl][c], dot);
            const float d = fmaf(-2.f, dot, sPn[jl]);
            if (d < mx) insert(d, j0 + jl);
        }
    }

#pragma unroll 1
    for (int r = 1; r < 4; ++r) {
        __syncthreads();
        if (jg == r) {
#pragma unroll
            for (int t = 0; t < KNB; ++t) { sMd[il][t] = bd[t]; sMi[il][t] = bi[t]; }
        }
        __syncthreads();
        if (jg == 0) {
#pragma unroll 1
            for (int t = 0; t < KNB; ++t) {
                const float d = sMd[il][t];
                if (d < mx) insert(d, sMi[il][t]);
            }
        }
    }
    if (jg == 0) {
        const size_t base = (((size_t)b * NPT + i0 + il) * JS + js) * KNB;
#pragma unroll
        for (int t = 0; t < KNB; ++t) { cand_d[base + t] = bd[t]; cand_i[base + t] = bi[t]; }
    }
}

// ---------------------------------------------------------------------------
// KNN scores via bf16 MFMA, C in {32,128}, j-split JS ways (proven in R5).
// ---------------------------------------------------------------------------
template<int C, int JS>
__launch_bounds__(256)
__global__ void knn_mfma_kernel(const unsigned short* __restrict__ fb16,
                                const float* __restrict__ norms,
                                float* __restrict__ cand_d,
                                int* __restrict__ cand_i) {
    constexpr int JL = NPT / JS;
    constexpr int KS = C / 32;
    const int b    = blockIdx.z;
    const int js   = blockIdx.y;
    const int i0   = blockIdx.x * 64;
    const int t    = threadIdx.x;
    const int w    = t >> 6;
    const int lane = t & 63;
    const int l15  = lane & 15;
    const int quad = lane >> 4;
    const int sr   = t >> 2, lp = t & 3;
    const unsigned short* fbb = fb16 + (size_t)b * NPT * C;
    const float* nb = norms + (size_t)b * NPT;

    __shared__ __align__(16) float sS[64][68];
    float (*sMd)[17] = (float (*)[17]) & sS[0][0];
    int   (*sMi)[17] = (int   (*)[17]) & sS[32][0];

    bf16x8 afr[KS * 4];
#pragma unroll
    for (int ks = 0; ks < KS; ++ks)
#pragma unroll
        for (int mi = 0; mi < 4; ++mi)
            afr[ks * 4 + mi] = *(const bf16x8*)(fbb + (size_t)(i0 + mi * 16 + l15) * C + ks * 32 + quad * 8);

    float bd[KNB]; int bi[KNB];
#pragma unroll
    for (int u = 0; u < KNB; ++u) { bd[u] = 1e30f; bi[u] = 0; }
    float mx = 1e30f; int mp = 0;

    auto insert = [&](float d, int j) {
#pragma unroll
        for (int u = 0; u < KNB; ++u) if (u == mp) { bd[u] = d; bi[u] = j; }
        mx = -1e30f;
#pragma unroll
        for (int u = 0; u < KNB; ++u) if (bd[u] > mx) { mx = bd[u]; mp = u; }
    };

    const int jend = (js + 1) * JL;
#pragma unroll 1
    for (int j0 = js * JL; j0 < jend; j0 += 64) {
        f32x4 acc[4];
#pragma unroll
        for (int mi = 0; mi < 4; ++mi) acc[mi] = (f32x4){0.f, 0.f, 0.f, 0.f};
        const unsigned short* prow = fbb + (size_t)(j0 + w * 16 + l15) * C + quad * 8;
#pragma unroll
        for (int ks = 0; ks < KS; ++ks) {
            const bf16x8 bfr = *(const bf16x8*)(prow + ks * 32);
#pragma unroll
            for (int mi = 0; mi < 4; ++mi)
                acc[mi] = __builtin_amdgcn_mfma_f32_16x16x32_bf16(afr[ks * 4 + mi], bfr, acc[mi], 0, 0, 0);
        }
        const float nv = nb[j0 + w * 16 + l15];
        __syncthreads();
#pragma unroll
        for (int mi = 0; mi < 4; ++mi)
#pragma unroll
            for (int r = 0; r < 4; ++r)
                sS[mi * 16 + quad * 4 + r][w * 16 + l15] = fmaf(-2.f, acc[mi][r], nv);
        __syncthreads();
#pragma unroll
        for (int jj = 0; jj < 16; ++jj) {
            const float d = sS[sr][4 * jj + lp];
            if (d < mx) insert(d, j0 + 4 * jj + lp);
        }
    }

#pragma unroll 1
    for (int r = 1; r < 4; ++r) {
        __syncthreads();
        if (lp == r) {
#pragma unroll
            for (int u = 0; u < KNB; ++u) { sMd[sr][u] = bd[u]; sMi[sr][u] = bi[u]; }
        }
        __syncthreads();
        if (lp == 0) {
#pragma unroll 1
            for (int u = 0; u < KNB; ++u) {
                const float d = sMd[sr][u];
                if (d < mx) insert(d, sMi[sr][u]);
            }
        }
    }
    if (lp == 0) {
        const size_t base = (((size_t)b * NPT + i0 + sr) * JS + js) * KNB;
#pragma unroll
        for (int u = 0; u < KNB; ++u) { cand_d[base + u] = bd[u]; cand_i[base + u] = bi[u]; }
    }
}

// ---------------------------------------------------------------------------
// Merge JS provisional top-16 lists per query -> final top-16 indices.
// ---------------------------------------------------------------------------
template<int JS>
__launch_bounds__(256)
__global__ void knn_merge_kernel(const float* __restrict__ cand_d,
                                 const int* __restrict__ cand_i,
                                 int* __restrict__ knn_out) {
    const int q = blockIdx.x * 256 + threadIdx.x;
    float bd[KNB]; int bi[KNB];
#pragma unroll
    for (int u = 0; u < KNB; ++u) { bd[u] = 1e30f; bi[u] = 0; }
    float mx = 1e30f; int mp = 0;

    auto insert = [&](float d, int j) {
#pragma unroll
        for (int u = 0; u < KNB; ++u) if (u == mp) { bd[u] = d; bi[u] = j; }
        mx = -1e30f;
#pragma unroll
        for (int u = 0; u < KNB; ++u) if (bd[u] > mx) { mx = bd[u]; mp = u; }
    };

    const float* pd = cand_d + (size_t)q * JS * KNB;
    const int*   pi = cand_i + (size_t)q * JS * KNB;
#pragma unroll 1
    for (int u = 0; u < JS * KNB; ++u) {
        const float d = pd[u];
        if (d < mx) insert(d, pi[u]);
    }
    int* o = knn_out + (size_t)q * KNB;
#pragma unroll
    for (int u = 0; u < KNB; ++u) o[u] = bi[u];
}

// ---------------------------------------------------------------------------
// Block 1: concat(x_i(3), x_j(3)) -> 16 -> 64 -> 32, lrelu each, sum over k.
// ---------------------------------------------------------------------------
__launch_bounds__(256)
__global__ void block1_kernel(const float* __restrict__ x, const int* __restrict__ knn,
                              const float* __restrict__ w1, const float* __restrict__ b1,
                              const float* __restrict__ w2, const float* __restrict__ b2,
                              const float* __restrict__ w3, const float* __restrict__ b3,
                              float* __restrict__ x2out) {
    __shared__ float sw1[96], sb1[16], sw2[1024], sb2[64], sw3[2048], sb3[32];
    __shared__ float sh[16][16][32];
    const int tid = threadIdx.x;
    for (int t = tid; t < 96;  t += 256) sw1[t] = w1[t];
    if (tid < 16) sb1[tid] = b1[tid];
    for (int t = tid; t < 1024; t += 256) sw2[t] = w2[t];
    if (tid < 64) sb2[tid] = b2[tid];
    for (int t = tid; t < 2048; t += 256) sw3[t] = w3[t];
    if (tid < 32) sb3[tid] = b3[tid];
    __syncthreads();

    const int pt = tid >> 4, k = tid & 15;
    const int bn = blockIdx.x * 16 + pt;
    const int b  = bn >> 11, n = bn & (NPT - 1);
    const float* xb = x + (size_t)b * NPT * 3;
    const int j = knn[(size_t)bn * KNB + k];

    float in6[6] = { xb[n*3+0], xb[n*3+1], xb[n*3+2],
                     xb[j*3+0], xb[j*3+1], xb[j*3+2] };
    float h1[16];
#pragma unroll
    for (int o = 0; o < 16; ++o) {
        float a = sb1[o];
#pragma unroll
        for (int i = 0; i < 6; ++i) a = fmaf(in6[i], sw1[i * 16 + o], a);
        h1[o] = lrelu(a);
    }
    float h2[64];
#pragma unroll
    for (int o = 0; o < 64; ++o) {
        float a = sb2[o];
#pragma unroll
        for (int i = 0; i < 16; ++i) a = fmaf(h1[i], sw2[i * 64 + o], a);
        h2[o] = lrelu(a);
    }
#pragma unroll
    for (int o = 0; o < 32; ++o) {
        float a = sb3[o];
#pragma unroll
        for (int i = 0; i < 64; ++i) a = fmaf(h2[i], sw3[i * 32 + o], a);
        sh[pt][k][o] = lrelu(a);
    }
    __syncthreads();
    for (int t = tid; t < 16 * 32; t += 256) {
        int p2 = t >> 5, o = t & 31;
        float s = 0.f;
#pragma unroll
        for (int kk = 0; kk < 16; ++kk) s += sh[p2][kk][o];
        x2out[(size_t)(blockIdx.x * 16 + p2) * 32 + o] = s;
    }
}

// ---------------------------------------------------------------------------
// Block 2 via MFMA. Block = 4 points x 4 waves; wave w owns point
// blockIdx.x*4+w with its 16 neighbor rows.
// Layer1: [16x64] @ W1[64x256] (A: center broadcast + neighbor gather from
// bf16 x2); bias+lrelu -> bf16 H1 in LDS (row stride 264 shorts).
// Layer2: [16x256] @ W2[256x128]; bias+lrelu per row; sum over 16 rows via
// in-register + shfl_xor(16/32); quad 0 writes x3[p][128].
// C/D layout: col=lane&15, row=quad*4+reg (verified R5).
// ---------------------------------------------------------------------------
__launch_bounds__(256)
__global__ void block2_mfma_kernel(const unsigned short* __restrict__ x2b,
                                   const int* __restrict__ knn,
                                   const unsigned short* __restrict__ w1t,  // [256][64]
                                   const float* __restrict__ b1,
                                   const unsigned short* __restrict__ w2t,  // [128][256]
                                   const float* __restrict__ b2,
                                   float* __restrict__ x3) {
    const int w    = threadIdx.x >> 6;
    const int lane = threadIdx.x & 63;
    const int l15  = lane & 15, quad = lane >> 4;
    const int p    = blockIdx.x * 4 + w;
    const int b    = p >> 11;
    __shared__ __align__(16) unsigned short sH1[64][264];

    const int nbr = knn[(size_t)p * KNB + l15];
    const bf16x8 a0 = *(const bf16x8*)(x2b + (size_t)p * 32 + quad * 8);
    const bf16x8 a1 = *(const bf16x8*)(x2b + ((size_t)(b * NPT) + nbr) * 32 + quad * 8);

    // ---- layer 1 ----
    f32x4 acc1[16];
#pragma unroll
    for (int nt = 0; nt < 16; ++nt) acc1[nt] = (f32x4){0.f, 0.f, 0.f, 0.f};
#pragma unroll 4
    for (int nt = 0; nt < 16; ++nt) {
        const unsigned short* wp = w1t + (size_t)(nt * 16 + l15) * 64 + quad * 8;
        const bf16x8 b0 = *(const bf16x8*)wp;
        const bf16x8 b1f = *(const bf16x8*)(wp + 32);
        acc1[nt] = __builtin_amdgcn_mfma_f32_16x16x32_bf16(a0, b0, acc1[nt], 0, 0, 0);
        acc1[nt] = __builtin_amdgcn_mfma_f32_16x16x32_bf16(a1, b1f, acc1[nt], 0, 0, 0);
    }
#pragma unroll
    for (int nt = 0; nt < 16; ++nt) {
        const float bv = b1[nt * 16 + l15];
#pragma unroll
        for (int r = 0; r < 4; ++r)
            sH1[w * 16 + quad * 4 + r][nt * 16 + l15] = bf16rne(lrelu(acc1[nt][r] + bv));
    }
    __syncthreads();

    // ---- layer 2 ----
    f32x4 acc2[8];
#pragma unroll
    for (int nt = 0; nt < 8; ++nt) acc2[nt] = (f32x4){0.f, 0.f, 0.f, 0.f};
#pragma unroll 2
    for (int ks = 0; ks < 8; ++ks) {
        const bf16x8 a = *(const bf16x8*)&sH1[w * 16 + l15][ks * 32 + quad * 8];
#pragma unroll
        for (int nt = 0; nt < 8; ++nt) {
            const bf16x8 bb = *(const bf16x8*)(w2t + (size_t)(nt * 16 + l15) * 256 + ks * 32 + quad * 8);
            acc2[nt] = __builtin_amdgcn_mfma_f32_16x16x32_bf16(a, bb, acc2[nt], 0, 0, 0);
        }
    }
#pragma unroll
    for (int nt = 0; nt < 8; ++nt) {
        const float bv = b2[nt * 16 + l15];
        float s = 0.f;
#pragma unroll
        for (int r = 0; r < 4; ++r) s += lrelu(acc2[nt][r] + bv);
        s += __shfl_xor(s, 16);
        s += __shfl_xor(s, 32);
        if (quad == 0) x3[(size_t)p * 128 + nt * 16 + l15] = s;
    }
}

// ---------------------------------------------------------------------------
// Block 3 via MFMA: [16x256] @ W3[256x128], A streamed from bf16 x3
// (cols 0..127 center broadcast, 128..255 neighbor gather). No LDS/barriers.
// ---------------------------------------------------------------------------
__launch_bounds__(256)
__global__ void block3_mfma_kernel(const unsigned short* __restrict__ x3b,
                                   const int* __restrict__ knn,
                                   const unsigned short* __restrict__ w3t,  // [128][256]
                                   const float* __restrict__ bias,
                                   float* __restrict__ x4) {
    const int w    = threadIdx.x >> 6;
    const int lane = threadIdx.x & 63;
    const int l15  = lane & 15, quad = lane >> 4;
    const int p    = blockIdx.x * 4 + w;
    const int b    = p >> 11;

    const int nbr = knn[(size_t)p * KNB + l15];
    const unsigned short* ctr = x3b + (size_t)p * 128 + quad * 8;
    const unsigned short* nbp = x3b + ((size_t)(b * NPT) + nbr) * 128 + quad * 8;

    f32x4 acc[8];
#pragma unroll
    for (int nt = 0; nt < 8; ++nt) acc[nt] = (f32x4){0.f, 0.f, 0.f, 0.f};
#pragma unroll 2
    for (int ks = 0; ks < 8; ++ks) {
        const bf16x8 a = (ks < 4) ? *(const bf16x8*)(ctr + ks * 32)
                                  : *(const bf16x8*)(nbp + (ks - 4) * 32);
#pragma unroll
        for (int nt = 0; nt < 8; ++nt) {
            const bf16x8 bb = *(const bf16x8*)(w3t + (size_t)(nt * 16 + l15) * 256 + ks * 32 + quad * 8);
            acc[nt] = __builtin_amdgcn_mfma_f32_16x16x32_bf16(a, bb, acc[nt], 0, 0, 0);
        }
    }
#pragma unroll
    for (int nt = 0; nt < 8; ++nt) {
        const float bv = bias[nt * 16 + l15];
        float s = 0.f;
#pragma unroll
        for (int r = 0; r < 4; ++r) s += lrelu(acc[nt][r] + bv);
        s += __shfl_xor(s, 16);
        s += __shfl_xor(s, 32);
        if (quad == 0) x4[(size_t)p * 128 + nt * 16 + l15] = s;
    }
}

// ---------------------------------------------------------------------------
// Maxpool stage 1
// ---------------------------------------------------------------------------
__launch_bounds__(128)
__global__ void maxpool_partial_kernel(const float* __restrict__ x4,
                                       float* __restrict__ part) {
    const int chunk = blockIdx.x, b = blockIdx.y, t = threadIdx.x;
    const float* xb = x4 + ((size_t)b * NPT + (size_t)chunk * 128) * 128;
    float m = -1e30f;
#pragma unroll 8
    for (int n = 0; n < 128; ++n) m = fmaxf(m, xb[(size_t)n * 128 + t]);
    part[((size_t)b * 16 + chunk) * 128 + t] = m;
}

// ---------------------------------------------------------------------------
// Head stage 2
// ---------------------------------------------------------------------------
__launch_bounds__(128)
__global__ void head2_kernel(const float* __restrict__ part,
                             const float* __restrict__ fc1w, const float* __restrict__ fc1b,
                             const float* __restrict__ fc2w, const float* __restrict__ fc2b,
                             const float* __restrict__ fc3w, const float* __restrict__ fc3b,
                             float* __restrict__ out) {
    const int g = blockIdx.x, b = blockIdx.y, t = threadIdx.x;
    __shared__ float s5[128], s6[128], s7[128];
    float m = -1e30f;
#pragma unroll
    for (int c = 0; c < 16; ++c)
        m = fmaxf(m, part[((size_t)b * 16 + c) * 128 + t]);
    s5[t] = m;
    __syncthreads();
    float a = fc1b[t];
#pragma unroll 4
    for (int i = 0; i < 128; ++i) a = fmaf(s5[i], fc1w[i * 128 + t], a);
    s6[t] = lrelu(a);
    __syncthreads();
    a = fc2b[t];
#pragma unroll 4
    for (int i = 0; i < 128; ++i) a = fmaf(s6[i], fc2w[i * 128 + t], a);
    s7[t] = lrelu(a);
    __syncthreads();
    const int o = g * 128 + t;
    float acc = fc3b[o];
#pragma unroll 4
    for (int i = 0; i < 128; ++i) acc = fmaf(s7[i], fc3w[(size_t)i * 6144 + o], acc);
    out[(size_t)b * 6144 + o] = acc;
}

// ---------------------------------------------------------------------------
extern "C" void kernel_launch(void* const* d_in, const int* in_sizes, int n_in,
                              void* d_out, int out_size, void* d_ws, size_t ws_size,
                              hipStream_t stream) {
    const float* x    = (const float*)d_in[0];
    const float* h1w1 = (const float*)d_in[1];
    const float* h1b1 = (const float*)d_in[2];
    const float* h1w2 = (const float*)d_in[3];
    const float* h1b2 = (const float*)d_in[4];
    const float* h1w3 = (const float*)d_in[5];
    const float* h1b3 = (const float*)d_in[6];
    const float* h2w1 = (const float*)d_in[7];
    const float* h2b1 = (const float*)d_in[8];
    const float* h2w2 = (const float*)d_in[9];
    const float* h2b2 = (const float*)d_in[10];
    const float* h3w1 = (const float*)d_in[11];
    const float* h3b1 = (const float*)d_in[12];
    const float* fc1w = (const float*)d_in[13];
    const float* fc1b = (const float*)d_in[14];
    const float* fc2w = (const float*)d_in[15];
    const float* fc2b = (const float*)d_in[16];
    const float* fc3w = (const float*)d_in[17];
    const float* fc3b = (const float*)d_in[18];

    float* ws  = (float*)d_ws;
    float* x2  = ws;                      //  524288 floats
    float* x3  = ws + 524288;             // 2097152 floats
    float* x4  = ws + 2621440;            // 2097152 floats
    int*   idx = (int*)(ws + 4718592);    //  262144 ints
    float* nrm = ws + 4980736;            //   16384 floats
    float* part= ws + 4997120;            //   16384 floats
    unsigned short* fb16 = (unsigned short*)(ws + 5013504); // 2M shorts (1M float slots)
    unsigned short* w1t  = (unsigned short*)(ws + 6062080); // 16384 shorts
    unsigned short* w2t  = (unsigned short*)(ws + 6070272); // 32768 shorts
    unsigned short* w3t  = (unsigned short*)(ws + 6086656); // 32768 shorts
    // candidate buffers alias the x4 region (free until block3 runs)
    float* cd  = ws + 2621440;            // 1048576 floats
    int*   ci  = (int*)(ws + 3670016);    // 1048576 ints
    float* out = (float*)d_out;

    const dim3 kg(32, 4, 8);   // (qtile, j-split, batch)

    // weight prep (tiny; L2-resident afterwards)
    wprep_kernel<<<64, 256, 0, stream>>>(h2w1, w1t, 64, 256);
    wprep_kernel<<<128, 256, 0, stream>>>(h2w2, w2t, 256, 128);
    wprep_kernel<<<128, 256, 0, stream>>>(h3w1, w3t, 256, 128);

    norms_kernel<3><<<64, 256, 0, stream>>>(x, nrm);
    knn_kernel<3, 64, 4><<<kg, 256, 0, stream>>>(x, nrm, cd, ci);
    knn_merge_kernel<4><<<64, 256, 0, stream>>>(cd, ci, idx);
    block1_kernel<<<1024, 256, 0, stream>>>(x, idx, h1w1, h1b1, h1w2, h1b2, h1w3, h1b3, x2);

    tobf16_kernel<<<2048, 256, 0, stream>>>(x2, fb16, BSZ * NPT * 32);
    norms16_kernel<32><<<64, 256, 0, stream>>>(fb16, nrm);
    knn_mfma_kernel<32, 4><<<kg, 256, 0, stream>>>(fb16, nrm, cd, ci);
    knn_merge_kernel<4><<<64, 256, 0, stream>>>(cd, ci, idx);
    block2_mfma_kernel<<<BSZ * NPT / 4, 256, 0, stream>>>(fb16, idx, w1t, h2b1, w2t, h2b2, x3);

    tobf16_kernel<<<8192, 256, 0, stream>>>(x3, fb16, BSZ * NPT * 128);
    norms16_kernel<128><<<64, 256, 0, stream>>>(fb16, nrm);
    knn_mfma_kernel<128, 4><<<kg, 256, 0, stream>>>(fb16, nrm, cd, ci);
    knn_merge_kernel<4><<<64, 256, 0, stream>>>(cd, ci, idx);
    block3_mfma_kernel<<<BSZ * NPT / 4, 256, 0, stream>>>(fb16, idx, w3t, h3b1, x4);

    maxpool_partial_kernel<<<dim3(16, 8), 128, 0, stream>>>(x4, part);
    head2_kernel<<<dim3(48, 8), 128, 0, stream>>>(part, fc1w, fc1b, fc2w, fc2b,
                                                  fc3w, fc3b, out);
}

// Round 7
// 1288.501 us; speedup vs baseline: 2.3693x; 1.0131x over previous
//
#include <hip/hip_runtime.h>

#define KNB 16
#define BSZ 8
#define NPT 2048

typedef __attribute__((ext_vector_type(8))) short bf16x8;
typedef __attribute__((ext_vector_type(4))) float f32x4;

__device__ __forceinline__ float lrelu(float x) { return x >= 0.f ? x : 0.01f * x; }

__device__ __forceinline__ unsigned short bf16rne(float f) {
    union { float f; unsigned int u; } v; v.f = f;
    return (unsigned short)((v.u + 0x7FFFu + ((v.u >> 16) & 1u)) >> 16);
}

// ---------------------------------------------------------------------------
// fp32 -> bf16 (RNE), flat
// ---------------------------------------------------------------------------
__global__ void tobf16_kernel(const float* __restrict__ in, unsigned short* __restrict__ out, int n) {
    int i = blockIdx.x * 256 + threadIdx.x;
    if (i < n) out[i] = bf16rne(in[i]);
}

// ---------------------------------------------------------------------------
// Weight prep: w[K][N] fp32 -> wt[N][K] bf16 (B-operand friendly layout)
// ---------------------------------------------------------------------------
__global__ void wprep_kernel(const float* __restrict__ w, unsigned short* __restrict__ wt,
                             int K, int N) {
    int i = blockIdx.x * 256 + threadIdx.x;
    if (i < K * N) { int k = i / N, n = i - k * N; wt[n * K + k] = bf16rne(w[i]); }
}

// ---------------------------------------------------------------------------
// Per-point squared norms from bf16 features (consistent with MFMA distances)
// ---------------------------------------------------------------------------
template<int C>
__global__ void norms16_kernel(const unsigned short* __restrict__ feat, float* __restrict__ out) {
    int gid = blockIdx.x * blockDim.x + threadIdx.x;
    if (gid < BSZ * NPT) {
        const unsigned short* p = feat + (size_t)gid * C;
        float s = 0.f;
#pragma unroll
        for (int c = 0; c < C; ++c) {
            union { unsigned int u; float f; } v; v.u = ((unsigned int)p[c]) << 16;
            s = fmaf(v.f, v.f, s);
        }
        out[gid] = s;
    }
}

template<int C>
__global__ void norms_kernel(const float* __restrict__ feat, float* __restrict__ out) {
    int gid = blockIdx.x * blockDim.x + threadIdx.x;
    if (gid < BSZ * NPT) {
        const float* p = feat + (size_t)gid * C;
        float s = 0.f;
#pragma unroll
        for (int c = 0; c < C; ++c) s = fmaf(p[c], p[c], s);
        out[gid] = s;
    }
}

// ---------------------------------------------------------------------------
// KNN for tiny C (C=3), fp32, j-split JS ways.
// ---------------------------------------------------------------------------
template<int C, int TJ, int JS>
__launch_bounds__(256)
__global__ void knn_kernel(const float* __restrict__ feat,
                           const float* __restrict__ norms,
                           float* __restrict__ cand_d,
                           int* __restrict__ cand_i) {
    constexpr int JL  = NPT / JS;
    constexpr int JPT = TJ / 4;
    constexpr int CP  = C + 4;
    const int b   = blockIdx.z;
    const int js  = blockIdx.y;
    const int i0  = blockIdx.x * 64;
    const int tid = threadIdx.x;
    const int il  = tid & 63;
    const int jg  = tid >> 6;
    const float* fb = feat + (size_t)b * NPT * C;

    __shared__ float sP[TJ][CP];
    __shared__ float sPn[TJ];
    __shared__ float sMd[64][KNB + 1];
    __shared__ int   sMi[64][KNB + 1];

    float q[C];
    {
        const float* qp = fb + (size_t)(i0 + il) * C;
#pragma unroll
        for (int c = 0; c < C; ++c) q[c] = qp[c];
    }

    float bd[KNB]; int bi[KNB];
#pragma unroll
    for (int t = 0; t < KNB; ++t) { bd[t] = 1e30f; bi[t] = 0; }
    float mx = 1e30f; int mp = 0;

    auto insert = [&](float d, int j) {
#pragma unroll
        for (int t = 0; t < KNB; ++t) if (t == mp) { bd[t] = d; bi[t] = j; }
        mx = -1e30f;
#pragma unroll
        for (int t = 0; t < KNB; ++t) if (bd[t] > mx) { mx = bd[t]; mp = t; }
    };

    for (int j0 = js * JL; j0 < (js + 1) * JL; j0 += TJ) {
        __syncthreads();
        for (int t = tid; t < TJ * C; t += 256) {
            int r = t / C, c = t - r * C;
            sP[r][c] = fb[(size_t)j0 * C + t];
        }
        if (tid < TJ) sPn[tid] = norms[b * NPT + j0 + tid];
        __syncthreads();
#pragma unroll 1
        for (int jj = 0; jj < JPT; ++jj) {
            const int jl = jg * JPT + jj;
            float dot = 0.f;
#pragma unroll
            for (int c = 0; c < C; ++c) dot = fmaf(q[c], sP[jl][c], dot);
            const float d = fmaf(-2.f, dot, sPn[jl]);
            if (d < mx) insert(d, j0 + jl);
        }
    }

#pragma unroll 1
    for (int r = 1; r < 4; ++r) {
        __syncthreads();
        if (jg == r) {
#pragma unroll
            for (int t = 0; t < KNB; ++t) { sMd[il][t] = bd[t]; sMi[il][t] = bi[t]; }
        }
        __syncthreads();
        if (jg == 0) {
#pragma unroll 1
            for (int t = 0; t < KNB; ++t) {
                const float d = sMd[il][t];
                if (d < mx) insert(d, sMi[il][t]);
            }
        }
    }
    if (jg == 0) {
        const size_t base = (((size_t)b * NPT + i0 + il) * JS + js) * KNB;
#pragma unroll
        for (int t = 0; t < KNB; ++t) { cand_d[base + t] = bd[t]; cand_i[base + t] = bi[t]; }
    }
}

// ---------------------------------------------------------------------------
// KNN scores via bf16 MFMA, C in {32,128}, j-split JS ways (proven in R5).
// ---------------------------------------------------------------------------
template<int C, int JS>
__launch_bounds__(256)
__global__ void knn_mfma_kernel(const unsigned short* __restrict__ fb16,
                                const float* __restrict__ norms,
                                float* __restrict__ cand_d,
                                int* __restrict__ cand_i) {
    constexpr int JL = NPT / JS;
    constexpr int KS = C / 32;
    const int b    = blockIdx.z;
    const int js   = blockIdx.y;
    const int i0   = blockIdx.x * 64;
    const int t    = threadIdx.x;
    const int w    = t >> 6;
    const int lane = t & 63;
    const int l15  = lane & 15;
    const int quad = lane >> 4;
    const int sr   = t >> 2, lp = t & 3;
    const unsigned short* fbb = fb16 + (size_t)b * NPT * C;
    const float* nb = norms + (size_t)b * NPT;

    __shared__ __align__(16) float sS[64][68];
    float (*sMd)[17] = (float (*)[17]) & sS[0][0];
    int   (*sMi)[17] = (int   (*)[17]) & sS[32][0];

    bf16x8 afr[KS * 4];
#pragma unroll
    for (int ks = 0; ks < KS; ++ks)
#pragma unroll
        for (int mi = 0; mi < 4; ++mi)
            afr[ks * 4 + mi] = *(const bf16x8*)(fbb + (size_t)(i0 + mi * 16 + l15) * C + ks * 32 + quad * 8);

    float bd[KNB]; int bi[KNB];
#pragma unroll
    for (int u = 0; u < KNB; ++u) { bd[u] = 1e30f; bi[u] = 0; }
    float mx = 1e30f; int mp = 0;

    auto insert = [&](float d, int j) {
#pragma unroll
        for (int u = 0; u < KNB; ++u) if (u == mp) { bd[u] = d; bi[u] = j; }
        mx = -1e30f;
#pragma unroll
        for (int u = 0; u < KNB; ++u) if (bd[u] > mx) { mx = bd[u]; mp = u; }
    };

    const int jend = (js + 1) * JL;
#pragma unroll 1
    for (int j0 = js * JL; j0 < jend; j0 += 64) {
        f32x4 acc[4];
#pragma unroll
        for (int mi = 0; mi < 4; ++mi) acc[mi] = (f32x4){0.f, 0.f, 0.f, 0.f};
        const unsigned short* prow = fbb + (size_t)(j0 + w * 16 + l15) * C + quad * 8;
#pragma unroll
        for (int ks = 0; ks < KS; ++ks) {
            const bf16x8 bfr = *(const bf16x8*)(prow + ks * 32);
#pragma unroll
            for (int mi = 0; mi < 4; ++mi)
                acc[mi] = __builtin_amdgcn_mfma_f32_16x16x32_bf16(afr[ks * 4 + mi], bfr, acc[mi], 0, 0, 0);
        }
        const float nv = nb[j0 + w * 16 + l15];
        __syncthreads();
#pragma unroll
        for (int mi = 0; mi < 4; ++mi)
#pragma unroll
            for (int r = 0; r < 4; ++r)
                sS[mi * 16 + quad * 4 + r][w * 16 + l15] = fmaf(-2.f, acc[mi][r], nv);
        __syncthreads();
#pragma unroll
        for (int jj = 0; jj < 16; ++jj) {
            const float d = sS[sr][4 * jj + lp];
            if (d < mx) insert(d, j0 + 4 * jj + lp);
        }
    }

#pragma unroll 1
    for (int r = 1; r < 4; ++r) {
        __syncthreads();
        if (lp == r) {
#pragma unroll
            for (int u = 0; u < KNB; ++u) { sMd[sr][u] = bd[u]; sMi[sr][u] = bi[u]; }
        }
        __syncthreads();
        if (lp == 0) {
#pragma unroll 1
            for (int u = 0; u < KNB; ++u) {
                const float d = sMd[sr][u];
                if (d < mx) insert(d, sMi[sr][u]);
            }
        }
    }
    if (lp == 0) {
        const size_t base = (((size_t)b * NPT + i0 + sr) * JS + js) * KNB;
#pragma unroll
        for (int u = 0; u < KNB; ++u) { cand_d[base + u] = bd[u]; cand_i[base + u] = bi[u]; }
    }
}

// ---------------------------------------------------------------------------
// Merge JS provisional top-16 lists per query -> final top-16 indices.
// ---------------------------------------------------------------------------
template<int JS>
__launch_bounds__(256)
__global__ void knn_merge_kernel(const float* __restrict__ cand_d,
                                 const int* __restrict__ cand_i,
                                 int* __restrict__ knn_out) {
    const int q = blockIdx.x * 256 + threadIdx.x;
    float bd[KNB]; int bi[KNB];
#pragma unroll
    for (int u = 0; u < KNB; ++u) { bd[u] = 1e30f; bi[u] = 0; }
    float mx = 1e30f; int mp = 0;

    auto insert = [&](float d, int j) {
#pragma unroll
        for (int u = 0; u < KNB; ++u) if (u == mp) { bd[u] = d; bi[u] = j; }
        mx = -1e30f;
#pragma unroll
        for (int u = 0; u < KNB; ++u) if (bd[u] > mx) { mx = bd[u]; mp = u; }
    };

    const float* pd = cand_d + (size_t)q * JS * KNB;
    const int*   pi = cand_i + (size_t)q * JS * KNB;
#pragma unroll 1
    for (int u = 0; u < JS * KNB; ++u) {
        const float d = pd[u];
        if (d < mx) insert(d, pi[u]);
    }
    int* o = knn_out + (size_t)q * KNB;
#pragma unroll
    for (int u = 0; u < KNB; ++u) o[u] = bi[u];
}

// ---------------------------------------------------------------------------
// Block 1: concat(x_i(3), x_j(3)) -> 16 -> 64 -> 32, lrelu each, sum over k.
// ---------------------------------------------------------------------------
__launch_bounds__(256)
__global__ void block1_kernel(const float* __restrict__ x, const int* __restrict__ knn,
                              const float* __restrict__ w1, const float* __restrict__ b1,
                              const float* __restrict__ w2, const float* __restrict__ b2,
                              const float* __restrict__ w3, const float* __restrict__ b3,
                              float* __restrict__ x2out) {
    __shared__ float sw1[96], sb1[16], sw2[1024], sb2[64], sw3[2048], sb3[32];
    __shared__ float sh[16][16][32];
    const int tid = threadIdx.x;
    for (int t = tid; t < 96;  t += 256) sw1[t] = w1[t];
    if (tid < 16) sb1[tid] = b1[tid];
    for (int t = tid; t < 1024; t += 256) sw2[t] = w2[t];
    if (tid < 64) sb2[tid] = b2[tid];
    for (int t = tid; t < 2048; t += 256) sw3[t] = w3[t];
    if (tid < 32) sb3[tid] = b3[tid];
    __syncthreads();

    const int pt = tid >> 4, k = tid & 15;
    const int bn = blockIdx.x * 16 + pt;
    const int b  = bn >> 11, n = bn & (NPT - 1);
    const float* xb = x + (size_t)b * NPT * 3;
    const int j = knn[(size_t)bn * KNB + k];

    float in6[6] = { xb[n*3+0], xb[n*3+1], xb[n*3+2],
                     xb[j*3+0], xb[j*3+1], xb[j*3+2] };
    float h1[16];
#pragma unroll
    for (int o = 0; o < 16; ++o) {
        float a = sb1[o];
#pragma unroll
        for (int i = 0; i < 6; ++i) a = fmaf(in6[i], sw1[i * 16 + o], a);
        h1[o] = lrelu(a);
    }
    float h2[64];
#pragma unroll
    for (int o = 0; o < 64; ++o) {
        float a = sb2[o];
#pragma unroll
        for (int i = 0; i < 16; ++i) a = fmaf(h1[i], sw2[i * 64 + o], a);
        h2[o] = lrelu(a);
    }
#pragma unroll
    for (int o = 0; o < 32; ++o) {
        float a = sb3[o];
#pragma unroll
        for (int i = 0; i < 64; ++i) a = fmaf(h2[i], sw3[i * 32 + o], a);
        sh[pt][k][o] = lrelu(a);
    }
    __syncthreads();
    for (int t = tid; t < 16 * 32; t += 256) {
        int p2 = t >> 5, o = t & 31;
        float s = 0.f;
#pragma unroll
        for (int kk = 0; kk < 16; ++kk) s += sh[p2][kk][o];
        x2out[(size_t)(blockIdx.x * 16 + p2) * 32 + o] = s;
    }
}

// ---------------------------------------------------------------------------
// Block 2 via MFMA. Block = 4 points x 4 waves; wave w owns point
// blockIdx.x*4+w with its 16 neighbor rows.
// Layer1 in TWO HALVES of 8 output-tiles (caps live accumulators at 32 regs;
// R6 fix: unroll-4 over 16 tiles held 64 acc regs live -> scratch spill ->
// 488 MB HBM writes/dispatch). __launch_bounds__(256,2): VGPR budget 256.
// ---------------------------------------------------------------------------
__launch_bounds__(256, 2)
__global__ void block2_mfma_kernel(const unsigned short* __restrict__ x2b,
                                   const int* __restrict__ knn,
                                   const unsigned short* __restrict__ w1t,  // [256][64]
                                   const float* __restrict__ b1,
                                   const unsigned short* __restrict__ w2t,  // [128][256]
                                   const float* __restrict__ b2,
                                   float* __restrict__ x3) {
    const int w    = threadIdx.x >> 6;
    const int lane = threadIdx.x & 63;
    const int l15  = lane & 15, quad = lane >> 4;
    const int p    = blockIdx.x * 4 + w;
    const int b    = p >> 11;
    __shared__ __align__(16) unsigned short sH1[64][264];

    const int nbr = knn[(size_t)p * KNB + l15];
    const bf16x8 a0 = *(const bf16x8*)(x2b + (size_t)p * 32 + quad * 8);
    const bf16x8 a1 = *(const bf16x8*)(x2b + ((size_t)(b * NPT) + nbr) * 32 + quad * 8);

    // ---- layer 1: two halves of 8 tiles ----
#pragma unroll 1
    for (int h = 0; h < 2; ++h) {
        f32x4 acc1[8];
#pragma unroll
        for (int nt = 0; nt < 8; ++nt) acc1[nt] = (f32x4){0.f, 0.f, 0.f, 0.f};
#pragma unroll
        for (int nt = 0; nt < 8; ++nt) {
            const unsigned short* wp = w1t + (size_t)((h * 8 + nt) * 16 + l15) * 64 + quad * 8;
            const bf16x8 b0 = *(const bf16x8*)wp;
            const bf16x8 b1f = *(const bf16x8*)(wp + 32);
            acc1[nt] = __builtin_amdgcn_mfma_f32_16x16x32_bf16(a0, b0, acc1[nt], 0, 0, 0);
            acc1[nt] = __builtin_amdgcn_mfma_f32_16x16x32_bf16(a1, b1f, acc1[nt], 0, 0, 0);
        }
#pragma unroll
        for (int nt = 0; nt < 8; ++nt) {
            const float bv = b1[(h * 8 + nt) * 16 + l15];
#pragma unroll
            for (int r = 0; r < 4; ++r)
                sH1[w * 16 + quad * 4 + r][(h * 8 + nt) * 16 + l15] = bf16rne(lrelu(acc1[nt][r] + bv));
        }
    }
    __syncthreads();

    // ---- layer 2 ----
    f32x4 acc2[8];
#pragma unroll
    for (int nt = 0; nt < 8; ++nt) acc2[nt] = (f32x4){0.f, 0.f, 0.f, 0.f};
#pragma unroll 2
    for (int ks = 0; ks < 8; ++ks) {
        const bf16x8 a = *(const bf16x8*)&sH1[w * 16 + l15][ks * 32 + quad * 8];
#pragma unroll
        for (int nt = 0; nt < 8; ++nt) {
            const bf16x8 bb = *(const bf16x8*)(w2t + (size_t)(nt * 16 + l15) * 256 + ks * 32 + quad * 8);
            acc2[nt] = __builtin_amdgcn_mfma_f32_16x16x32_bf16(a, bb, acc2[nt], 0, 0, 0);
        }
    }
#pragma unroll
    for (int nt = 0; nt < 8; ++nt) {
        const float bv = b2[nt * 16 + l15];
        float s = 0.f;
#pragma unroll
        for (int r = 0; r < 4; ++r) s += lrelu(acc2[nt][r] + bv);
        s += __shfl_xor(s, 16);
        s += __shfl_xor(s, 32);
        if (quad == 0) x3[(size_t)p * 128 + nt * 16 + l15] = s;
    }
}

// ---------------------------------------------------------------------------
// Block 3 via MFMA: [16x256] @ W3[256x128], A streamed from bf16 x3
// (cols 0..127 center broadcast, 128..255 neighbor gather). No LDS/barriers.
// ---------------------------------------------------------------------------
__launch_bounds__(256, 2)
__global__ void block3_mfma_kernel(const unsigned short* __restrict__ x3b,
                                   const int* __restrict__ knn,
                                   const unsigned short* __restrict__ w3t,  // [128][256]
                                   const float* __restrict__ bias,
                                   float* __restrict__ x4) {
    const int w    = threadIdx.x >> 6;
    const int lane = threadIdx.x & 63;
    const int l15  = lane & 15, quad = lane >> 4;
    const int p    = blockIdx.x * 4 + w;
    const int b    = p >> 11;

    const int nbr = knn[(size_t)p * KNB + l15];
    const unsigned short* ctr = x3b + (size_t)p * 128 + quad * 8;
    const unsigned short* nbp = x3b + ((size_t)(b * NPT) + nbr) * 128 + quad * 8;

    f32x4 acc[8];
#pragma unroll
    for (int nt = 0; nt < 8; ++nt) acc[nt] = (f32x4){0.f, 0.f, 0.f, 0.f};
#pragma unroll 2
    for (int ks = 0; ks < 8; ++ks) {
        const bf16x8 a = (ks < 4) ? *(const bf16x8*)(ctr + ks * 32)
                                  : *(const bf16x8*)(nbp + (ks - 4) * 32);
#pragma unroll
        for (int nt = 0; nt < 8; ++nt) {
            const bf16x8 bb = *(const bf16x8*)(w3t + (size_t)(nt * 16 + l15) * 256 + ks * 32 + quad * 8);
            acc[nt] = __builtin_amdgcn_mfma_f32_16x16x32_bf16(a, bb, acc[nt], 0, 0, 0);
        }
    }
#pragma unroll
    for (int nt = 0; nt < 8; ++nt) {
        const float bv = bias[nt * 16 + l15];
        float s = 0.f;
#pragma unroll
        for (int r = 0; r < 4; ++r) s += lrelu(acc[nt][r] + bv);
        s += __shfl_xor(s, 16);
        s += __shfl_xor(s, 32);
        if (quad == 0) x4[(size_t)p * 128 + nt * 16 + l15] = s;
    }
}

// ---------------------------------------------------------------------------
// Maxpool stage 1
// ---------------------------------------------------------------------------
__launch_bounds__(128)
__global__ void maxpool_partial_kernel(const float* __restrict__ x4,
                                       float* __restrict__ part) {
    const int chunk = blockIdx.x, b = blockIdx.y, t = threadIdx.x;
    const float* xb = x4 + ((size_t)b * NPT + (size_t)chunk * 128) * 128;
    float m = -1e30f;
#pragma unroll 8
    for (int n = 0; n < 128; ++n) m = fmaxf(m, xb[(size_t)n * 128 + t]);
    part[((size_t)b * 16 + chunk) * 128 + t] = m;
}

// ---------------------------------------------------------------------------
// Head stage 2
// ---------------------------------------------------------------------------
__launch_bounds__(128)
__global__ void head2_kernel(const float* __restrict__ part,
                             const float* __restrict__ fc1w, const float* __restrict__ fc1b,
                             const float* __restrict__ fc2w, const float* __restrict__ fc2b,
                             const float* __restrict__ fc3w, const float* __restrict__ fc3b,
                             float* __restrict__ out) {
    const int g = blockIdx.x, b = blockIdx.y, t = threadIdx.x;
    __shared__ float s5[128], s6[128], s7[128];
    float m = -1e30f;
#pragma unroll
    for (int c = 0; c < 16; ++c)
        m = fmaxf(m, part[((size_t)b * 16 + c) * 128 + t]);
    s5[t] = m;
    __syncthreads();
    float a = fc1b[t];
#pragma unroll 4
    for (int i = 0; i < 128; ++i) a = fmaf(s5[i], fc1w[i * 128 + t], a);
    s6[t] = lrelu(a);
    __syncthreads();
    a = fc2b[t];
#pragma unroll 4
    for (int i = 0; i < 128; ++i) a = fmaf(s6[i], fc2w[i * 128 + t], a);
    s7[t] = lrelu(a);
    __syncthreads();
    const int o = g * 128 + t;
    float acc = fc3b[o];
#pragma unroll 4
    for (int i = 0; i < 128; ++i) acc = fmaf(s7[i], fc3w[(size_t)i * 6144 + o], acc);
    out[(size_t)b * 6144 + o] = acc;
}

// ---------------------------------------------------------------------------
extern "C" void kernel_launch(void* const* d_in, const int* in_sizes, int n_in,
                              void* d_out, int out_size, void* d_ws, size_t ws_size,
                              hipStream_t stream) {
    const float* x    = (const float*)d_in[0];
    const float* h1w1 = (const float*)d_in[1];
    const float* h1b1 = (const float*)d_in[2];
    const float* h1w2 = (const float*)d_in[3];
    const float* h1b2 = (const float*)d_in[4];
    const float* h1w3 = (const float*)d_in[5];
    const float* h1b3 = (const float*)d_in[6];
    const float* h2w1 = (const float*)d_in[7];
    const float* h2b1 = (const float*)d_in[8];
    const float* h2w2 = (const float*)d_in[9];
    const float* h2b2 = (const float*)d_in[10];
    const float* h3w1 = (const float*)d_in[11];
    const float* h3b1 = (const float*)d_in[12];
    const float* fc1w = (const float*)d_in[13];
    const float* fc1b = (const float*)d_in[14];
    const float* fc2w = (const float*)d_in[15];
    const float* fc2b = (const float*)d_in[16];
    const float* fc3w = (const float*)d_in[17];
    const float* fc3b = (const float*)d_in[18];

    float* ws  = (float*)d_ws;
    float* x2  = ws;                      //  524288 floats
    float* x3  = ws + 524288;             // 2097152 floats
    float* x4  = ws + 2621440;            // 2097152 floats
    int*   idx = (int*)(ws + 4718592);    //  262144 ints
    float* nrm = ws + 4980736;            //   16384 floats
    float* part= ws + 4997120;            //   16384 floats
    unsigned short* fb16 = (unsigned short*)(ws + 5013504); // 2M shorts (1M float slots)
    unsigned short* w1t  = (unsigned short*)(ws + 6062080); // 16384 shorts
    unsigned short* w2t  = (unsigned short*)(ws + 6070272); // 32768 shorts
    unsigned short* w3t  = (unsigned short*)(ws + 6086656); // 32768 shorts
    // candidate buffers alias the x4 region (free until block3 runs)
    float* cd  = ws + 2621440;            // 1048576 floats
    int*   ci  = (int*)(ws + 3670016);    // 1048576 ints
    float* out = (float*)d_out;

    const dim3 kg(32, 4, 8);   // (qtile, j-split, batch)

    // weight prep (tiny; L2-resident afterwards)
    wprep_kernel<<<64, 256, 0, stream>>>(h2w1, w1t, 64, 256);
    wprep_kernel<<<128, 256, 0, stream>>>(h2w2, w2t, 256, 128);
    wprep_kernel<<<128, 256, 0, stream>>>(h3w1, w3t, 256, 128);

    norms_kernel<3><<<64, 256, 0, stream>>>(x, nrm);
    knn_kernel<3, 64, 4><<<kg, 256, 0, stream>>>(x, nrm, cd, ci);
    knn_merge_kernel<4><<<64, 256, 0, stream>>>(cd, ci, idx);
    block1_kernel<<<1024, 256, 0, stream>>>(x, idx, h1w1, h1b1, h1w2, h1b2, h1w3, h1b3, x2);

    tobf16_kernel<<<2048, 256, 0, stream>>>(x2, fb16, BSZ * NPT * 32);
    norms16_kernel<32><<<64, 256, 0, stream>>>(fb16, nrm);
    knn_mfma_kernel<32, 4><<<kg, 256, 0, stream>>>(fb16, nrm, cd, ci);
    knn_merge_kernel<4><<<64, 256, 0, stream>>>(cd, ci, idx);
    block2_mfma_kernel<<<BSZ * NPT / 4, 256, 0, stream>>>(fb16, idx, w1t, h2b1, w2t, h2b2, x3);

    tobf16_kernel<<<8192, 256, 0, stream>>>(x3, fb16, BSZ * NPT * 128);
    norms16_kernel<128><<<64, 256, 0, stream>>>(fb16, nrm);
    knn_mfma_kernel<128, 4><<<kg, 256, 0, stream>>>(fb16, nrm, cd, ci);
    knn_merge_kernel<4><<<64, 256, 0, stream>>>(cd, ci, idx);
    block3_mfma_kernel<<<BSZ * NPT / 4, 256, 0, stream>>>(fb16, idx, w3t, h3b1, x4);

    maxpool_partial_kernel<<<dim3(16, 8), 128, 0, stream>>>(x4, part);
    head2_kernel<<<dim3(48, 8), 128, 0, stream>>>(part, fc1w, fc1b, fc2w, fc2b,
                                                  fc3w, fc3b, out);
}

// Round 8
// 769.871 us; speedup vs baseline: 3.9655x; 1.6737x over previous
//
#include <hip/hip_runtime.h>

#define KNB 16
#define BSZ 8
#define NPT 2048

typedef __attribute__((ext_vector_type(8))) short bf16x8;
typedef __attribute__((ext_vector_type(4))) float f32x4;

__device__ __forceinline__ float lrelu(float x) { return x >= 0.f ? x : 0.01f * x; }

__device__ __forceinline__ unsigned short bf16rne(float f) {
    union { float f; unsigned int u; } v; v.f = f;
    return (unsigned short)((v.u + 0x7FFFu + ((v.u >> 16) & 1u)) >> 16);
}

// pack candidate index into low 11 mantissa bits of fp32 score -> unique,
// float-comparable key. idx = bits & 2047.
__device__ __forceinline__ float packkey(float d, int idx) {
    union { float f; unsigned int u; } v; v.f = d;
    v.u = (v.u & 0xFFFFF800u) | (unsigned int)idx;
    return v.f;
}

__device__ __forceinline__ float max16(const float* L) {
    float m = L[0];
#pragma unroll
    for (int u = 1; u < 16; ++u) m = fmaxf(m, L[u]);
    return m;
}

// ---------------------------------------------------------------------------
// fp32 -> bf16 (RNE), flat
// ---------------------------------------------------------------------------
__global__ void tobf16_kernel(const float* __restrict__ in, unsigned short* __restrict__ out, int n) {
    int i = blockIdx.x * 256 + threadIdx.x;
    if (i < n) out[i] = bf16rne(in[i]);
}

// ---------------------------------------------------------------------------
// Weight prep: w[K][N] fp32 -> wt[N][K] bf16
// ---------------------------------------------------------------------------
__global__ void wprep_kernel(const float* __restrict__ w, unsigned short* __restrict__ wt,
                             int K, int N) {
    int i = blockIdx.x * 256 + threadIdx.x;
    if (i < K * N) { int k = i / N, n = i - k * N; wt[n * K + k] = bf16rne(w[i]); }
}

// ---------------------------------------------------------------------------
// Per-point squared norms
// ---------------------------------------------------------------------------
template<int C>
__global__ void norms16_kernel(const unsigned short* __restrict__ feat, float* __restrict__ out) {
    int gid = blockIdx.x * blockDim.x + threadIdx.x;
    if (gid < BSZ * NPT) {
        const unsigned short* p = feat + (size_t)gid * C;
        float s = 0.f;
#pragma unroll
        for (int c = 0; c < C; ++c) {
            union { unsigned int u; float f; } v; v.u = ((unsigned int)p[c]) << 16;
            s = fmaf(v.f, v.f, s);
        }
        out[gid] = s;
    }
}

template<int C>
__global__ void norms_kernel(const float* __restrict__ feat, float* __restrict__ out) {
    int gid = blockIdx.x * blockDim.x + threadIdx.x;
    if (gid < BSZ * NPT) {
        const float* p = feat + (size_t)gid * C;
        float s = 0.f;
#pragma unroll
        for (int c = 0; c < C; ++c) s = fmaf(p[c], p[c], s);
        out[gid] = s;
    }
}

// ---------------------------------------------------------------------------
// KNN C=3, fp32, j-split JS. Wave w scans a contiguous quarter of the js
// range (j-loads wave-uniform -> L1 broadcast; no staging LDS, no in-loop
// barriers). Packed-key top-16 per lane; cross-wave merge at end.
// ---------------------------------------------------------------------------
template<int JS>
__launch_bounds__(256, 3)
__global__ void knn3_kernel(const float* __restrict__ feat,
                            const float* __restrict__ norms,
                            float* __restrict__ cand) {
    constexpr int JL = NPT / JS;
    constexpr int JP = JL / 4;
    const int b = blockIdx.z, js = blockIdx.y, i0 = blockIdx.x * 64;
    const int t = threadIdx.x, w = t >> 6, lane = t & 63;
    const float* fb = feat + (size_t)b * NPT * 3;
    const float* nb = norms + (size_t)b * NPT;

    __shared__ float sS[4][64][17];

    float q0, q1, q2;
    { const float* qp = fb + (size_t)(i0 + lane) * 3; q0 = qp[0]; q1 = qp[1]; q2 = qp[2]; }

    float L[16];
    const int jbeg = js * JL + w * JP;
#pragma unroll
    for (int jj = 0; jj < 16; ++jj) {
        const int j = jbeg + jj;
        const float* pp = fb + (size_t)j * 3;
        const float d = fmaf(-2.f, fmaf(q0, pp[0], fmaf(q1, pp[1], q2 * pp[2])), nb[j]);
        L[jj] = packkey(d, j);
    }
    float mx = max16(L);

#pragma unroll 2
    for (int jj = 16; jj < JP; ++jj) {
        const int j = jbeg + jj;
        const float* pp = fb + (size_t)j * 3;
        const float d = fmaf(-2.f, fmaf(q0, pp[0], fmaf(q1, pp[1], q2 * pp[2])), nb[j]);
        const float k = packkey(d, j);
        if (k < mx) {
#pragma unroll
            for (int u = 0; u < 16; ++u) L[u] = (L[u] == mx) ? k : L[u];
            mx = max16(L);
        }
    }

    // cross-wave merge (rows = lanes)
#pragma unroll
    for (int c = 0; c < 16; ++c) sS[w][lane][c] = L[c];
    __syncthreads();
    if (w == 0 || w == 2) {
#pragma unroll
        for (int c = 0; c < 16; ++c) {
            const float k = sS[w + 1][lane][c];
            if (k < mx) {
#pragma unroll
                for (int u = 0; u < 16; ++u) L[u] = (L[u] == mx) ? k : L[u];
                mx = max16(L);
            }
        }
        if (w == 2) {
#pragma unroll
            for (int c = 0; c < 16; ++c) sS[2][lane][c] = L[c];
        }
    }
    __syncthreads();
    if (w == 0) {
#pragma unroll
        for (int c = 0; c < 16; ++c) {
            const float k = sS[2][lane][c];
            if (k < mx) {
#pragma unroll
                for (int u = 0; u < 16; ++u) L[u] = (L[u] == mx) ? k : L[u];
                mx = max16(L);
            }
        }
        float* o = cand + (((size_t)b * NPT + i0 + lane) * JS + js) * 16;
#pragma unroll
        for (int c = 0; c < 16; ++c) o[c] = L[c];
    }
}

// ---------------------------------------------------------------------------
// KNN via bf16 MFMA, C in {32,128}, j-split JS. Wave w owns cols
// [w*16,w*16+16) of each 64x64 tile: MFMA -> pack(score,idx) -> wave-PRIVATE
// LDS strip (stride 17; same-wave in-order LDS => NO barrier) -> per-lane
// (lane=row) packed-key top-16 of this wave's columns. Zero barriers in the
// K-loop. Cross-wave merge at the end (2 barriers total).
// ---------------------------------------------------------------------------
template<int C, int JS>
__launch_bounds__(256, 3)
__global__ void knn_mfma_kernel(const unsigned short* __restrict__ fb16,
                                const float* __restrict__ norms,
                                float* __restrict__ cand) {
    constexpr int JL = NPT / JS;
    constexpr int KS = C / 32;
    const int b    = blockIdx.z;
    const int js   = blockIdx.y;
    const int i0   = blockIdx.x * 64;
    const int t    = threadIdx.x;
    const int w    = t >> 6;
    const int lane = t & 63;
    const int l15  = lane & 15;
    const int quad = lane >> 4;
    const unsigned short* fbb = fb16 + (size_t)b * NPT * C;
    const float* nb = norms + (size_t)b * NPT;

    __shared__ float sS[4][64][17];

    // A fragments: query rows, loaded once per block
    bf16x8 afr[KS * 4];
#pragma unroll
    for (int ks = 0; ks < KS; ++ks)
#pragma unroll
        for (int mi = 0; mi < 4; ++mi)
            afr[ks * 4 + mi] = *(const bf16x8*)(fbb + (size_t)(i0 + mi * 16 + l15) * C + ks * 32 + quad * 8);

    float L[16];
#pragma unroll
    for (int u = 0; u < 16; ++u) L[u] = 3e38f;
    float mx = 3e38f;

    const int jbeg = js * JL;
#pragma unroll 1
    for (int j0 = jbeg; j0 < jbeg + JL; j0 += 64) {
        f32x4 acc[4];
#pragma unroll
        for (int mi = 0; mi < 4; ++mi) acc[mi] = (f32x4){0.f, 0.f, 0.f, 0.f};
        const unsigned short* prow = fbb + (size_t)(j0 + w * 16 + l15) * C + quad * 8;
#pragma unroll
        for (int ks = 0; ks < KS; ++ks) {
            const bf16x8 bfr = *(const bf16x8*)(prow + ks * 32);
#pragma unroll
            for (int mi = 0; mi < 4; ++mi)
                acc[mi] = __builtin_amdgcn_mfma_f32_16x16x32_bf16(afr[ks * 4 + mi], bfr, acc[mi], 0, 0, 0);
        }
        const float nv  = nb[j0 + w * 16 + l15];
        const int  cidx = j0 + w * 16 + l15;          // 0..2047, fits 11 bits
        // C/D layout: col=lane&15, row=quad*4+reg (+16*mi). Write packed keys
        // into this wave's private strip; read back transposed (lane=row).
#pragma unroll
        for (int mi = 0; mi < 4; ++mi)
#pragma unroll
            for (int r = 0; r < 4; ++r)
                sS[w][mi * 16 + quad * 4 + r][l15] = packkey(fmaf(-2.f, acc[mi][r], nv), cidx);
        float k0[16];
#pragma unroll
        for (int c = 0; c < 16; ++c) k0[c] = sS[w][lane][c];
        if (j0 == jbeg) {
#pragma unroll
            for (int c = 0; c < 16; ++c) L[c] = k0[c];
            mx = max16(L);
        } else {
#pragma unroll
            for (int c = 0; c < 16; ++c) {
                const float k = k0[c];
                if (k < mx) {
#pragma unroll
                    for (int u = 0; u < 16; ++u) L[u] = (L[u] == mx) ? k : L[u];
                    mx = max16(L);
                }
            }
        }
    }

    // cross-wave merge: per row, 4 column-partition lists -> 16
#pragma unroll
    for (int c = 0; c < 16; ++c) sS[w][lane][c] = L[c];
    __syncthreads();
    if (w == 0 || w == 2) {
#pragma unroll
        for (int c = 0; c < 16; ++c) {
            const float k = sS[w + 1][lane][c];
            if (k < mx) {
#pragma unroll
                for (int u = 0; u < 16; ++u) L[u] = (L[u] == mx) ? k : L[u];
                mx = max16(L);
            }
        }
        if (w == 2) {
#pragma unroll
            for (int c = 0; c < 16; ++c) sS[2][lane][c] = L[c];
        }
    }
    __syncthreads();
    if (w == 0) {
#pragma unroll
        for (int c = 0; c < 16; ++c) {
            const float k = sS[2][lane][c];
            if (k < mx) {
#pragma unroll
                for (int u = 0; u < 16; ++u) L[u] = (L[u] == mx) ? k : L[u];
                mx = max16(L);
            }
        }
        float* o = cand + (((size_t)b * NPT + i0 + lane) * JS + js) * 16;
#pragma unroll
        for (int c = 0; c < 16; ++c) o[c] = L[c];
    }
}

// ---------------------------------------------------------------------------
// Merge JS packed-key lists per query -> final top-16 indices.
// ---------------------------------------------------------------------------
template<int JS>
__launch_bounds__(256)
__global__ void knn_merge_kernel(const float* __restrict__ cand, int* __restrict__ knn_out) {
    const int q = blockIdx.x * 256 + threadIdx.x;
    const float* pd = cand + (size_t)q * JS * 16;
    float L[16];
#pragma unroll
    for (int u = 0; u < 16; ++u) L[u] = pd[u];
    float mx = max16(L);
#pragma unroll 2
    for (int u = 16; u < JS * 16; ++u) {
        const float k = pd[u];
        if (k < mx) {
#pragma unroll
            for (int v = 0; v < 16; ++v) L[v] = (L[v] == mx) ? k : L[v];
            mx = max16(L);
        }
    }
    int* o = knn_out + (size_t)q * KNB;
#pragma unroll
    for (int u = 0; u < 16; ++u) {
        union { float f; unsigned int v; } z; z.f = L[u];
        o[u] = (int)(z.v & 2047u);
    }
}

// ---------------------------------------------------------------------------
// Block 1: concat(x_i(3), x_j(3)) -> 16 -> 64 -> 32, lrelu each, sum over k.
// ---------------------------------------------------------------------------
__launch_bounds__(256)
__global__ void block1_kernel(const float* __restrict__ x, const int* __restrict__ knn,
                              const float* __restrict__ w1, const float* __restrict__ b1,
                              const float* __restrict__ w2, const float* __restrict__ b2,
                              const float* __restrict__ w3, const float* __restrict__ b3,
                              float* __restrict__ x2out) {
    __shared__ float sw1[96], sb1[16], sw2[1024], sb2[64], sw3[2048], sb3[32];
    __shared__ float sh[16][16][32];
    const int tid = threadIdx.x;
    for (int t = tid; t < 96;  t += 256) sw1[t] = w1[t];
    if (tid < 16) sb1[tid] = b1[tid];
    for (int t = tid; t < 1024; t += 256) sw2[t] = w2[t];
    if (tid < 64) sb2[tid] = b2[tid];
    for (int t = tid; t < 2048; t += 256) sw3[t] = w3[t];
    if (tid < 32) sb3[tid] = b3[tid];
    __syncthreads();

    const int pt = tid >> 4, k = tid & 15;
    const int bn = blockIdx.x * 16 + pt;
    const int b  = bn >> 11, n = bn & (NPT - 1);
    const float* xb = x + (size_t)b * NPT * 3;
    const int j = knn[(size_t)bn * KNB + k];

    float in6[6] = { xb[n*3+0], xb[n*3+1], xb[n*3+2],
                     xb[j*3+0], xb[j*3+1], xb[j*3+2] };
    float h1[16];
#pragma unroll
    for (int o = 0; o < 16; ++o) {
        float a = sb1[o];
#pragma unroll
        for (int i = 0; i < 6; ++i) a = fmaf(in6[i], sw1[i * 16 + o], a);
        h1[o] = lrelu(a);
    }
    float h2[64];
#pragma unroll
    for (int o = 0; o < 64; ++o) {
        float a = sb2[o];
#pragma unroll
        for (int i = 0; i < 16; ++i) a = fmaf(h1[i], sw2[i * 64 + o], a);
        h2[o] = lrelu(a);
    }
#pragma unroll
    for (int o = 0; o < 32; ++o) {
        float a = sb3[o];
#pragma unroll
        for (int i = 0; i < 64; ++i) a = fmaf(h2[i], sw3[i * 32 + o], a);
        sh[pt][k][o] = lrelu(a);
    }
    __syncthreads();
    for (int t = tid; t < 16 * 32; t += 256) {
        int p2 = t >> 5, o = t & 31;
        float s = 0.f;
#pragma unroll
        for (int kk = 0; kk < 16; ++kk) s += sh[p2][kk][o];
        x2out[(size_t)(blockIdx.x * 16 + p2) * 32 + o] = s;
    }
}

// ---------------------------------------------------------------------------
// Block 2 via MFMA (R7: layer1 split into two halves; no spill).
// ---------------------------------------------------------------------------
__launch_bounds__(256, 2)
__global__ void block2_mfma_kernel(const unsigned short* __restrict__ x2b,
                                   const int* __restrict__ knn,
                                   const unsigned short* __restrict__ w1t,  // [256][64]
                                   const float* __restrict__ b1,
                                   const unsigned short* __restrict__ w2t,  // [128][256]
                                   const float* __restrict__ b2,
                                   float* __restrict__ x3) {
    const int w    = threadIdx.x >> 6;
    const int lane = threadIdx.x & 63;
    const int l15  = lane & 15, quad = lane >> 4;
    const int p    = blockIdx.x * 4 + w;
    const int b    = p >> 11;
    __shared__ __align__(16) unsigned short sH1[64][264];

    const int nbr = knn[(size_t)p * KNB + l15];
    const bf16x8 a0 = *(const bf16x8*)(x2b + (size_t)p * 32 + quad * 8);
    const bf16x8 a1 = *(const bf16x8*)(x2b + ((size_t)(b * NPT) + nbr) * 32 + quad * 8);

#pragma unroll 1
    for (int h = 0; h < 2; ++h) {
        f32x4 acc1[8];
#pragma unroll
        for (int nt = 0; nt < 8; ++nt) acc1[nt] = (f32x4){0.f, 0.f, 0.f, 0.f};
#pragma unroll
        for (int nt = 0; nt < 8; ++nt) {
            const unsigned short* wp = w1t + (size_t)((h * 8 + nt) * 16 + l15) * 64 + quad * 8;
            const bf16x8 b0 = *(const bf16x8*)wp;
            const bf16x8 b1f = *(const bf16x8*)(wp + 32);
            acc1[nt] = __builtin_amdgcn_mfma_f32_16x16x32_bf16(a0, b0, acc1[nt], 0, 0, 0);
            acc1[nt] = __builtin_amdgcn_mfma_f32_16x16x32_bf16(a1, b1f, acc1[nt], 0, 0, 0);
        }
#pragma unroll
        for (int nt = 0; nt < 8; ++nt) {
            const float bv = b1[(h * 8 + nt) * 16 + l15];
#pragma unroll
            for (int r = 0; r < 4; ++r)
                sH1[w * 16 + quad * 4 + r][(h * 8 + nt) * 16 + l15] = bf16rne(lrelu(acc1[nt][r] + bv));
        }
    }
    __syncthreads();

    f32x4 acc2[8];
#pragma unroll
    for (int nt = 0; nt < 8; ++nt) acc2[nt] = (f32x4){0.f, 0.f, 0.f, 0.f};
#pragma unroll 2
    for (int ks = 0; ks < 8; ++ks) {
        const bf16x8 a = *(const bf16x8*)&sH1[w * 16 + l15][ks * 32 + quad * 8];
#pragma unroll
        for (int nt = 0; nt < 8; ++nt) {
            const bf16x8 bb = *(const bf16x8*)(w2t + (size_t)(nt * 16 + l15) * 256 + ks * 32 + quad * 8);
            acc2[nt] = __builtin_amdgcn_mfma_f32_16x16x32_bf16(a, bb, acc2[nt], 0, 0, 0);
        }
    }
#pragma unroll
    for (int nt = 0; nt < 8; ++nt) {
        const float bv = b2[nt * 16 + l15];
        float s = 0.f;
#pragma unroll
        for (int r = 0; r < 4; ++r) s += lrelu(acc2[nt][r] + bv);
        s += __shfl_xor(s, 16);
        s += __shfl_xor(s, 32);
        if (quad == 0) x3[(size_t)p * 128 + nt * 16 + l15] = s;
    }
}

// ---------------------------------------------------------------------------
// Block 3 via MFMA: A streamed from bf16 x3. No LDS/barriers.
// ---------------------------------------------------------------------------
__launch_bounds__(256, 2)
__global__ void block3_mfma_kernel(const unsigned short* __restrict__ x3b,
                                   const int* __restrict__ knn,
                                   const unsigned short* __restrict__ w3t,  // [128][256]
                                   const float* __restrict__ bias,
                                   float* __restrict__ x4) {
    const int w    = threadIdx.x >> 6;
    const int lane = threadIdx.x & 63;
    const int l15  = lane & 15, quad = lane >> 4;
    const int p    = blockIdx.x * 4 + w;
    const int b    = p >> 11;

    const int nbr = knn[(size_t)p * KNB + l15];
    const unsigned short* ctr = x3b + (size_t)p * 128 + quad * 8;
    const unsigned short* nbp = x3b + ((size_t)(b * NPT) + nbr) * 128 + quad * 8;

    f32x4 acc[8];
#pragma unroll
    for (int nt = 0; nt < 8; ++nt) acc[nt] = (f32x4){0.f, 0.f, 0.f, 0.f};
#pragma unroll 2
    for (int ks = 0; ks < 8; ++ks) {
        const bf16x8 a = (ks < 4) ? *(const bf16x8*)(ctr + ks * 32)
                                  : *(const bf16x8*)(nbp + (ks - 4) * 32);
#pragma unroll
        for (int nt = 0; nt < 8; ++nt) {
            const bf16x8 bb = *(const bf16x8*)(w3t + (size_t)(nt * 16 + l15) * 256 + ks * 32 + quad * 8);
            acc[nt] = __builtin_amdgcn_mfma_f32_16x16x32_bf16(a, bb, acc[nt], 0, 0, 0);
        }
    }
#pragma unroll
    for (int nt = 0; nt < 8; ++nt) {
        const float bv = bias[nt * 16 + l15];
        float s = 0.f;
#pragma unroll
        for (int r = 0; r < 4; ++r) s += lrelu(acc[nt][r] + bv);
        s += __shfl_xor(s, 16);
        s += __shfl_xor(s, 32);
        if (quad == 0) x4[(size_t)p * 128 + nt * 16 + l15] = s;
    }
}

// ---------------------------------------------------------------------------
// Maxpool stage 1
// ---------------------------------------------------------------------------
__launch_bounds__(128)
__global__ void maxpool_partial_kernel(const float* __restrict__ x4,
                                       float* __restrict__ part) {
    const int chunk = blockIdx.x, b = blockIdx.y, t = threadIdx.x;
    const float* xb = x4 + ((size_t)b * NPT + (size_t)chunk * 128) * 128;
    float m = -1e30f;
#pragma unroll 8
    for (int n = 0; n < 128; ++n) m = fmaxf(m, xb[(size_t)n * 128 + t]);
    part[((size_t)b * 16 + chunk) * 128 + t] = m;
}

// ---------------------------------------------------------------------------
// Head stage 2
// ---------------------------------------------------------------------------
__launch_bounds__(128)
__global__ void head2_kernel(const float* __restrict__ part,
                             const float* __restrict__ fc1w, const float* __restrict__ fc1b,
                             const float* __restrict__ fc2w, const float* __restrict__ fc2b,
                             const float* __restrict__ fc3w, const float* __restrict__ fc3b,
                             float* __restrict__ out) {
    const int g = blockIdx.x, b = blockIdx.y, t = threadIdx.x;
    __shared__ float s5[128], s6[128], s7[128];
    float m = -1e30f;
#pragma unroll
    for (int c = 0; c < 16; ++c)
        m = fmaxf(m, part[((size_t)b * 16 + c) * 128 + t]);
    s5[t] = m;
    __syncthreads();
    float a = fc1b[t];
#pragma unroll 4
    for (int i = 0; i < 128; ++i) a = fmaf(s5[i], fc1w[i * 128 + t], a);
    s6[t] = lrelu(a);
    __syncthreads();
    a = fc2b[t];
#pragma unroll 4
    for (int i = 0; i < 128; ++i) a = fmaf(s6[i], fc2w[i * 128 + t], a);
    s7[t] = lrelu(a);
    __syncthreads();
    const int o = g * 128 + t;
    float acc = fc3b[o];
#pragma unroll 4
    for (int i = 0; i < 128; ++i) acc = fmaf(s7[i], fc3w[(size_t)i * 6144 + o], acc);
    out[(size_t)b * 6144 + o] = acc;
}

// ---------------------------------------------------------------------------
extern "C" void kernel_launch(void* const* d_in, const int* in_sizes, int n_in,
                              void* d_out, int out_size, void* d_ws, size_t ws_size,
                              hipStream_t stream) {
    const float* x    = (const float*)d_in[0];
    const float* h1w1 = (const float*)d_in[1];
    const float* h1b1 = (const float*)d_in[2];
    const float* h1w2 = (const float*)d_in[3];
    const float* h1b2 = (const float*)d_in[4];
    const float* h1w3 = (const float*)d_in[5];
    const float* h1b3 = (const float*)d_in[6];
    const float* h2w1 = (const float*)d_in[7];
    const float* h2b1 = (const float*)d_in[8];
    const float* h2w2 = (const float*)d_in[9];
    const float* h2b2 = (const float*)d_in[10];
    const float* h3w1 = (const float*)d_in[11];
    const float* h3b1 = (const float*)d_in[12];
    const float* fc1w = (const float*)d_in[13];
    const float* fc1b = (const float*)d_in[14];
    const float* fc2w = (const float*)d_in[15];
    const float* fc2b = (const float*)d_in[16];
    const float* fc3w = (const float*)d_in[17];
    const float* fc3b = (const float*)d_in[18];

    float* ws  = (float*)d_ws;
    float* x2  = ws;                      //  524288 floats
    float* x3  = ws + 524288;             // 2097152 floats
    float* x4  = ws + 2621440;            // 2097152 floats
    int*   idx = (int*)(ws + 4718592);    //  262144 ints
    float* nrm = ws + 4980736;            //   16384 floats
    float* part= ws + 4997120;            //   16384 floats
    unsigned short* fb16 = (unsigned short*)(ws + 5013504); // 2M shorts
    unsigned short* w1t  = (unsigned short*)(ws + 6062080);
    unsigned short* w2t  = (unsigned short*)(ws + 6070272);
    unsigned short* w3t  = (unsigned short*)(ws + 6086656);
    // packed-key candidate buffer aliases the x4 region (free until block3)
    float* cd  = ws + 2621440;            // 1048576 floats (4 MB)
    float* out = (float*)d_out;

    const dim3 kg(32, 4, 8);   // (qtile, j-split, batch)

    wprep_kernel<<<64, 256, 0, stream>>>(h2w1, w1t, 64, 256);
    wprep_kernel<<<128, 256, 0, stream>>>(h2w2, w2t, 256, 128);
    wprep_kernel<<<128, 256, 0, stream>>>(h3w1, w3t, 256, 128);

    norms_kernel<3><<<64, 256, 0, stream>>>(x, nrm);
    knn3_kernel<4><<<kg, 256, 0, stream>>>(x, nrm, cd);
    knn_merge_kernel<4><<<64, 256, 0, stream>>>(cd, idx);
    block1_kernel<<<1024, 256, 0, stream>>>(x, idx, h1w1, h1b1, h1w2, h1b2, h1w3, h1b3, x2);

    tobf16_kernel<<<2048, 256, 0, stream>>>(x2, fb16, BSZ * NPT * 32);
    norms16_kernel<32><<<64, 256, 0, stream>>>(fb16, nrm);
    knn_mfma_kernel<32, 4><<<kg, 256, 0, stream>>>(fb16, nrm, cd);
    knn_merge_kernel<4><<<64, 256, 0, stream>>>(cd, idx);
    block2_mfma_kernel<<<BSZ * NPT / 4, 256, 0, stream>>>(fb16, idx, w1t, h2b1, w2t, h2b2, x3);

    tobf16_kernel<<<8192, 256, 0, stream>>>(x3, fb16, BSZ * NPT * 128);
    norms16_kernel<128><<<64, 256, 0, stream>>>(fb16, nrm);
    knn_mfma_kernel<128, 4><<<kg, 256, 0, stream>>>(fb16, nrm, cd);
    knn_merge_kernel<4><<<64, 256, 0, stream>>>(cd, idx);
    block3_mfma_kernel<<<BSZ * NPT / 4, 256, 0, stream>>>(fb16, idx, w3t, h3b1, x4);

    maxpool_partial_kernel<<<dim3(16, 8), 128, 0, stream>>>(x4, part);
    head2_kernel<<<dim3(48, 8), 128, 0, stream>>>(part, fc1w, fc1b, fc2w, fc2b,
                                                  fc3w, fc3b, out);
}

// Round 9
// 552.492 us; speedup vs baseline: 5.5257x; 1.3935x over previous
//
#include <hip/hip_runtime.h>

#define KNB 16
#define BSZ 8
#define NPT 2048

typedef __attribute__((ext_vector_type(8))) short bf16x8;
typedef __attribute__((ext_vector_type(4))) float f32x4;

__device__ __forceinline__ float lrelu(float x) { return x >= 0.f ? x : 0.01f * x; }

__device__ __forceinline__ unsigned short bf16rne(float f) {
    union { float f; unsigned int u; } v; v.f = f;
    return (unsigned short)((v.u + 0x7FFFu + ((v.u >> 16) & 1u)) >> 16);
}

// pack candidate index into low 11 mantissa bits of fp32 score -> unique,
// float-comparable key. idx = bits & 2047.
__device__ __forceinline__ float packkey(float d, int idx) {
    union { float f; unsigned int u; } v; v.f = d;
    v.u = (v.u & 0xFFFFF800u) | (unsigned int)idx;
    return v.f;
}

__device__ __forceinline__ float max16(const float* L) {
    float m = L[0];
#pragma unroll
    for (int u = 1; u < 16; ++u) m = fmaxf(m, L[u]);
    return m;
}

// ---------------------------------------------------------------------------
// fp32 -> bf16 (RNE), flat
// ---------------------------------------------------------------------------
__global__ void tobf16_kernel(const float* __restrict__ in, unsigned short* __restrict__ out, int n) {
    int i = blockIdx.x * 256 + threadIdx.x;
    if (i < n) out[i] = bf16rne(in[i]);
}

// ---------------------------------------------------------------------------
// Weight prep: w[K][N] fp32 -> wt[N][K] bf16
// ---------------------------------------------------------------------------
__global__ void wprep_kernel(const float* __restrict__ w, unsigned short* __restrict__ wt,
                             int K, int N) {
    int i = blockIdx.x * 256 + threadIdx.x;
    if (i < K * N) { int k = i / N, n = i - k * N; wt[n * K + k] = bf16rne(w[i]); }
}

// ---------------------------------------------------------------------------
// Per-point squared norms
// ---------------------------------------------------------------------------
template<int C>
__global__ void norms16_kernel(const unsigned short* __restrict__ feat, float* __restrict__ out) {
    int gid = blockIdx.x * blockDim.x + threadIdx.x;
    if (gid < BSZ * NPT) {
        const unsigned short* p = feat + (size_t)gid * C;
        float s = 0.f;
#pragma unroll
        for (int c = 0; c < C; ++c) {
            union { unsigned int u; float f; } v; v.u = ((unsigned int)p[c]) << 16;
            s = fmaf(v.f, v.f, s);
        }
        out[gid] = s;
    }
}

template<int C>
__global__ void norms_kernel(const float* __restrict__ feat, float* __restrict__ out) {
    int gid = blockIdx.x * blockDim.x + threadIdx.x;
    if (gid < BSZ * NPT) {
        const float* p = feat + (size_t)gid * C;
        float s = 0.f;
#pragma unroll
        for (int c = 0; c < C; ++c) s = fmaf(p[c], p[c], s);
        out[gid] = s;
    }
}

// ---------------------------------------------------------------------------
// KNN C=3, fp32, j-split JS (R8 structure, unchanged).
// ---------------------------------------------------------------------------
template<int JS>
__launch_bounds__(256, 3)
__global__ void knn3_kernel(const float* __restrict__ feat,
                            const float* __restrict__ norms,
                            float* __restrict__ cand) {
    constexpr int JL = NPT / JS;
    constexpr int JP = JL / 4;
    const int b = blockIdx.z, js = blockIdx.y, i0 = blockIdx.x * 64;
    const int t = threadIdx.x, w = t >> 6, lane = t & 63;
    const float* fb = feat + (size_t)b * NPT * 3;
    const float* nb = norms + (size_t)b * NPT;

    __shared__ float sS[4][64][17];

    float q0, q1, q2;
    { const float* qp = fb + (size_t)(i0 + lane) * 3; q0 = qp[0]; q1 = qp[1]; q2 = qp[2]; }

    float L[16];
    const int jbeg = js * JL + w * JP;
#pragma unroll
    for (int jj = 0; jj < 16; ++jj) {
        const int j = jbeg + jj;
        const float* pp = fb + (size_t)j * 3;
        const float d = fmaf(-2.f, fmaf(q0, pp[0], fmaf(q1, pp[1], q2 * pp[2])), nb[j]);
        L[jj] = packkey(d, j);
    }
    float mx = max16(L);

#pragma unroll 2
    for (int jj = 16; jj < JP; ++jj) {
        const int j = jbeg + jj;
        const float* pp = fb + (size_t)j * 3;
        const float d = fmaf(-2.f, fmaf(q0, pp[0], fmaf(q1, pp[1], q2 * pp[2])), nb[j]);
        const float k = packkey(d, j);
        if (k < mx) {
#pragma unroll
            for (int u = 0; u < 16; ++u) L[u] = (L[u] == mx) ? k : L[u];
            mx = max16(L);
        }
    }

#pragma unroll
    for (int c = 0; c < 16; ++c) sS[w][lane][c] = L[c];
    __syncthreads();
    if (w == 0 || w == 2) {
#pragma unroll
        for (int c = 0; c < 16; ++c) {
            const float k = sS[w + 1][lane][c];
            if (k < mx) {
#pragma unroll
                for (int u = 0; u < 16; ++u) L[u] = (L[u] == mx) ? k : L[u];
                mx = max16(L);
            }
        }
        if (w == 2) {
#pragma unroll
            for (int c = 0; c < 16; ++c) sS[2][lane][c] = L[c];
        }
    }
    __syncthreads();
    if (w == 0) {
#pragma unroll
        for (int c = 0; c < 16; ++c) {
            const float k = sS[2][lane][c];
            if (k < mx) {
#pragma unroll
                for (int u = 0; u < 16; ++u) L[u] = (L[u] == mx) ? k : L[u];
                mx = max16(L);
            }
        }
        float* o = cand + (((size_t)b * NPT + i0 + lane) * JS + js) * 16;
#pragma unroll
        for (int c = 0; c < 16; ++c) o[c] = L[c];
    }
}

// ---------------------------------------------------------------------------
// KNN via bf16 MFMA, C in {32,128}, j-split JS (R8 structure, unchanged).
// ---------------------------------------------------------------------------
template<int C, int JS>
__launch_bounds__(256, 3)
__global__ void knn_mfma_kernel(const unsigned short* __restrict__ fb16,
                                const float* __restrict__ norms,
                                float* __restrict__ cand) {
    constexpr int JL = NPT / JS;
    constexpr int KS = C / 32;
    const int b    = blockIdx.z;
    const int js   = blockIdx.y;
    const int i0   = blockIdx.x * 64;
    const int t    = threadIdx.x;
    const int w    = t >> 6;
    const int lane = t & 63;
    const int l15  = lane & 15;
    const int quad = lane >> 4;
    const unsigned short* fbb = fb16 + (size_t)b * NPT * C;
    const float* nb = norms + (size_t)b * NPT;

    __shared__ float sS[4][64][17];

    bf16x8 afr[KS * 4];
#pragma unroll
    for (int ks = 0; ks < KS; ++ks)
#pragma unroll
        for (int mi = 0; mi < 4; ++mi)
            afr[ks * 4 + mi] = *(const bf16x8*)(fbb + (size_t)(i0 + mi * 16 + l15) * C + ks * 32 + quad * 8);

    float L[16];
#pragma unroll
    for (int u = 0; u < 16; ++u) L[u] = 3e38f;
    float mx = 3e38f;

    const int jbeg = js * JL;
#pragma unroll 1
    for (int j0 = jbeg; j0 < jbeg + JL; j0 += 64) {
        f32x4 acc[4];
#pragma unroll
        for (int mi = 0; mi < 4; ++mi) acc[mi] = (f32x4){0.f, 0.f, 0.f, 0.f};
        const unsigned short* prow = fbb + (size_t)(j0 + w * 16 + l15) * C + quad * 8;
#pragma unroll
        for (int ks = 0; ks < KS; ++ks) {
            const bf16x8 bfr = *(const bf16x8*)(prow + ks * 32);
#pragma unroll
            for (int mi = 0; mi < 4; ++mi)
                acc[mi] = __builtin_amdgcn_mfma_f32_16x16x32_bf16(afr[ks * 4 + mi], bfr, acc[mi], 0, 0, 0);
        }
        const float nv  = nb[j0 + w * 16 + l15];
        const int  cidx = j0 + w * 16 + l15;
#pragma unroll
        for (int mi = 0; mi < 4; ++mi)
#pragma unroll
            for (int r = 0; r < 4; ++r)
                sS[w][mi * 16 + quad * 4 + r][l15] = packkey(fmaf(-2.f, acc[mi][r], nv), cidx);
        float k0[16];
#pragma unroll
        for (int c = 0; c < 16; ++c) k0[c] = sS[w][lane][c];
        if (j0 == jbeg) {
#pragma unroll
            for (int c = 0; c < 16; ++c) L[c] = k0[c];
            mx = max16(L);
        } else {
#pragma unroll
            for (int c = 0; c < 16; ++c) {
                const float k = k0[c];
                if (k < mx) {
#pragma unroll
                    for (int u = 0; u < 16; ++u) L[u] = (L[u] == mx) ? k : L[u];
                    mx = max16(L);
                }
            }
        }
    }

#pragma unroll
    for (int c = 0; c < 16; ++c) sS[w][lane][c] = L[c];
    __syncthreads();
    if (w == 0 || w == 2) {
#pragma unroll
        for (int c = 0; c < 16; ++c) {
            const float k = sS[w + 1][lane][c];
            if (k < mx) {
#pragma unroll
                for (int u = 0; u < 16; ++u) L[u] = (L[u] == mx) ? k : L[u];
                mx = max16(L);
            }
        }
        if (w == 2) {
#pragma unroll
            for (int c = 0; c < 16; ++c) sS[2][lane][c] = L[c];
        }
    }
    __syncthreads();
    if (w == 0) {
#pragma unroll
        for (int c = 0; c < 16; ++c) {
            const float k = sS[2][lane][c];
            if (k < mx) {
#pragma unroll
                for (int u = 0; u < 16; ++u) L[u] = (L[u] == mx) ? k : L[u];
                mx = max16(L);
            }
        }
        float* o = cand + (((size_t)b * NPT + i0 + lane) * JS + js) * 16;
#pragma unroll
        for (int c = 0; c < 16; ++c) o[c] = L[c];
    }
}

// ---------------------------------------------------------------------------
// Merge JS packed-key lists per query -> final top-16 indices.
// ---------------------------------------------------------------------------
template<int JS>
__launch_bounds__(256)
__global__ void knn_merge_kernel(const float* __restrict__ cand, int* __restrict__ knn_out) {
    const int q = blockIdx.x * 256 + threadIdx.x;
    const float* pd = cand + (size_t)q * JS * 16;
    float L[16];
#pragma unroll
    for (int u = 0; u < 16; ++u) L[u] = pd[u];
    float mx = max16(L);
#pragma unroll 2
    for (int u = 16; u < JS * 16; ++u) {
        const float k = pd[u];
        if (k < mx) {
#pragma unroll
            for (int v = 0; v < 16; ++v) L[v] = (L[v] == mx) ? k : L[v];
            mx = max16(L);
        }
    }
    int* o = knn_out + (size_t)q * KNB;
#pragma unroll
    for (int u = 0; u < 16; ++u) {
        union { float f; unsigned int v; } z; z.f = L[u];
        o[u] = (int)(z.v & 2047u);
    }
}

// ---------------------------------------------------------------------------
// Block 1: concat(x_i(3), x_j(3)) -> 16 -> 64 -> 32, lrelu each, sum over k.
// ---------------------------------------------------------------------------
__launch_bounds__(256)
__global__ void block1_kernel(const float* __restrict__ x, const int* __restrict__ knn,
                              const float* __restrict__ w1, const float* __restrict__ b1,
                              const float* __restrict__ w2, const float* __restrict__ b2,
                              const float* __restrict__ w3, const float* __restrict__ b3,
                              float* __restrict__ x2out) {
    __shared__ float sw1[96], sb1[16], sw2[1024], sb2[64], sw3[2048], sb3[32];
    __shared__ float sh[16][16][32];
    const int tid = threadIdx.x;
    for (int t = tid; t < 96;  t += 256) sw1[t] = w1[t];
    if (tid < 16) sb1[tid] = b1[tid];
    for (int t = tid; t < 1024; t += 256) sw2[t] = w2[t];
    if (tid < 64) sb2[tid] = b2[tid];
    for (int t = tid; t < 2048; t += 256) sw3[t] = w3[t];
    if (tid < 32) sb3[tid] = b3[tid];
    __syncthreads();

    const int pt = tid >> 4, k = tid & 15;
    const int bn = blockIdx.x * 16 + pt;
    const int b  = bn >> 11, n = bn & (NPT - 1);
    const float* xb = x + (size_t)b * NPT * 3;
    const int j = knn[(size_t)bn * KNB + k];

    float in6[6] = { xb[n*3+0], xb[n*3+1], xb[n*3+2],
                     xb[j*3+0], xb[j*3+1], xb[j*3+2] };
    float h1[16];
#pragma unroll
    for (int o = 0; o < 16; ++o) {
        float a = sb1[o];
#pragma unroll
        for (int i = 0; i < 6; ++i) a = fmaf(in6[i], sw1[i * 16 + o], a);
        h1[o] = lrelu(a);
    }
    float h2[64];
#pragma unroll
    for (int o = 0; o < 64; ++o) {
        float a = sb2[o];
#pragma unroll
        for (int i = 0; i < 16; ++i) a = fmaf(h1[i], sw2[i * 64 + o], a);
        h2[o] = lrelu(a);
    }
#pragma unroll
    for (int o = 0; o < 32; ++o) {
        float a = sb3[o];
#pragma unroll
        for (int i = 0; i < 64; ++i) a = fmaf(h2[i], sw3[i * 32 + o], a);
        sh[pt][k][o] = lrelu(a);
    }
    __syncthreads();
    for (int t = tid; t < 16 * 32; t += 256) {
        int p2 = t >> 5, o = t & 31;
        float s = 0.f;
#pragma unroll
        for (int kk = 0; kk < 16; ++kk) s += sh[p2][kk][o];
        x2out[(size_t)(blockIdx.x * 16 + p2) * 32 + o] = s;
    }
}

// ---------------------------------------------------------------------------
// Block 2 fused, weight-stationary (R9). Block = 256 thr, 8 points; all 4
// waves cooperate per point. Wave w: layer1 cols [64w,64w+64) (B1 8 frags),
// layer2 cols [32w,32w+32) (B2 16 frags) -- loaded ONCE per kernel. Per
// point: 3 TA loads + 8 MFMA -> H1 slice -> dbuf LDS -> 1 barrier -> 8
// ds_read_b128 + 16 MFMA -> shfl-reduce -> store. Fixes R8's TA-bound
// per-point weight reload (~1500 L1 transactions/wave/point -> ~50).
// ---------------------------------------------------------------------------
__launch_bounds__(256, 2)
__global__ void block2_fused_kernel(const unsigned short* __restrict__ x2b,
                                    const int* __restrict__ knn,
                                    const unsigned short* __restrict__ w1t,  // [256][64]
                                    const float* __restrict__ b1,
                                    const unsigned short* __restrict__ w2t,  // [128][256]
                                    const float* __restrict__ b2,
                                    float* __restrict__ x3) {
    const int w    = threadIdx.x >> 6;
    const int lane = threadIdx.x & 63;
    const int l15  = lane & 15, quad = lane >> 4;
    __shared__ __align__(16) unsigned short sH1[2][16][264];

    // one-time B fragments + biases
    bf16x8 B1[4][2];
#pragma unroll
    for (int nt2 = 0; nt2 < 4; ++nt2)
#pragma unroll
        for (int ks = 0; ks < 2; ++ks)
            B1[nt2][ks] = *(const bf16x8*)(w1t + (size_t)(w * 64 + nt2 * 16 + l15) * 64 + ks * 32 + quad * 8);
    bf16x8 B2[2][8];
#pragma unroll
    for (int nt2 = 0; nt2 < 2; ++nt2)
#pragma unroll
        for (int ks = 0; ks < 8; ++ks)
            B2[nt2][ks] = *(const bf16x8*)(w2t + (size_t)(w * 32 + nt2 * 16 + l15) * 256 + ks * 32 + quad * 8);
    float b1v[4];
#pragma unroll
    for (int nt2 = 0; nt2 < 4; ++nt2) b1v[nt2] = b1[w * 64 + nt2 * 16 + l15];
    float b2v[2];
#pragma unroll
    for (int nt2 = 0; nt2 < 2; ++nt2) b2v[nt2] = b2[w * 32 + nt2 * 16 + l15];

    const int p0 = blockIdx.x * 8;
#pragma unroll 1
    for (int pi = 0; pi < 8; ++pi) {
        const int p = p0 + pi, b = p >> 11, buf = pi & 1;
        const int nbr = knn[(size_t)p * KNB + l15];
        const bf16x8 a0 = *(const bf16x8*)(x2b + (size_t)p * 32 + quad * 8);
        const bf16x8 a1 = *(const bf16x8*)(x2b + ((size_t)(b * NPT) + nbr) * 32 + quad * 8);
        // layer 1: this wave's 64-col slice
#pragma unroll
        for (int nt2 = 0; nt2 < 4; ++nt2) {
            f32x4 acc = (f32x4){0.f, 0.f, 0.f, 0.f};
            acc = __builtin_amdgcn_mfma_f32_16x16x32_bf16(a0, B1[nt2][0], acc, 0, 0, 0);
            acc = __builtin_amdgcn_mfma_f32_16x16x32_bf16(a1, B1[nt2][1], acc, 0, 0, 0);
#pragma unroll
            for (int r = 0; r < 4; ++r)
                sH1[buf][quad * 4 + r][w * 64 + nt2 * 16 + l15] = bf16rne(lrelu(acc[r] + b1v[nt2]));
        }
        __syncthreads();   // H1[buf] complete (also fences reads of buf from pi-2)
        // layer 2: A from LDS, this wave's 32-col slice
        bf16x8 af[8];
#pragma unroll
        for (int ks = 0; ks < 8; ++ks)
            af[ks] = *(const bf16x8*)&sH1[buf][l15][ks * 32 + quad * 8];
#pragma unroll
        for (int nt2 = 0; nt2 < 2; ++nt2) {
            f32x4 acc = (f32x4){0.f, 0.f, 0.f, 0.f};
#pragma unroll
            for (int ks = 0; ks < 8; ++ks)
                acc = __builtin_amdgcn_mfma_f32_16x16x32_bf16(af[ks], B2[nt2][ks], acc, 0, 0, 0);
            float s = 0.f;
#pragma unroll
            for (int r = 0; r < 4; ++r) s += lrelu(acc[r] + b2v[nt2]);
            s += __shfl_xor(s, 16);
            s += __shfl_xor(s, 32);
            if (quad == 0) x3[(size_t)p * 128 + w * 32 + nt2 * 16 + l15] = s;
        }
    }
}

// ---------------------------------------------------------------------------
// Block 3 fused, weight-stationary: wave w owns cols [32w,32w+32) of 128;
// B3 (16 frags) loaded once; 8 points per block; A streamed from global
// (center broadcast + neighbor gather). No LDS, no barriers.
// ---------------------------------------------------------------------------
__launch_bounds__(256, 3)
__global__ void block3_fused_kernel(const unsigned short* __restrict__ x3b,
                                    const int* __restrict__ knn,
                                    const unsigned short* __restrict__ w3t,  // [128][256]
                                    const float* __restrict__ bias,
                                    float* __restrict__ x4) {
    const int w    = threadIdx.x >> 6;
    const int lane = threadIdx.x & 63;
    const int l15  = lane & 15, quad = lane >> 4;

    bf16x8 B3[2][8];
#pragma unroll
    for (int nt2 = 0; nt2 < 2; ++nt2)
#pragma unroll
        for (int ks = 0; ks < 8; ++ks)
            B3[nt2][ks] = *(const bf16x8*)(w3t + (size_t)(w * 32 + nt2 * 16 + l15) * 256 + ks * 32 + quad * 8);
    float bv[2];
#pragma unroll
    for (int nt2 = 0; nt2 < 2; ++nt2) bv[nt2] = bias[w * 32 + nt2 * 16 + l15];

    const int p0 = blockIdx.x * 8;
#pragma unroll 1
    for (int pi = 0; pi < 8; ++pi) {
        const int p = p0 + pi, b = p >> 11;
        const int nbr = knn[(size_t)p * KNB + l15];
        const unsigned short* ctr = x3b + (size_t)p * 128 + quad * 8;
        const unsigned short* nbp = x3b + ((size_t)(b * NPT) + nbr) * 128 + quad * 8;
        bf16x8 af[8];
#pragma unroll
        for (int ks = 0; ks < 4; ++ks) af[ks] = *(const bf16x8*)(ctr + ks * 32);
#pragma unroll
        for (int ks = 0; ks < 4; ++ks) af[4 + ks] = *(const bf16x8*)(nbp + ks * 32);
#pragma unroll
        for (int nt2 = 0; nt2 < 2; ++nt2) {
            f32x4 acc = (f32x4){0.f, 0.f, 0.f, 0.f};
#pragma unroll
            for (int ks = 0; ks < 8; ++ks)
                acc = __builtin_amdgcn_mfma_f32_16x16x32_bf16(af[ks], B3[nt2][ks], acc, 0, 0, 0);
            float s = 0.f;
#pragma unroll
            for (int r = 0; r < 4; ++r) s += lrelu(acc[r] + bv[nt2]);
            s += __shfl_xor(s, 16);
            s += __shfl_xor(s, 32);
            if (quad == 0) x4[(size_t)p * 128 + w * 32 + nt2 * 16 + l15] = s;
        }
    }
}

// ---------------------------------------------------------------------------
// Maxpool stage 1
// ---------------------------------------------------------------------------
__launch_bounds__(128)
__global__ void maxpool_partial_kernel(const float* __restrict__ x4,
                                       float* __restrict__ part) {
    const int chunk = blockIdx.x, b = blockIdx.y, t = threadIdx.x;
    const float* xb = x4 + ((size_t)b * NPT + (size_t)chunk * 128) * 128;
    float m = -1e30f;
#pragma unroll 8
    for (int n = 0; n < 128; ++n) m = fmaxf(m, xb[(size_t)n * 128 + t]);
    part[((size_t)b * 16 + chunk) * 128 + t] = m;
}

// ---------------------------------------------------------------------------
// Head stage 2
// ---------------------------------------------------------------------------
__launch_bounds__(128)
__global__ void head2_kernel(const float* __restrict__ part,
                             const float* __restrict__ fc1w, const float* __restrict__ fc1b,
                             const float* __restrict__ fc2w, const float* __restrict__ fc2b,
                             const float* __restrict__ fc3w, const float* __restrict__ fc3b,
                             float* __restrict__ out) {
    const int g = blockIdx.x, b = blockIdx.y, t = threadIdx.x;
    __shared__ float s5[128], s6[128], s7[128];
    float m = -1e30f;
#pragma unroll
    for (int c = 0; c < 16; ++c)
        m = fmaxf(m, part[((size_t)b * 16 + c) * 128 + t]);
    s5[t] = m;
    __syncthreads();
    float a = fc1b[t];
#pragma unroll 4
    for (int i = 0; i < 128; ++i) a = fmaf(s5[i], fc1w[i * 128 + t], a);
    s6[t] = lrelu(a);
    __syncthreads();
    a = fc2b[t];
#pragma unroll 4
    for (int i = 0; i < 128; ++i) a = fmaf(s6[i], fc2w[i * 128 + t], a);
    s7[t] = lrelu(a);
    __syncthreads();
    const int o = g * 128 + t;
    float acc = fc3b[o];
#pragma unroll 4
    for (int i = 0; i < 128; ++i) acc = fmaf(s7[i], fc3w[(size_t)i * 6144 + o], acc);
    out[(size_t)b * 6144 + o] = acc;
}

// ---------------------------------------------------------------------------
extern "C" void kernel_launch(void* const* d_in, const int* in_sizes, int n_in,
                              void* d_out, int out_size, void* d_ws, size_t ws_size,
                              hipStream_t stream) {
    const float* x    = (const float*)d_in[0];
    const float* h1w1 = (const float*)d_in[1];
    const float* h1b1 = (const float*)d_in[2];
    const float* h1w2 = (const float*)d_in[3];
    const float* h1b2 = (const float*)d_in[4];
    const float* h1w3 = (const float*)d_in[5];
    const float* h1b3 = (const float*)d_in[6];
    const float* h2w1 = (const float*)d_in[7];
    const float* h2b1 = (const float*)d_in[8];
    const float* h2w2 = (const float*)d_in[9];
    const float* h2b2 = (const float*)d_in[10];
    const float* h3w1 = (const float*)d_in[11];
    const float* h3b1 = (const float*)d_in[12];
    const float* fc1w = (const float*)d_in[13];
    const float* fc1b = (const float*)d_in[14];
    const float* fc2w = (const float*)d_in[15];
    const float* fc2b = (const float*)d_in[16];
    const float* fc3w = (const float*)d_in[17];
    const float* fc3b = (const float*)d_in[18];

    float* ws  = (float*)d_ws;
    float* x2  = ws;                      //  524288 floats
    float* x3  = ws + 524288;             // 2097152 floats
    float* x4  = ws + 2621440;            // 2097152 floats
    int*   idx = (int*)(ws + 4718592);    //  262144 ints
    float* nrm = ws + 4980736;            //   16384 floats
    float* part= ws + 4997120;            //   16384 floats
    unsigned short* fb16 = (unsigned short*)(ws + 5013504); // 2M shorts
    unsigned short* w1t  = (unsigned short*)(ws + 6062080);
    unsigned short* w2t  = (unsigned short*)(ws + 6070272);
    unsigned short* w3t  = (unsigned short*)(ws + 6086656);
    // packed-key candidate buffer aliases the x4 region (free until block3)
    float* cd  = ws + 2621440;            // 1048576 floats (4 MB)
    float* out = (float*)d_out;

    const dim3 kg(32, 4, 8);   // (qtile, j-split, batch)

    wprep_kernel<<<64, 256, 0, stream>>>(h2w1, w1t, 64, 256);
    wprep_kernel<<<128, 256, 0, stream>>>(h2w2, w2t, 256, 128);
    wprep_kernel<<<128, 256, 0, stream>>>(h3w1, w3t, 256, 128);

    norms_kernel<3><<<64, 256, 0, stream>>>(x, nrm);
    knn3_kernel<4><<<kg, 256, 0, stream>>>(x, nrm, cd);
    knn_merge_kernel<4><<<64, 256, 0, stream>>>(cd, idx);
    block1_kernel<<<1024, 256, 0, stream>>>(x, idx, h1w1, h1b1, h1w2, h1b2, h1w3, h1b3, x2);

    tobf16_kernel<<<2048, 256, 0, stream>>>(x2, fb16, BSZ * NPT * 32);
    norms16_kernel<32><<<64, 256, 0, stream>>>(fb16, nrm);
    knn_mfma_kernel<32, 4><<<kg, 256, 0, stream>>>(fb16, nrm, cd);
    knn_merge_kernel<4><<<64, 256, 0, stream>>>(cd, idx);
    block2_fused_kernel<<<BSZ * NPT / 8, 256, 0, stream>>>(fb16, idx, w1t, h2b1, w2t, h2b2, x3);

    tobf16_kernel<<<8192, 256, 0, stream>>>(x3, fb16, BSZ * NPT * 128);
    norms16_kernel<128><<<64, 256, 0, stream>>>(fb16, nrm);
    knn_mfma_kernel<128, 4><<<kg, 256, 0, stream>>>(fb16, nrm, cd);
    knn_merge_kernel<4><<<64, 256, 0, stream>>>(cd, idx);
    block3_fused_kernel<<<BSZ * NPT / 8, 256, 0, stream>>>(fb16, idx, w3t, h3b1, x4);

    maxpool_partial_kernel<<<dim3(16, 8), 128, 0, stream>>>(x4, part);
    head2_kernel<<<dim3(48, 8), 128, 0, stream>>>(part, fc1w, fc1b, fc2w, fc2b,
                                                  fc3w, fc3b, out);
}

// Round 10
// 500.785 us; speedup vs baseline: 6.0962x; 1.1033x over previous
//
#include <hip/hip_runtime.h>

#define KNB 16
#define BSZ 8
#define NPT 2048

typedef __attribute__((ext_vector_type(8))) short bf16x8;
typedef __attribute__((ext_vector_type(4))) float f32x4;

__device__ __forceinline__ float lrelu(float x) { return x >= 0.f ? x : 0.01f * x; }

__device__ __forceinline__ unsigned short bf16rne(float f) {
    union { float f; unsigned int u; } v; v.f = f;
    return (unsigned short)((v.u + 0x7FFFu + ((v.u >> 16) & 1u)) >> 16);
}

// pack candidate index into low 11 mantissa bits of fp32 score -> unique,
// float-comparable key. idx = bits & 2047.
__device__ __forceinline__ float packkey(float d, int idx) {
    union { float f; unsigned int u; } v; v.f = d;
    v.u = (v.u & 0xFFFFF800u) | (unsigned int)idx;
    return v.f;
}

__device__ __forceinline__ float max16(const float* L) {
    float m = L[0];
#pragma unroll
    for (int u = 1; u < 16; ++u) m = fmaxf(m, L[u]);
    return m;
}

// ---------------------------------------------------------------------------
// Weight prep: w[K][N] fp32 -> wt[N][K] bf16 (B-operand layout, block2/3)
// ---------------------------------------------------------------------------
__global__ void wprep_kernel(const float* __restrict__ w, unsigned short* __restrict__ wt,
                             int K, int N) {
    int i = blockIdx.x * 256 + threadIdx.x;
    if (i < K * N) { int k = i / N, n = i - k * N; wt[n * K + k] = bf16rne(w[i]); }
}

// ---------------------------------------------------------------------------
// Block1 weight prep: A-operand layout [out][Kpad] bf16, K zero-padded.
// w1: [6][16]->[16][32]; w2: [16][64]->[64][32]; w3: [64][32]->[32][64].
// ---------------------------------------------------------------------------
__global__ void wprep_b1_kernel(const float* __restrict__ w1, const float* __restrict__ w2,
                                const float* __restrict__ w3,
                                unsigned short* __restrict__ w1a, unsigned short* __restrict__ w2a,
                                unsigned short* __restrict__ w3a) {
    int i = blockIdx.x * 256 + threadIdx.x;
    if (i < 512) {
        int n = i >> 5, k = i & 31;
        w1a[i] = (k < 6) ? bf16rne(w1[k * 16 + n]) : (unsigned short)0;
    } else if (i < 2560) {
        int j = i - 512, n = j >> 5, k = j & 31;
        w2a[j] = (k < 16) ? bf16rne(w2[k * 64 + n]) : (unsigned short)0;
    } else if (i < 4608) {
        int j = i - 2560, n = j >> 6, k = j & 63;
        w3a[j] = bf16rne(w3[k * 32 + n]);
    }
}

// ---------------------------------------------------------------------------
// Per-point squared norms
// ---------------------------------------------------------------------------
template<int C>
__global__ void norms16_kernel(const unsigned short* __restrict__ feat, float* __restrict__ out) {
    int gid = blockIdx.x * blockDim.x + threadIdx.x;
    if (gid < BSZ * NPT) {
        const unsigned short* p = feat + (size_t)gid * C;
        float s = 0.f;
#pragma unroll
        for (int c = 0; c < C; ++c) {
            union { unsigned int u; float f; } v; v.u = ((unsigned int)p[c]) << 16;
            s = fmaf(v.f, v.f, s);
        }
        out[gid] = s;
    }
}

template<int C>
__global__ void norms_kernel(const float* __restrict__ feat, float* __restrict__ out) {
    int gid = blockIdx.x * blockDim.x + threadIdx.x;
    if (gid < BSZ * NPT) {
        const float* p = feat + (size_t)gid * C;
        float s = 0.f;
#pragma unroll
        for (int c = 0; c < C; ++c) s = fmaf(p[c], p[c], s);
        out[gid] = s;
    }
}

// ---------------------------------------------------------------------------
// KNN C=3, fp32, j-split JS (R8 structure, unchanged).
// ---------------------------------------------------------------------------
template<int JS>
__launch_bounds__(256, 3)
__global__ void knn3_kernel(const float* __restrict__ feat,
                            const float* __restrict__ norms,
                            float* __restrict__ cand) {
    constexpr int JL = NPT / JS;
    constexpr int JP = JL / 4;
    const int b = blockIdx.z, js = blockIdx.y, i0 = blockIdx.x * 64;
    const int t = threadIdx.x, w = t >> 6, lane = t & 63;
    const float* fb = feat + (size_t)b * NPT * 3;
    const float* nb = norms + (size_t)b * NPT;

    __shared__ float sS[4][64][17];

    float q0, q1, q2;
    { const float* qp = fb + (size_t)(i0 + lane) * 3; q0 = qp[0]; q1 = qp[1]; q2 = qp[2]; }

    float L[16];
    const int jbeg = js * JL + w * JP;
#pragma unroll
    for (int jj = 0; jj < 16; ++jj) {
        const int j = jbeg + jj;
        const float* pp = fb + (size_t)j * 3;
        const float d = fmaf(-2.f, fmaf(q0, pp[0], fmaf(q1, pp[1], q2 * pp[2])), nb[j]);
        L[jj] = packkey(d, j);
    }
    float mx = max16(L);

#pragma unroll 2
    for (int jj = 16; jj < JP; ++jj) {
        const int j = jbeg + jj;
        const float* pp = fb + (size_t)j * 3;
        const float d = fmaf(-2.f, fmaf(q0, pp[0], fmaf(q1, pp[1], q2 * pp[2])), nb[j]);
        const float k = packkey(d, j);
        if (k < mx) {
#pragma unroll
            for (int u = 0; u < 16; ++u) L[u] = (L[u] == mx) ? k : L[u];
            mx = max16(L);
        }
    }

#pragma unroll
    for (int c = 0; c < 16; ++c) sS[w][lane][c] = L[c];
    __syncthreads();
    if (w == 0 || w == 2) {
#pragma unroll
        for (int c = 0; c < 16; ++c) {
            const float k = sS[w + 1][lane][c];
            if (k < mx) {
#pragma unroll
                for (int u = 0; u < 16; ++u) L[u] = (L[u] == mx) ? k : L[u];
                mx = max16(L);
            }
        }
        if (w == 2) {
#pragma unroll
            for (int c = 0; c < 16; ++c) sS[2][lane][c] = L[c];
        }
    }
    __syncthreads();
    if (w == 0) {
#pragma unroll
        for (int c = 0; c < 16; ++c) {
            const float k = sS[2][lane][c];
            if (k < mx) {
#pragma unroll
                for (int u = 0; u < 16; ++u) L[u] = (L[u] == mx) ? k : L[u];
                mx = max16(L);
            }
        }
        float* o = cand + (((size_t)b * NPT + i0 + lane) * JS + js) * 16;
#pragma unroll
        for (int c = 0; c < 16; ++c) o[c] = L[c];
    }
}

// ---------------------------------------------------------------------------
// KNN via bf16 MFMA, C in {32,128}, j-split JS (R8 structure, unchanged).
// ---------------------------------------------------------------------------
template<int C, int JS>
__launch_bounds__(256, 3)
__global__ void knn_mfma_kernel(const unsigned short* __restrict__ fb16,
                                const float* __restrict__ norms,
                                float* __restrict__ cand) {
    constexpr int JL = NPT / JS;
    constexpr int KS = C / 32;
    const int b    = blockIdx.z;
    const int js   = blockIdx.y;
    const int i0   = blockIdx.x * 64;
    const int t    = threadIdx.x;
    const int w    = t >> 6;
    const int lane = t & 63;
    const int l15  = lane & 15;
    const int quad = lane >> 4;
    const unsigned short* fbb = fb16 + (size_t)b * NPT * C;
    const float* nb = norms + (size_t)b * NPT;

    __shared__ float sS[4][64][17];

    bf16x8 afr[KS * 4];
#pragma unroll
    for (int ks = 0; ks < KS; ++ks)
#pragma unroll
        for (int mi = 0; mi < 4; ++mi)
            afr[ks * 4 + mi] = *(const bf16x8*)(fbb + (size_t)(i0 + mi * 16 + l15) * C + ks * 32 + quad * 8);

    float L[16];
#pragma unroll
    for (int u = 0; u < 16; ++u) L[u] = 3e38f;
    float mx = 3e38f;

    const int jbeg = js * JL;
#pragma unroll 1
    for (int j0 = jbeg; j0 < jbeg + JL; j0 += 64) {
        f32x4 acc[4];
#pragma unroll
        for (int mi = 0; mi < 4; ++mi) acc[mi] = (f32x4){0.f, 0.f, 0.f, 0.f};
        const unsigned short* prow = fbb + (size_t)(j0 + w * 16 + l15) * C + quad * 8;
#pragma unroll
        for (int ks = 0; ks < KS; ++ks) {
            const bf16x8 bfr = *(const bf16x8*)(prow + ks * 32);
#pragma unroll
            for (int mi = 0; mi < 4; ++mi)
                acc[mi] = __builtin_amdgcn_mfma_f32_16x16x32_bf16(afr[ks * 4 + mi], bfr, acc[mi], 0, 0, 0);
        }
        const float nv  = nb[j0 + w * 16 + l15];
        const int  cidx = j0 + w * 16 + l15;
#pragma unroll
        for (int mi = 0; mi < 4; ++mi)
#pragma unroll
            for (int r = 0; r < 4; ++r)
                sS[w][mi * 16 + quad * 4 + r][l15] = packkey(fmaf(-2.f, acc[mi][r], nv), cidx);
        float k0[16];
#pragma unroll
        for (int c = 0; c < 16; ++c) k0[c] = sS[w][lane][c];
        if (j0 == jbeg) {
#pragma unroll
            for (int c = 0; c < 16; ++c) L[c] = k0[c];
            mx = max16(L);
        } else {
#pragma unroll
            for (int c = 0; c < 16; ++c) {
                const float k = k0[c];
                if (k < mx) {
#pragma unroll
                    for (int u = 0; u < 16; ++u) L[u] = (L[u] == mx) ? k : L[u];
                    mx = max16(L);
                }
            }
        }
    }

#pragma unroll
    for (int c = 0; c < 16; ++c) sS[w][lane][c] = L[c];
    __syncthreads();
    if (w == 0 || w == 2) {
#pragma unroll
        for (int c = 0; c < 16; ++c) {
            const float k = sS[w + 1][lane][c];
            if (k < mx) {
#pragma unroll
                for (int u = 0; u < 16; ++u) L[u] = (L[u] == mx) ? k : L[u];
                mx = max16(L);
            }
        }
        if (w == 2) {
#pragma unroll
            for (int c = 0; c < 16; ++c) sS[2][lane][c] = L[c];
        }
    }
    __syncthreads();
    if (w == 0) {
#pragma unroll
        for (int c = 0; c < 16; ++c) {
            const float k = sS[2][lane][c];
            if (k < mx) {
#pragma unroll
                for (int u = 0; u < 16; ++u) L[u] = (L[u] == mx) ? k : L[u];
                mx = max16(L);
            }
        }
        float* o = cand + (((size_t)b * NPT + i0 + lane) * JS + js) * 16;
#pragma unroll
        for (int c = 0; c < 16; ++c) o[c] = L[c];
    }
}

// ---------------------------------------------------------------------------
// Merge JS packed-key lists per query -> final top-16 indices.
// ---------------------------------------------------------------------------
template<int JS>
__launch_bounds__(256)
__global__ void knn_merge_kernel(const float* __restrict__ cand, int* __restrict__ knn_out) {
    const int q = blockIdx.x * 256 + threadIdx.x;
    const float* pd = cand + (size_t)q * JS * 16;
    float L[16];
#pragma unroll
    for (int u = 0; u < 16; ++u) L[u] = pd[u];
    float mx = max16(L);
#pragma unroll 2
    for (int u = 16; u < JS * 16; ++u) {
        const float k = pd[u];
        if (k < mx) {
#pragma unroll
            for (int v = 0; v < 16; ++v) L[v] = (L[v] == mx) ? k : L[v];
            mx = max16(L);
        }
    }
    int* o = knn_out + (size_t)q * KNB;
#pragma unroll
    for (int u = 0; u < 16; ++u) {
        union { float f; unsigned int v; } z; z.f = L[u];
        o[u] = (int)(z.v & 2047u);
    }
}

// ---------------------------------------------------------------------------
// Block 1 via MFMA, swapped operands (D = W^T . X^T), zero LDS/barriers.
// Wave = 1 point per step (16 neighbor rows live in the lane/column dim);
// D-frag (col=l15,row=quad*4+r) -> next layer's B-frag (lane=l15=k,
// kdim=quad*8+j) via 8 cross-quad shuffles at constant l15. K padded 6->32,
// 16->32 with zeros (weights pre-padded in w1a/w2a/w3a). Final sum over k =
// butterfly shfl_xor over l15. Writes x2 directly in bf16.
// ---------------------------------------------------------------------------
__launch_bounds__(256, 3)
__global__ void block1_mfma_kernel(const float* __restrict__ x, const int* __restrict__ knn,
                                   const unsigned short* __restrict__ w1a, const float* __restrict__ b1,
                                   const unsigned short* __restrict__ w2a, const float* __restrict__ b2,
                                   const unsigned short* __restrict__ w3a, const float* __restrict__ b3,
                                   unsigned short* __restrict__ x2b) {
    const int w = threadIdx.x >> 6, lane = threadIdx.x & 63;
    const int l15 = lane & 15, quad = lane >> 4;

    const bf16x8 W1 = *(const bf16x8*)(w1a + l15 * 32 + quad * 8);
    bf16x8 W2[4];
#pragma unroll
    for (int nt = 0; nt < 4; ++nt)
        W2[nt] = *(const bf16x8*)(w2a + (nt * 16 + l15) * 32 + quad * 8);
    bf16x8 W3[2][2];
#pragma unroll
    for (int tt = 0; tt < 2; ++tt)
#pragma unroll
        for (int ks = 0; ks < 2; ++ks)
            W3[tt][ks] = *(const bf16x8*)(w3a + (tt * 16 + l15) * 64 + ks * 32 + quad * 8);
    float b1v[4], b2v[4][4], b3v[2][4];
#pragma unroll
    for (int r = 0; r < 4; ++r) b1v[r] = b1[quad * 4 + r];
#pragma unroll
    for (int nt = 0; nt < 4; ++nt)
#pragma unroll
        for (int r = 0; r < 4; ++r) b2v[nt][r] = b2[nt * 16 + quad * 4 + r];
#pragma unroll
    for (int tt = 0; tt < 2; ++tt)
#pragma unroll
        for (int r = 0; r < 4; ++r) b3v[tt][r] = b3[tt * 16 + quad * 4 + r];

    const int src0 = ((2 * quad) & 3) * 16 + l15;
    const int src1 = ((2 * quad + 1) & 3) * 16 + l15;
    const int ntsel = quad >> 1;

    const int p0 = blockIdx.x * 16 + w * 4;
#pragma unroll 1
    for (int pi = 0; pi < 4; ++pi) {
        const int p = p0 + pi, b = p >> 11, n = p & (NPT - 1);
        // B1 = X^T frag: lane l15 = neighbor k, ch = quad*8+j (real ch 0..5)
        int d0 = 0, d1 = 0, d2 = 0;
        if (quad == 0) {
            const float* xc = x + ((size_t)b * NPT + n) * 3;
            const int jn = knn[(size_t)p * KNB + l15];
            const float* xn = x + ((size_t)b * NPT + jn) * 3;
            const unsigned s0 = bf16rne(xc[0]), s1 = bf16rne(xc[1]), s2 = bf16rne(xc[2]);
            const unsigned s3 = bf16rne(xn[0]), s4 = bf16rne(xn[1]), s5 = bf16rne(xn[2]);
            d0 = (int)(s0 | (s1 << 16));
            d1 = (int)(s2 | (s3 << 16));
            d2 = (int)(s4 | (s5 << 16));
        }
        union { int i[4]; bf16x8 v; } B1;
        B1.i[0] = d0; B1.i[1] = d1; B1.i[2] = d2; B1.i[3] = 0;
        const f32x4 a1 = __builtin_amdgcn_mfma_f32_16x16x32_bf16(W1, B1.v, (f32x4){0.f, 0.f, 0.f, 0.f}, 0, 0, 0);

        // H1 (lane l15=k holds ch quad*4+r): bias+lrelu, pack rows
        int h10, h11;
        {
            const unsigned t0 = bf16rne(lrelu(a1[0] + b1v[0]));
            const unsigned t1 = bf16rne(lrelu(a1[1] + b1v[1]));
            const unsigned t2 = bf16rne(lrelu(a1[2] + b1v[2]));
            const unsigned t3 = bf16rne(lrelu(a1[3] + b1v[3]));
            h10 = (int)(t0 | (t1 << 16));
            h11 = (int)(t2 | (t3 << 16));
        }
        // B2 frag: ch = quad*8+j (pad >=16 -> quads 2,3 zero)
        union { int i[4]; bf16x8 v; } B2;
        {
            const int e0 = __shfl(h10, src0), e1 = __shfl(h11, src0);
            const int e2 = __shfl(h10, src1), e3 = __shfl(h11, src1);
            const bool val = quad < 2;
            B2.i[0] = val ? e0 : 0; B2.i[1] = val ? e1 : 0;
            B2.i[2] = val ? e2 : 0; B2.i[3] = val ? e3 : 0;
        }
        f32x4 a2[4];
#pragma unroll
        for (int nt = 0; nt < 4; ++nt)
            a2[nt] = __builtin_amdgcn_mfma_f32_16x16x32_bf16(W2[nt], B2.v, (f32x4){0.f, 0.f, 0.f, 0.f}, 0, 0, 0);
        int dpk[4][2];
#pragma unroll
        for (int nt = 0; nt < 4; ++nt) {
            const unsigned t0 = bf16rne(lrelu(a2[nt][0] + b2v[nt][0]));
            const unsigned t1 = bf16rne(lrelu(a2[nt][1] + b2v[nt][1]));
            const unsigned t2 = bf16rne(lrelu(a2[nt][2] + b2v[nt][2]));
            const unsigned t3 = bf16rne(lrelu(a2[nt][3] + b2v[nt][3]));
            dpk[nt][0] = (int)(t0 | (t1 << 16));
            dpk[nt][1] = (int)(t2 | (t3 << 16));
        }
        // layer 3: K=64 over 2 k-steps; B3 frag ch = ks*32 + quad*8 + j
        f32x4 a3[2] = { (f32x4){0.f, 0.f, 0.f, 0.f}, (f32x4){0.f, 0.f, 0.f, 0.f} };
#pragma unroll
        for (int ks = 0; ks < 2; ++ks) {
            union { int i[4]; bf16x8 v; } B3;
            const int a0l = __shfl(dpk[2 * ks][0], src0), a0h = __shfl(dpk[2 * ks + 1][0], src0);
            const int a1l = __shfl(dpk[2 * ks][1], src0), a1h = __shfl(dpk[2 * ks + 1][1], src0);
            const int a2l = __shfl(dpk[2 * ks][0], src1), a2h = __shfl(dpk[2 * ks + 1][0], src1);
            const int a3l = __shfl(dpk[2 * ks][1], src1), a3h = __shfl(dpk[2 * ks + 1][1], src1);
            B3.i[0] = ntsel ? a0h : a0l;
            B3.i[1] = ntsel ? a1h : a1l;
            B3.i[2] = ntsel ? a2h : a2l;
            B3.i[3] = ntsel ? a3h : a3l;
#pragma unroll
            for (int tt = 0; tt < 2; ++tt)
                a3[tt] = __builtin_amdgcn_mfma_f32_16x16x32_bf16(W3[tt][ks], B3.v, a3[tt], 0, 0, 0);
        }
        // bias+lrelu, sum over k (lanes l15), store bf16
#pragma unroll
        for (int tt = 0; tt < 2; ++tt) {
#pragma unroll
            for (int r = 0; r < 4; ++r) {
                float s = lrelu(a3[tt][r] + b3v[tt][r]);
                s += __shfl_xor(s, 1);
                s += __shfl_xor(s, 2);
                s += __shfl_xor(s, 4);
                s += __shfl_xor(s, 8);
                if (l15 == 0)
                    x2b[(size_t)p * 32 + tt * 16 + quad * 4 + r] = bf16rne(s);
            }
        }
    }
}

// ---------------------------------------------------------------------------
// Block 2 fused, weight-stationary (R9); now writes x3 directly in bf16.
// ---------------------------------------------------------------------------
__launch_bounds__(256, 2)
__global__ void block2_fused_kernel(const unsigned short* __restrict__ x2b,
                                    const int* __restrict__ knn,
                                    const unsigned short* __restrict__ w1t,  // [256][64]
                                    const float* __restrict__ b1,
                                    const unsigned short* __restrict__ w2t,  // [128][256]
                                    const float* __restrict__ b2,
                                    unsigned short* __restrict__ x3b) {
    const int w    = threadIdx.x >> 6;
    const int lane = threadIdx.x & 63;
    const int l15  = lane & 15, quad = lane >> 4;
    __shared__ __align__(16) unsigned short sH1[2][16][264];

    bf16x8 B1[4][2];
#pragma unroll
    for (int nt2 = 0; nt2 < 4; ++nt2)
#pragma unroll
        for (int ks = 0; ks < 2; ++ks)
            B1[nt2][ks] = *(const bf16x8*)(w1t + (size_t)(w * 64 + nt2 * 16 + l15) * 64 + ks * 32 + quad * 8);
    bf16x8 B2[2][8];
#pragma unroll
    for (int nt2 = 0; nt2 < 2; ++nt2)
#pragma unroll
        for (int ks = 0; ks < 8; ++ks)
            B2[nt2][ks] = *(const bf16x8*)(w2t + (size_t)(w * 32 + nt2 * 16 + l15) * 256 + ks * 32 + quad * 8);
    float b1v[4];
#pragma unroll
    for (int nt2 = 0; nt2 < 4; ++nt2) b1v[nt2] = b1[w * 64 + nt2 * 16 + l15];
    float b2v[2];
#pragma unroll
    for (int nt2 = 0; nt2 < 2; ++nt2) b2v[nt2] = b2[w * 32 + nt2 * 16 + l15];

    const int p0 = blockIdx.x * 8;
#pragma unroll 1
    for (int pi = 0; pi < 8; ++pi) {
        const int p = p0 + pi, b = p >> 11, buf = pi & 1;
        const int nbr = knn[(size_t)p * KNB + l15];
        const bf16x8 a0 = *(const bf16x8*)(x2b + (size_t)p * 32 + quad * 8);
        const bf16x8 a1 = *(const bf16x8*)(x2b + ((size_t)(b * NPT) + nbr) * 32 + quad * 8);
#pragma unroll
        for (int nt2 = 0; nt2 < 4; ++nt2) {
            f32x4 acc = (f32x4){0.f, 0.f, 0.f, 0.f};
            acc = __builtin_amdgcn_mfma_f32_16x16x32_bf16(a0, B1[nt2][0], acc, 0, 0, 0);
            acc = __builtin_amdgcn_mfma_f32_16x16x32_bf16(a1, B1[nt2][1], acc, 0, 0, 0);
#pragma unroll
            for (int r = 0; r < 4; ++r)
                sH1[buf][quad * 4 + r][w * 64 + nt2 * 16 + l15] = bf16rne(lrelu(acc[r] + b1v[nt2]));
        }
        __syncthreads();
        bf16x8 af[8];
#pragma unroll
        for (int ks = 0; ks < 8; ++ks)
            af[ks] = *(const bf16x8*)&sH1[buf][l15][ks * 32 + quad * 8];
#pragma unroll
        for (int nt2 = 0; nt2 < 2; ++nt2) {
            f32x4 acc = (f32x4){0.f, 0.f, 0.f, 0.f};
#pragma unroll
            for (int ks = 0; ks < 8; ++ks)
                acc = __builtin_amdgcn_mfma_f32_16x16x32_bf16(af[ks], B2[nt2][ks], acc, 0, 0, 0);
            float s = 0.f;
#pragma unroll
            for (int r = 0; r < 4; ++r) s += lrelu(acc[r] + b2v[nt2]);
            s += __shfl_xor(s, 16);
            s += __shfl_xor(s, 32);
            if (quad == 0) x3b[(size_t)p * 128 + w * 32 + nt2 * 16 + l15] = bf16rne(s);
        }
    }
}

// ---------------------------------------------------------------------------
// Block 3 fused, weight-stationary (R9, unchanged): x4 fp32 out.
// ---------------------------------------------------------------------------
__launch_bounds__(256, 3)
__global__ void block3_fused_kernel(const unsigned short* __restrict__ x3b,
                                    const int* __restrict__ knn,
                                    const unsigned short* __restrict__ w3t,  // [128][256]
                                    const float* __restrict__ bias,
                                    float* __restrict__ x4) {
    const int w    = threadIdx.x >> 6;
    const int lane = threadIdx.x & 63;
    const int l15  = lane & 15, quad = lane >> 4;

    bf16x8 B3[2][8];
#pragma unroll
    for (int nt2 = 0; nt2 < 2; ++nt2)
#pragma unroll
        for (int ks = 0; ks < 8; ++ks)
            B3[nt2][ks] = *(const bf16x8*)(w3t + (size_t)(w * 32 + nt2 * 16 + l15) * 256 + ks * 32 + quad * 8);
    float bv[2];
#pragma unroll
    for (int nt2 = 0; nt2 < 2; ++nt2) bv[nt2] = bias[w * 32 + nt2 * 16 + l15];

    const int p0 = blockIdx.x * 8;
#pragma unroll 1
    for (int pi = 0; pi < 8; ++pi) {
        const int p = p0 + pi, b = p >> 11;
        const int nbr = knn[(size_t)p * KNB + l15];
        const unsigned short* ctr = x3b + (size_t)p * 128 + quad * 8;
        const unsigned short* nbp = x3b + ((size_t)(b * NPT) + nbr) * 128 + quad * 8;
        bf16x8 af[8];
#pragma unroll
        for (int ks = 0; ks < 4; ++ks) af[ks] = *(const bf16x8*)(ctr + ks * 32);
#pragma unroll
        for (int ks = 0; ks < 4; ++ks) af[4 + ks] = *(const bf16x8*)(nbp + ks * 32);
#pragma unroll
        for (int nt2 = 0; nt2 < 2; ++nt2) {
            f32x4 acc = (f32x4){0.f, 0.f, 0.f, 0.f};
#pragma unroll
            for (int ks = 0; ks < 8; ++ks)
                acc = __builtin_amdgcn_mfma_f32_16x16x32_bf16(af[ks], B3[nt2][ks], acc, 0, 0, 0);
            float s = 0.f;
#pragma unroll
            for (int r = 0; r < 4; ++r) s += lrelu(acc[r] + bv[nt2]);
            s += __shfl_xor(s, 16);
            s += __shfl_xor(s, 32);
            if (quad == 0) x4[(size_t)p * 128 + w * 32 + nt2 * 16 + l15] = s;
        }
    }
}

// ---------------------------------------------------------------------------
// Maxpool stage 1
// ---------------------------------------------------------------------------
__launch_bounds__(128)
__global__ void maxpool_partial_kernel(const float* __restrict__ x4,
                                       float* __restrict__ part) {
    const int chunk = blockIdx.x, b = blockIdx.y, t = threadIdx.x;
    const float* xb = x4 + ((size_t)b * NPT + (size_t)chunk * 128) * 128;
    float m = -1e30f;
#pragma unroll 8
    for (int n = 0; n < 128; ++n) m = fmaxf(m, xb[(size_t)n * 128 + t]);
    part[((size_t)b * 16 + chunk) * 128 + t] = m;
}

// ---------------------------------------------------------------------------
// Head stage 2
// ---------------------------------------------------------------------------
__launch_bounds__(128)
__global__ void head2_kernel(const float* __restrict__ part,
                             const float* __restrict__ fc1w, const float* __restrict__ fc1b,
                             const float* __restrict__ fc2w, const float* __restrict__ fc2b,
                             const float* __restrict__ fc3w, const float* __restrict__ fc3b,
                             float* __restrict__ out) {
    const int g = blockIdx.x, b = blockIdx.y, t = threadIdx.x;
    __shared__ float s5[128], s6[128], s7[128];
    float m = -1e30f;
#pragma unroll
    for (int c = 0; c < 16; ++c)
        m = fmaxf(m, part[((size_t)b * 16 + c) * 128 + t]);
    s5[t] = m;
    __syncthreads();
    float a = fc1b[t];
#pragma unroll 4
    for (int i = 0; i < 128; ++i) a = fmaf(s5[i], fc1w[i * 128 + t], a);
    s6[t] = lrelu(a);
    __syncthreads();
    a = fc2b[t];
#pragma unroll 4
    for (int i = 0; i < 128; ++i) a = fmaf(s6[i], fc2w[i * 128 + t], a);
    s7[t] = lrelu(a);
    __syncthreads();
    const int o = g * 128 + t;
    float acc = fc3b[o];
#pragma unroll 4
    for (int i = 0; i < 128; ++i) acc = fmaf(s7[i], fc3w[(size_t)i * 6144 + o], acc);
    out[(size_t)b * 6144 + o] = acc;
}

// ---------------------------------------------------------------------------
extern "C" void kernel_launch(void* const* d_in, const int* in_sizes, int n_in,
                              void* d_out, int out_size, void* d_ws, size_t ws_size,
                              hipStream_t stream) {
    const float* x    = (const float*)d_in[0];
    const float* h1w1 = (const float*)d_in[1];
    const float* h1b1 = (const float*)d_in[2];
    const float* h1w2 = (const float*)d_in[3];
    const float* h1b2 = (const float*)d_in[4];
    const float* h1w3 = (const float*)d_in[5];
    const float* h1b3 = (const float*)d_in[6];
    const float* h2w1 = (const float*)d_in[7];
    const float* h2b1 = (const float*)d_in[8];
    const float* h2w2 = (const float*)d_in[9];
    const float* h2b2 = (const float*)d_in[10];
    const float* h3w1 = (const float*)d_in[11];
    const float* h3b1 = (const float*)d_in[12];
    const float* fc1w = (const float*)d_in[13];
    const float* fc1b = (const float*)d_in[14];
    const float* fc2w = (const float*)d_in[15];
    const float* fc2b = (const float*)d_in[16];
    const float* fc3w = (const float*)d_in[17];
    const float* fc3b = (const float*)d_in[18];

    float* ws = (float*)d_ws;
    unsigned short* x2b16 = (unsigned short*)ws;              //  524288 sh (262144 fl)
    unsigned short* x3b16 = (unsigned short*)(ws + 262144);   // 2097152 sh (1048576 fl)
    float* x4   = ws + 1310720;                               // 2097152 fl
    int*   idx  = (int*)(ws + 3407872);                       //  262144 int
    float* nrm  = ws + 3670016;                               //   16384 fl
    float* part = ws + 3686400;                               //   16384 fl
    unsigned short* w1t = (unsigned short*)(ws + 3702784);    //  16384 sh
    unsigned short* w2t = (unsigned short*)(ws + 3710976);    //  32768 sh
    unsigned short* w3t = (unsigned short*)(ws + 3727360);    //  32768 sh
    unsigned short* w1a = (unsigned short*)(ws + 3743744);    //    512 sh
    unsigned short* w2a = (unsigned short*)(ws + 3744000);    //   2048 sh
    unsigned short* w3a = (unsigned short*)(ws + 3745024);    //   2048 sh
    float* cd   = ws + 3746048;                               // 1048576 fl (~19.2 MB total)
    float* out  = (float*)d_out;

    const dim3 kg(32, 4, 8);   // (qtile, j-split, batch)

    wprep_kernel<<<64, 256, 0, stream>>>(h2w1, w1t, 64, 256);
    wprep_kernel<<<128, 256, 0, stream>>>(h2w2, w2t, 256, 128);
    wprep_kernel<<<128, 256, 0, stream>>>(h3w1, w3t, 256, 128);
    wprep_b1_kernel<<<18, 256, 0, stream>>>(h1w1, h1w2, h1w3, w1a, w2a, w3a);

    norms_kernel<3><<<64, 256, 0, stream>>>(x, nrm);
    knn3_kernel<4><<<kg, 256, 0, stream>>>(x, nrm, cd);
    knn_merge_kernel<4><<<64, 256, 0, stream>>>(cd, idx);
    block1_mfma_kernel<<<1024, 256, 0, stream>>>(x, idx, w1a, h1b1, w2a, h1b2, w3a, h1b3, x2b16);

    norms16_kernel<32><<<64, 256, 0, stream>>>(x2b16, nrm);
    knn_mfma_kernel<32, 4><<<kg, 256, 0, stream>>>(x2b16, nrm, cd);
    knn_merge_kernel<4><<<64, 256, 0, stream>>>(cd, idx);
    block2_fused_kernel<<<BSZ * NPT / 8, 256, 0, stream>>>(x2b16, idx, w1t, h2b1, w2t, h2b2, x3b16);

    norms16_kernel<128><<<64, 256, 0, stream>>>(x3b16, nrm);
    knn_mfma_kernel<128, 4><<<kg, 256, 0, stream>>>(x3b16, nrm, cd);
    knn_merge_kernel<4><<<64, 256, 0, stream>>>(cd, idx);
    block3_fused_kernel<<<BSZ * NPT / 8, 256, 0, stream>>>(x3b16, idx, w3t, h3b1, x4);

    maxpool_partial_kernel<<<dim3(16, 8), 128, 0, stream>>>(x4, part);
    head2_kernel<<<dim3(48, 8), 128, 0, stream>>>(part, fc1w, fc1b, fc2w, fc2b,
                                                  fc3w, fc3b, out);
}